// Round 1
// baseline (11335.636 us; speedup 1.0000x reference)
//
#include <hip/hip_runtime.h>
#include <math.h>

#define NH 8
#define DHD 64
#define DIMM 512
#define QB 4
#define NT 1024
#define NHQ 32
#define NROWS 32768
#define GAMMA_C 0.01f

// ---------------- workspace layout (float offsets) ----------------
#define OFF_FQ    0u
#define OFF_FK    2097152u
#define OFF_FV    4194304u
#define OFF_RAW   6291456u
#define OFF_NQ    39845888u
#define OFF_MUQ   39878656u
#define OFF_TN    39911424u
#define OFF_NK    39944192u
#define OFF_SK    39976960u
#define OFF_VC    40009728u
#define OFF_RMAX  40042496u
#define OFF_NU    40075264u
#define OFF_UU    40077312u
#define OFF_FEAT  40077344u
#define OFF_WV    40078368u
#define OFF_SCAL  40078392u
#define OFF_ACC   40078400u   // 8 doubles (16 floats), 8-byte aligned

// zero the f64 accumulators
__global__ void k_zero(double* acc) {
    if (threadIdx.x < 8) acc[threadIdx.x] = 0.0;
}

// LN(token) @ W_in -> f[hq][n][d]
__global__ __launch_bounds__(256) void k_proj(const float* __restrict__ x,
        const float* __restrict__ lnw, const float* __restrict__ lnb,
        const float* __restrict__ Win, float* __restrict__ fout) {
    int tok = blockIdx.x;
    int qi = tok >> 10, n = tok & 1023;
    __shared__ float xs[DIMM];
    __shared__ float red[16];
    __shared__ float mu_s, rstd_s;
    int t = threadIdx.x;
    float a = x[(size_t)tok * DIMM + t];
    float b = x[(size_t)tok * DIMM + t + 256];
    float s = a + b, s2 = a * a + b * b;
    for (int o = 32; o > 0; o >>= 1) { s += __shfl_down(s, o); s2 += __shfl_down(s2, o); }
    int wid = t >> 6, lane = t & 63;
    if (lane == 0) { red[wid] = s; red[wid + 8] = s2; }
    __syncthreads();
    if (t == 0) {
        float S = red[0] + red[1] + red[2] + red[3];
        float S2 = red[8] + red[9] + red[10] + red[11];
        float mu = S / 512.0f;
        float var = S2 / 512.0f - mu * mu;
        if (var < 0.0f) var = 0.0f;
        mu_s = mu; rstd_s = rsqrtf(var + 1e-5f);
    }
    __syncthreads();
    float mu = mu_s, rstd = rstd_s;
    xs[t]       = (a - mu) * rstd * lnw[t] + lnb[t];
    xs[t + 256] = (b - mu) * rstd * lnw[t + 256] + lnb[t + 256];
    __syncthreads();
    float acc0 = 0.0f, acc1 = 0.0f;
    for (int d = 0; d < DIMM; ++d) {
        float xv = xs[d];
        acc0 += xv * Win[d * DIMM + t];
        acc1 += xv * Win[d * DIMM + t + 256];
    }
    int j0 = t, j1 = t + 256;
    fout[((size_t)((j0 >> 6) * QB + qi) * NT + n) * DHD + (j0 & 63)] = acc0;
    fout[((size_t)((j1 >> 6) * QB + qi) * NT + n) * DHD + (j1 & 63)] = acc1;
}

// per-row norms / means / sums for fq and fk
__global__ __launch_bounds__(256) void k_rowstats(const float* __restrict__ fq,
        const float* __restrict__ fk, float* nq, float* muq, float* nk, float* sk) {
    int row = blockIdx.x * 4 + (threadIdx.x >> 6);
    int lane = threadIdx.x & 63;
    const float* f = (blockIdx.y == 0) ? fq : fk;
    float v = f[(size_t)row * DHD + lane];
    float s = v, s2 = v * v;
    for (int o = 32; o > 0; o >>= 1) { s += __shfl_down(s, o); s2 += __shfl_down(s2, o); }
    if (lane == 0) {
        if (blockIdx.y == 0) { nq[row] = sqrtf(s2); muq[row] = s / 64.0f; }
        else                 { nk[row] = sqrtf(s2); sk[row] = s; }
    }
}

// per-(hq) column mean of fk over tokens (nu), and u = sum_d nu
__global__ __launch_bounds__(64) void k_colmean(const float* __restrict__ fk,
        float* nu, float* uu) {
    int hq = blockIdx.x; int d = threadIdx.x;
    const float* base = fk + (size_t)hq * NT * DHD;
    float s = 0.0f;
    for (int m = 0; m < NT; ++m) s += base[m * DHD + d];
    float nud = s / (float)NT;
    nu[hq * DHD + d] = nud;
    float tsum = nud;
    for (int o = 32; o > 0; o >>= 1) tsum += __shfl_down(tsum, o);
    if (d == 0) uu[hq] = tsum;
}

// t_n = fq_row . nu
__global__ __launch_bounds__(256) void k_tn(const float* __restrict__ fq,
        const float* __restrict__ nu, float* tn) {
    int row = blockIdx.x * 4 + (threadIdx.x >> 6);
    int lane = threadIdx.x & 63;
    int hq = row >> 10;
    float p = fq[(size_t)row * DHD + lane] * nu[hq * DHD + lane];
    for (int o = 32; o > 0; o >>= 1) p += __shfl_down(p, o);
    if (lane == 0) tn[row] = p;
}

// feat[h] = concat(mean_{q,n} fq[h], mean_{q,n} fk[h])
__global__ __launch_bounds__(64) void k_feat(const float* __restrict__ fq,
        const float* __restrict__ fk, float* feat) {
    int h = blockIdx.x; int d = threadIdx.x;
    float sq = 0.0f, skk = 0.0f;
    for (int qi = 0; qi < QB; ++qi) {
        const float* bq = fq + (size_t)(h * QB + qi) * NT * DHD;
        const float* bk = fk + (size_t)(h * QB + qi) * NT * DHD;
        for (int n = 0; n < NT; ++n) { sq += bq[n * DHD + d]; skk += bk[n * DHD + d]; }
    }
    feat[h * 128 + d] = sq / 4096.0f;
    feat[h * 128 + 64 + d] = skk / 4096.0f;
}

// tiny MLP weight predictor -> wv[h][3]
__global__ __launch_bounds__(256) void k_mlp(const float* __restrict__ feat,
        const float* __restrict__ W1, const float* __restrict__ b1,
        const float* __restrict__ lw, const float* __restrict__ lb,
        const float* __restrict__ W2, const float* __restrict__ b2,
        const float* __restrict__ W3, const float* __restrict__ b3,
        const float* __restrict__ W4, const float* __restrict__ b4,
        const float* __restrict__ wtemp, float* wv) {
    __shared__ float h1[256], h2[192], h3[64], red[8];
    int t = threadIdx.x;
    for (int h = 0; h < NH; ++h) {
        float p = 0.0f;
        for (int i = 0; i < 128; ++i) p += feat[h * 128 + i] * W1[i * 256 + t];
        p += b1[t];
        float s = p, s2 = p * p;
        for (int o = 32; o > 0; o >>= 1) { s += __shfl_down(s, o); s2 += __shfl_down(s2, o); }
        if ((t & 63) == 0) { red[t >> 6] = s; red[4 + (t >> 6)] = s2; }
        __syncthreads();
        float S = red[0] + red[1] + red[2] + red[3];
        float S2 = red[4] + red[5] + red[6] + red[7];
        float mu = S / 256.0f;
        float var = S2 / 256.0f - mu * mu; if (var < 0.0f) var = 0.0f;
        float xh = (p - mu) * rsqrtf(var + 1e-5f) * lw[t] + lb[t];
        h1[t] = fmaxf(xh, 0.0f);
        __syncthreads();
        if (t < 192) {
            float a = 0.0f;
            for (int i = 0; i < 256; ++i) a += h1[i] * W2[i * 192 + t];
            h2[t] = fmaxf(a + b2[t], 0.0f);
        }
        __syncthreads();
        if (t < 64) {
            float a = 0.0f;
            for (int i = 0; i < 192; ++i) a += h2[i] * W3[i * 64 + t];
            h3[t] = fmaxf(a + b3[t], 0.0f);
        }
        __syncthreads();
        if (t == 0) {
            float lg[3];
            for (int j = 0; j < 3; ++j) {
                float a = 0.0f;
                for (int i = 0; i < 64; ++i) a += h3[i] * W4[i * 3 + j];
                lg[j] = a + b4[j];
            }
            float mx = fmaxf(lg[0], fmaxf(lg[1], lg[2]));
            float e0 = expf(lg[0] - mx), e1 = expf(lg[1] - mx), e2 = expf(lg[2] - mx);
            float se = e0 + e1 + e2;
            float pr0 = e0 / se, pr1 = e1 / se, pr2 = e2 / se;
            float wt = wtemp[0]; wt = fminf(fmaxf(wt, 0.01f), 1.0f);
            float q0 = pr0 / wt, q1 = pr1 / wt, q2 = pr2 / wt;
            float m2 = fmaxf(q0, fmaxf(q1, q2));
            float f0 = expf(q0 - m2), f1 = expf(q1 - m2), f2 = expf(q2 - m2);
            float sf = f0 + f1 + f2; f0 /= sf; f1 /= sf; f2 /= sf;
            f0 = fminf(fmaxf(f0, 0.01f), 0.95f);
            f1 = fminf(fmaxf(f1, 0.01f), 0.95f);
            f2 = fminf(fmaxf(f2, 0.01f), 0.95f);
            float sw = f0 + f1 + f2;
            wv[h * 3 + 0] = f0 / sw; wv[h * 3 + 1] = f1 / sw; wv[h * 3 + 2] = f2 / sw;
        }
        __syncthreads();
    }
}

// batched raw = fq @ fk^T  (32 x 1024x1024x64), fp32 tiled
__global__ __launch_bounds__(256) void k_qkt(const float* __restrict__ fq,
        const float* __restrict__ fk, float* __restrict__ raw) {
    int hq = blockIdx.z;
    int n0 = blockIdx.y * 64, m0 = blockIdx.x * 64;
    __shared__ float As[64][65];
    __shared__ float Bs[64][65];
    const float* A = fq + (size_t)hq * NT * DHD;
    const float* B = fk + (size_t)hq * NT * DHD;
    int t = threadIdx.x;
    for (int i = t; i < 4096; i += 256) {
        int r = i >> 6, c = i & 63;
        As[r][c] = A[(size_t)(n0 + r) * DHD + c];
        Bs[r][c] = B[(size_t)(m0 + r) * DHD + c];
    }
    __syncthreads();
    int ti = t >> 4, tj = t & 15;
    float acc[4][4] = {};
    for (int d = 0; d < 64; ++d) {
        float av[4], bv[4];
        for (int i = 0; i < 4; ++i) av[i] = As[ti * 4 + i][d];
        for (int j = 0; j < 4; ++j) bv[j] = Bs[tj * 4 + j][d];
        for (int i = 0; i < 4; ++i)
            for (int j = 0; j < 4; ++j) acc[i][j] += av[i] * bv[j];
    }
    float* R = raw + (size_t)hq * NT * NT;
    for (int i = 0; i < 4; ++i)
        for (int j = 0; j < 4; ++j)
            R[(size_t)(n0 + ti * 4 + i) * NT + m0 + tj * 4 + j] = acc[i][j];
}

// pass B: global sums of cosine_sim / cov, per-row margin mean
__global__ __launch_bounds__(256) void k_passb(const float* __restrict__ raw,
        const float* __restrict__ nq, const float* __restrict__ muq,
        const float* __restrict__ tn, const float* __restrict__ nk,
        const float* __restrict__ sk, const float* __restrict__ uu,
        float* __restrict__ vcrow, double* acc) {
    int row = blockIdx.x;
    int hq = row >> 10;
    const float* R = raw + (size_t)row * NT;
    float nqv = nq[row], muv = muq[row], tv = tn[row], uv = uu[hq];
    float c1 = nqv + 1e-6f;
    float c2 = fmaxf(nqv, 1e-4f);
    const float covscale = 0.001f / 1024.0f;
    double scos = 0, s2cos = 0, scov = 0, s2cov = 0;
    float smarg = 0.0f;
    for (int m = threadIdx.x; m < NT; m += 256) {
        float r = R[m];
        float nkv = nk[hq * NT + m];
        float skv = sk[hq * NT + m];
        float cosv = r / (c1 * (nkv + 1e-6f));
        cosv = fminf(fmaxf(cosv, -0.95f), 0.95f);
        float cs = r / (c2 * fmaxf(nkv, 1e-4f));
        cs = fminf(fmaxf(cs, -0.95f), 0.95f);
        float marg = fminf(fmaxf(GAMMA_C - cs, 0.0f), 15.0f);
        float cp = (r - tv - muv * skv + muv * uv) / 8.0001f;
        float cov = fminf(fmaxf(covscale * cp, -50.0f), 50.0f);
        scos += cosv; s2cos += (double)cosv * cosv;
        scov += cov;  s2cov += (double)cov * cov;
        smarg += marg;
    }
    for (int o = 32; o > 0; o >>= 1) {
        scos += __shfl_down(scos, o); s2cos += __shfl_down(s2cos, o);
        scov += __shfl_down(scov, o); s2cov += __shfl_down(s2cov, o);
        smarg += __shfl_down(smarg, o);
    }
    __shared__ float wm[4];
    int wid = threadIdx.x >> 6, lane = threadIdx.x & 63;
    if (lane == 0) {
        atomicAdd(&acc[0], scos); atomicAdd(&acc[1], s2cos);
        atomicAdd(&acc[2], scov); atomicAdd(&acc[3], s2cov);
        wm[wid] = smarg;
    }
    __syncthreads();
    if (threadIdx.x == 0) {
        float rm = (wm[0] + wm[1] + wm[2] + wm[3]) / 1024.0f;
        vcrow[row] = rm;
        atomicAdd(&acc[4], (double)rm * 1024.0);
        atomicAdd(&acc[5], (double)rm * (double)rm * 1024.0);
    }
}

__global__ void k_fin1(const double* acc, float* scal) {
    const double cnt = 33554432.0;
    scal[0] = (float)sqrt(fmax(0.0, (acc[1] - acc[0] * acc[0] / cnt) / (cnt - 1.0)));
    scal[1] = (float)sqrt(fmax(0.0, (acc[3] - acc[2] * acc[2] / cnt) / (cnt - 1.0)));
    scal[2] = (float)sqrt(fmax(0.0, (acc[5] - acc[4] * acc[4] / cnt) / (cnt - 1.0)));
}

// pass D: dots (in place over raw), global sum/sumsq dots, row max
__global__ __launch_bounds__(256) void k_passd(float* __restrict__ raw,
        const float* __restrict__ nq, const float* __restrict__ muq,
        const float* __restrict__ tn, const float* __restrict__ nk,
        const float* __restrict__ sk, const float* __restrict__ uu,
        const float* __restrict__ vcrow, const float* __restrict__ wv,
        const float* __restrict__ scal, float* __restrict__ rmax, double* acc) {
    int row = blockIdx.x;
    int hq = row >> 10;
    int h = hq >> 2;
    float* R = raw + (size_t)row * NT;
    float nqv = nq[row], muv = muq[row], tv = tn[row], uv = uu[hq];
    float c1 = nqv + 1e-6f;
    float vc = vcrow[row];
    float s1 = scal[0] + 1e-4f, s2v = scal[1] + 1e-4f, s3 = scal[2] + 1e-4f;
    float w0 = wv[h * 3], w1 = wv[h * 3 + 1], w2 = wv[h * 3 + 2];
    float addc = w2 * (vc / s3) * 0.3f;
    float fc1 = w0 / s1;
    float fc2 = w1 * 0.3f / s2v;
    const float covscale = 0.001f / 1024.0f;
    double sd = 0, s2d = 0;
    float mx = -1e30f;
    for (int m = threadIdx.x; m < NT; m += 256) {
        float r = R[m];
        float nkv = nk[hq * NT + m], skv = sk[hq * NT + m];
        float cosv = fminf(fmaxf(r / (c1 * (nkv + 1e-6f)), -0.95f), 0.95f);
        float cp = (r - tv - muv * skv + muv * uv) / 8.0001f;
        float cov = fminf(fmaxf(covscale * cp, -50.0f), 50.0f);
        float d = fc1 * cosv + fc2 * cov + addc;
        R[m] = d;
        sd += d; s2d += (double)d * d;
        mx = fmaxf(mx, d);
    }
    for (int o = 32; o > 0; o >>= 1) {
        sd += __shfl_down(sd, o); s2d += __shfl_down(s2d, o);
        mx = fmaxf(mx, __shfl_down(mx, o));
    }
    __shared__ float wmx[4];
    int wid = threadIdx.x >> 6, lane = threadIdx.x & 63;
    if (lane == 0) {
        atomicAdd(&acc[6], sd); atomicAdd(&acc[7], s2d);
        wmx[wid] = mx;
    }
    __syncthreads();
    if (threadIdx.x == 0)
        rmax[row] = fmaxf(fmaxf(wmx[0], wmx[1]), fmaxf(wmx[2], wmx[3]));
}

__global__ void k_fin2(const double* acc, float* scal) {
    const double cnt = 33554432.0;
    float ds = (float)sqrt(fmax(0.0, (acc[7] - acc[6] * acc[6] / cnt) / (cnt - 1.0)));
    float temp = (ds < 1e-5f) ? 0.01f : ((ds < 1e-3f) ? 0.05f : (0.2f + ds * 2.0f));
    temp = fminf(fmaxf(temp, 0.01f), 8.0f);
    scal[3] = temp;
}

// softmax rows of dots (in place)
__global__ __launch_bounds__(256) void k_softmax(float* __restrict__ raw,
        const float* __restrict__ rmax, const float* __restrict__ scal) {
    int row = blockIdx.x;
    float* R = raw + (size_t)row * NT;
    float inv = 1.0f / scal[3];
    float mx = rmax[row];
    int t = threadIdx.x;
    float e0 = expf((R[t] - mx) * inv);
    float e1 = expf((R[t + 256] - mx) * inv);
    float e2 = expf((R[t + 512] - mx) * inv);
    float e3 = expf((R[t + 768] - mx) * inv);
    float s = e0 + e1 + e2 + e3;
    for (int o = 32; o > 0; o >>= 1) s += __shfl_down(s, o);
    __shared__ float ws_[4];
    if ((t & 63) == 0) ws_[t >> 6] = s;
    __syncthreads();
    float tot = ws_[0] + ws_[1] + ws_[2] + ws_[3];
    float invtot = 1.0f / tot;
    R[t] = e0 * invtot; R[t + 256] = e1 * invtot;
    R[t + 512] = e2 * invtot; R[t + 768] = e3 * invtot;
}

// batched attnv = attn @ fv  (32 x 1024x1024x64)
__global__ __launch_bounds__(256) void k_pv(const float* __restrict__ attn,
        const float* __restrict__ fv, float* __restrict__ av) {
    int hq = blockIdx.y;
    int n0 = blockIdx.x * 64;
    __shared__ float Ps[64][65];
    __shared__ float Vs[64][65];
    const float* A = attn + (size_t)hq * NT * NT;
    const float* V = fv + (size_t)hq * NT * DHD;
    int t = threadIdx.x;
    int ti = t >> 4, tj = t & 15;
    float acc[4][4] = {};
    for (int k0 = 0; k0 < NT; k0 += 64) {
        for (int i = t; i < 4096; i += 256) {
            int r = i >> 6, c = i & 63;
            Ps[r][c] = A[(size_t)(n0 + r) * NT + k0 + c];
            Vs[r][c] = V[(size_t)(k0 + r) * DHD + c];
        }
        __syncthreads();
        for (int kk = 0; kk < 64; ++kk) {
            float av4[4], bv[4];
            for (int i = 0; i < 4; ++i) av4[i] = Ps[ti * 4 + i][kk];
            for (int j = 0; j < 4; ++j) bv[j] = Vs[kk][tj * 4 + j];
            for (int i = 0; i < 4; ++i)
                for (int j = 0; j < 4; ++j) acc[i][j] += av4[i] * bv[j];
        }
        __syncthreads();
    }
    for (int i = 0; i < 4; ++i)
        for (int j = 0; j < 4; ++j)
            av[((size_t)hq * NT + n0 + ti * 4 + i) * DHD + tj * 4 + j] = acc[i][j];
}

// out = gather(attnv) @ W_out + b_out
__global__ __launch_bounds__(256) void k_out(const float* __restrict__ av,
        const float* __restrict__ Wout, const float* __restrict__ bout,
        float* __restrict__ out) {
    int tok = blockIdx.x;
    int qi = tok >> 10, n = tok & 1023;
    __shared__ float xs[DIMM];
    int t = threadIdx.x;
    for (int j = t; j < DIMM; j += 256)
        xs[j] = av[((size_t)((j >> 6) * QB + qi) * NT + n) * DHD + (j & 63)];
    __syncthreads();
    float a0 = bout[t], a1 = bout[t + 256];
    for (int d = 0; d < DIMM; ++d) {
        float xv = xs[d];
        a0 += xv * Wout[d * DIMM + t];
        a1 += xv * Wout[d * DIMM + t + 256];
    }
    out[(size_t)tok * DIMM + t] = a0;
    out[(size_t)tok * DIMM + t + 256] = a1;
}

extern "C" void kernel_launch(void* const* d_in, const int* in_sizes, int n_in,
                              void* d_out, int out_size, void* d_ws, size_t ws_size,
                              hipStream_t stream) {
    const float* q     = (const float*)d_in[0];
    const float* k     = (const float*)d_in[1];
    const float* v     = (const float*)d_in[2];
    const float* ln_w  = (const float*)d_in[3];
    const float* ln_b  = (const float*)d_in[4];
    const float* W_in  = (const float*)d_in[5];
    const float* W_out = (const float*)d_in[6];
    const float* b_out = (const float*)d_in[7];
    const float* wp_W1 = (const float*)d_in[8];
    const float* wp_b1 = (const float*)d_in[9];
    const float* wp_lw = (const float*)d_in[10];
    const float* wp_lb = (const float*)d_in[11];
    const float* wp_W2 = (const float*)d_in[12];
    const float* wp_b2 = (const float*)d_in[13];
    const float* wp_W3 = (const float*)d_in[14];
    const float* wp_b3 = (const float*)d_in[15];
    const float* wp_W4 = (const float*)d_in[16];
    const float* wp_b4 = (const float*)d_in[17];
    const float* wtemp = (const float*)d_in[18];

    float* ws = (float*)d_ws;
    float* fq    = ws + OFF_FQ;
    float* fk    = ws + OFF_FK;
    float* fv    = ws + OFF_FV;
    float* raw   = ws + OFF_RAW;
    float* nq    = ws + OFF_NQ;
    float* muq   = ws + OFF_MUQ;
    float* tn    = ws + OFF_TN;
    float* nk    = ws + OFF_NK;
    float* sk    = ws + OFF_SK;
    float* vcrow = ws + OFF_VC;
    float* rmax  = ws + OFF_RMAX;
    float* nu    = ws + OFF_NU;
    float* uu    = ws + OFF_UU;
    float* feat  = ws + OFF_FEAT;
    float* wv    = ws + OFF_WV;
    float* scal  = ws + OFF_SCAL;
    double* acc  = (double*)(ws + OFF_ACC);

    k_zero<<<1, 64, 0, stream>>>(acc);
    k_proj<<<4096, 256, 0, stream>>>(q, ln_w, ln_b, W_in, fq);
    k_proj<<<4096, 256, 0, stream>>>(k, ln_w, ln_b, W_in, fk);
    k_proj<<<4096, 256, 0, stream>>>(v, ln_w, ln_b, W_in, fv);
    k_rowstats<<<dim3(8192, 2), 256, 0, stream>>>(fq, fk, nq, muq, nk, sk);
    k_colmean<<<32, 64, 0, stream>>>(fk, nu, uu);
    k_tn<<<8192, 256, 0, stream>>>(fq, nu, tn);
    k_feat<<<8, 64, 0, stream>>>(fq, fk, feat);
    k_mlp<<<1, 256, 0, stream>>>(feat, wp_W1, wp_b1, wp_lw, wp_lb,
                                 wp_W2, wp_b2, wp_W3, wp_b3, wp_W4, wp_b4,
                                 wtemp, wv);
    k_qkt<<<dim3(16, 16, 32), 256, 0, stream>>>(fq, fk, raw);
    k_passb<<<32768, 256, 0, stream>>>(raw, nq, muq, tn, nk, sk, uu, vcrow, acc);
    k_fin1<<<1, 1, 0, stream>>>(acc, scal);
    k_passd<<<32768, 256, 0, stream>>>(raw, nq, muq, tn, nk, sk, uu, vcrow, wv,
                                       scal, rmax, acc);
    k_fin2<<<1, 1, 0, stream>>>(acc, scal);
    k_softmax<<<32768, 256, 0, stream>>>(raw, rmax, scal);
    k_pv<<<dim3(16, 32), 256, 0, stream>>>(raw, fv, fq);
    k_out<<<4096, 256, 0, stream>>>(fq, W_out, b_out, (float*)d_out);
}

// Round 2
// 973.900 us; speedup vs baseline: 11.6394x; 11.6394x over previous
//
#include <hip/hip_runtime.h>
#include <math.h>

#define NT 1024
#define DHD 64

// ---------------- workspace layout (float offsets) ----------------
#define OFF_FQ    0u
#define OFF_FK    2097152u
#define OFF_FV    4194304u
#define OFF_RAW   6291456u    // 33554432 floats; mu/rstd live here pre-QKT
#define OFF_NQ    39845888u
#define OFF_MUQ   39878656u
#define OFF_TN    39911424u
#define OFF_NK    39944192u
#define OFF_SK    39976960u
#define OFF_VC    40009728u
#define OFF_PB    40042496u   // 32768 floats: qkt partials; reused as rmax after fin1
#define OFF_PB2   40075264u   // 2048 floats: passd partials (shares with nu, dead after k_tn)
#define OFF_UU    40077312u   // 32
#define OFF_FEAT  40077344u   // 1024
#define OFF_WV    40078368u   // 24
#define OFF_SCAL  40078392u   // 8

__global__ void k_zero2(float* vcrow, float* feat) {
    int i = blockIdx.x * 256 + threadIdx.x;
    if (i < 32768) vcrow[i] = 0.0f;
    if (i < 1024) feat[i] = 0.0f;
}

// per-token LN stats (mu, rstd) for q,k,v
__global__ __launch_bounds__(256) void k_lnstats(const float* __restrict__ q,
        const float* __restrict__ k, const float* __restrict__ v,
        float* __restrict__ mu, float* __restrict__ rstd) {
    int t = threadIdx.x;
    int wid = t >> 6, lane = t & 63;
    int token = blockIdx.x * 4 + wid;            // 0..12287
    int inp = token >> 12;
    int lt = token & 4095;
    const float* xp = (inp == 0) ? q : ((inp == 1) ? k : v);
    const float4* xr = (const float4*)(xp + (size_t)lt * 512);
    float4 a = xr[lane], b = xr[lane + 64];
    float s = a.x + a.y + a.z + a.w + b.x + b.y + b.z + b.w;
    float s2 = a.x*a.x + a.y*a.y + a.z*a.z + a.w*a.w
             + b.x*b.x + b.y*b.y + b.z*b.z + b.w*b.w;
    for (int o = 32; o > 0; o >>= 1) { s += __shfl_down(s, o); s2 += __shfl_down(s2, o); }
    if (lane == 0) {
        float m_ = s / 512.0f;
        float var = s2 / 512.0f - m_ * m_;
        if (var < 0.0f) var = 0.0f;
        mu[token] = m_;
        rstd[token] = rsqrtf(var + 1e-5f);
    }
}

// [4096 tok x 512] = LN(x) @ Win, tiled 64x64, scatter to f[hq][n][d]
__global__ __launch_bounds__(256) void k_proj(const float* __restrict__ x,
        const float* __restrict__ mu, const float* __restrict__ rstd,
        const float* __restrict__ lnw, const float* __restrict__ lnb,
        const float* __restrict__ Win, float* __restrict__ fout) {
    __shared__ float As[64][68];
    __shared__ float Bt[64][68];
    int col0 = blockIdx.x * 64, tok0 = blockIdx.y * 64;
    int t = threadIdx.x;
    int ti = t >> 4, tj = t & 15;
    float acc[4][4] = {};
    for (int k0 = 0; k0 < 512; k0 += 64) {
        #pragma unroll
        for (int p = 0; p < 4; ++p) {
            int flat = p * 1024 + t * 4;
            int r = flat >> 6, c0 = flat & 63;
            int tok = tok0 + r;
            float4 g = *(const float4*)&x[(size_t)tok * 512 + k0 + c0];
            float4 w = *(const float4*)&lnw[k0 + c0];
            float4 bb = *(const float4*)&lnb[k0 + c0];
            float m_ = mu[tok], rs = rstd[tok];
            float4 a;
            a.x = (g.x - m_) * rs * w.x + bb.x;
            a.y = (g.y - m_) * rs * w.y + bb.y;
            a.z = (g.z - m_) * rs * w.z + bb.z;
            a.w = (g.w - m_) * rs * w.w + bb.w;
            *(float4*)&As[r][c0] = a;
            float4 gb = *(const float4*)&Win[(size_t)(k0 + r) * 512 + col0 + c0];
            Bt[c0 + 0][r] = gb.x; Bt[c0 + 1][r] = gb.y;
            Bt[c0 + 2][r] = gb.z; Bt[c0 + 3][r] = gb.w;
        }
        __syncthreads();
        #pragma unroll
        for (int d = 0; d < 64; d += 4) {
            float4 aa[4], bb4[4];
            #pragma unroll
            for (int i = 0; i < 4; ++i) aa[i] = *(const float4*)&As[ti * 4 + i][d];
            #pragma unroll
            for (int j = 0; j < 4; ++j) bb4[j] = *(const float4*)&Bt[tj + 16 * j][d];
            #pragma unroll
            for (int i = 0; i < 4; ++i)
                #pragma unroll
                for (int j = 0; j < 4; ++j)
                    acc[i][j] += aa[i].x * bb4[j].x + aa[i].y * bb4[j].y
                               + aa[i].z * bb4[j].z + aa[i].w * bb4[j].w;
        }
        __syncthreads();
    }
    int head4 = (col0 >> 6) * 4;
    #pragma unroll
    for (int i = 0; i < 4; ++i) {
        int tok = tok0 + ti * 4 + i;
        int qi = tok >> 10, n = tok & 1023;
        float* dst = fout + ((size_t)(head4 + qi) * NT + n) * 64;
        dst[tj]      = acc[i][0];
        dst[tj + 16] = acc[i][1];
        dst[tj + 32] = acc[i][2];
        dst[tj + 48] = acc[i][3];
    }
}

// per-row norms / means / sums for fq and fk
__global__ __launch_bounds__(256) void k_rowstats(const float* __restrict__ fq,
        const float* __restrict__ fk, float* nq, float* muq, float* nk, float* sk) {
    int row = blockIdx.x * 4 + (threadIdx.x >> 6);
    int lane = threadIdx.x & 63;
    const float* f = (blockIdx.y == 0) ? fq : fk;
    float v = f[(size_t)row * DHD + lane];
    float s = v, s2 = v * v;
    for (int o = 32; o > 0; o >>= 1) { s += __shfl_down(s, o); s2 += __shfl_down(s2, o); }
    if (lane == 0) {
        if (blockIdx.y == 0) { nq[row] = sqrtf(s2); muq[row] = s / 64.0f; }
        else                 { nk[row] = sqrtf(s2); sk[row] = s; }
    }
}

// per-(hq) column mean of fk over tokens (nu), and u = sum_d nu
__global__ __launch_bounds__(64) void k_colmean(const float* __restrict__ fk,
        float* nu, float* uu) {
    int hq = blockIdx.x; int d = threadIdx.x;
    const float* base = fk + (size_t)hq * NT * DHD;
    float s = 0.0f;
    for (int m = 0; m < NT; ++m) s += base[m * DHD + d];
    float nud = s / (float)NT;
    nu[hq * DHD + d] = nud;
    float tsum = nud;
    for (int o = 32; o > 0; o >>= 1) tsum += __shfl_down(tsum, o);
    if (d == 0) uu[hq] = tsum;
}

// t_n = fq_row . nu
__global__ __launch_bounds__(256) void k_tn(const float* __restrict__ fq,
        const float* __restrict__ nu, float* tn) {
    int row = blockIdx.x * 4 + (threadIdx.x >> 6);
    int lane = threadIdx.x & 63;
    int hq = row >> 10;
    float p = fq[(size_t)row * DHD + lane] * nu[hq * DHD + lane];
    for (int o = 32; o > 0; o >>= 1) p += __shfl_down(p, o);
    if (lane == 0) tn[row] = p;
}

// feat accumulation: grid (16 chunks, 8 heads)
__global__ __launch_bounds__(256) void k_featacc(const float* __restrict__ fq,
        const float* __restrict__ fk, float* feat) {
    __shared__ float l1[4][64], l2[4][64];
    int h = blockIdx.y, chunk = blockIdx.x;
    int t = threadIdx.x;
    int d = t & 63, rg = t >> 6;
    const float* bq = fq + (size_t)h * 4096 * 64;
    const float* bk = fk + (size_t)h * 4096 * 64;
    float sq = 0.0f, sk_ = 0.0f;
    for (int rr = 0; rr < 64; ++rr) {
        int idx = chunk * 256 + rg * 64 + rr;
        sq  += bq[(size_t)idx * 64 + d];
        sk_ += bk[(size_t)idx * 64 + d];
    }
    l1[rg][d] = sq; l2[rg][d] = sk_;
    __syncthreads();
    if (t < 64) {
        float a = l1[0][t] + l1[1][t] + l1[2][t] + l1[3][t];
        float b = l2[0][t] + l2[1][t] + l2[2][t] + l2[3][t];
        atomicAdd(&feat[h * 128 + t], a * (1.0f / 4096.0f));
        atomicAdd(&feat[h * 128 + 64 + t], b * (1.0f / 4096.0f));
    }
}

// tiny MLP weight predictor -> wv[h][3]
__global__ __launch_bounds__(256) void k_mlp(const float* __restrict__ feat,
        const float* __restrict__ W1, const float* __restrict__ b1,
        const float* __restrict__ lw, const float* __restrict__ lb,
        const float* __restrict__ W2, const float* __restrict__ b2,
        const float* __restrict__ W3, const float* __restrict__ b3,
        const float* __restrict__ W4, const float* __restrict__ b4,
        const float* __restrict__ wtemp, float* wv) {
    __shared__ float h1[256], h2[192], h3[64], red[8];
    int t = threadIdx.x;
    for (int h = 0; h < 8; ++h) {
        float p = 0.0f;
        for (int i = 0; i < 128; ++i) p += feat[h * 128 + i] * W1[i * 256 + t];
        p += b1[t];
        float s = p, s2 = p * p;
        for (int o = 32; o > 0; o >>= 1) { s += __shfl_down(s, o); s2 += __shfl_down(s2, o); }
        if ((t & 63) == 0) { red[t >> 6] = s; red[4 + (t >> 6)] = s2; }
        __syncthreads();
        float S = red[0] + red[1] + red[2] + red[3];
        float S2 = red[4] + red[5] + red[6] + red[7];
        float mu = S / 256.0f;
        float var = S2 / 256.0f - mu * mu; if (var < 0.0f) var = 0.0f;
        float xh = (p - mu) * rsqrtf(var + 1e-5f) * lw[t] + lb[t];
        h1[t] = fmaxf(xh, 0.0f);
        __syncthreads();
        if (t < 192) {
            float a = 0.0f;
            for (int i = 0; i < 256; ++i) a += h1[i] * W2[i * 192 + t];
            h2[t] = fmaxf(a + b2[t], 0.0f);
        }
        __syncthreads();
        if (t < 64) {
            float a = 0.0f;
            for (int i = 0; i < 192; ++i) a += h2[i] * W3[i * 64 + t];
            h3[t] = fmaxf(a + b3[t], 0.0f);
        }
        __syncthreads();
        if (t == 0) {
            float lg[3];
            for (int j = 0; j < 3; ++j) {
                float a = 0.0f;
                for (int i = 0; i < 64; ++i) a += h3[i] * W4[i * 3 + j];
                lg[j] = a + b4[j];
            }
            float mx = fmaxf(lg[0], fmaxf(lg[1], lg[2]));
            float e0 = expf(lg[0] - mx), e1 = expf(lg[1] - mx), e2 = expf(lg[2] - mx);
            float se = e0 + e1 + e2;
            float pr0 = e0 / se, pr1 = e1 / se, pr2 = e2 / se;
            float wt = wtemp[0]; wt = fminf(fmaxf(wt, 0.01f), 1.0f);
            float q0 = pr0 / wt, q1 = pr1 / wt, q2 = pr2 / wt;
            float m2 = fmaxf(q0, fmaxf(q1, q2));
            float f0 = expf(q0 - m2), f1 = expf(q1 - m2), f2 = expf(q2 - m2);
            float sf = f0 + f1 + f2; f0 /= sf; f1 /= sf; f2 /= sf;
            f0 = fminf(fmaxf(f0, 0.01f), 0.95f);
            f1 = fminf(fmaxf(f1, 0.01f), 0.95f);
            f2 = fminf(fmaxf(f2, 0.01f), 0.95f);
            float sw = f0 + f1 + f2;
            wv[h * 3 + 0] = f0 / sw; wv[h * 3 + 1] = f1 / sw; wv[h * 3 + 2] = f2 / sw;
        }
        __syncthreads();
    }
}

// QK^T (64x64 tile) fused with pass-B statistics
__global__ __launch_bounds__(256) void k_qkt(const float* __restrict__ fq,
        const float* __restrict__ fk,
        const float* __restrict__ nq, const float* __restrict__ muq,
        const float* __restrict__ tn, const float* __restrict__ nk,
        const float* __restrict__ sk, const float* __restrict__ uu,
        float* __restrict__ raw, float* __restrict__ vcrow,
        float* __restrict__ pb) {
    __shared__ float As[64][68];
    __shared__ float Bs[64][68];
    __shared__ float rsum[4][4];
    int hq = blockIdx.z;
    int m0 = blockIdx.x * 64, n0 = blockIdx.y * 64;
    const float* A = fq + (size_t)hq * NT * 64;
    const float* B = fk + (size_t)hq * NT * 64;
    int t = threadIdx.x;
    int ti = t >> 4, tj = t & 15;
    #pragma unroll
    for (int p = 0; p < 4; ++p) {
        int flat = p * 1024 + t * 4;
        int r = flat >> 6, c0 = flat & 63;
        *(float4*)&As[r][c0] = *(const float4*)&A[(size_t)(n0 + r) * 64 + c0];
        *(float4*)&Bs[r][c0] = *(const float4*)&B[(size_t)(m0 + r) * 64 + c0];
    }
    __syncthreads();
    float acc[4][4] = {};
    #pragma unroll
    for (int d = 0; d < 64; d += 4) {
        float4 aa[4], bb4[4];
        #pragma unroll
        for (int i = 0; i < 4; ++i) aa[i] = *(const float4*)&As[ti * 4 + i][d];
        #pragma unroll
        for (int j = 0; j < 4; ++j) bb4[j] = *(const float4*)&Bs[tj + 16 * j][d];
        #pragma unroll
        for (int i = 0; i < 4; ++i)
            #pragma unroll
            for (int j = 0; j < 4; ++j)
                acc[i][j] += aa[i].x * bb4[j].x + aa[i].y * bb4[j].y
                           + aa[i].z * bb4[j].z + aa[i].w * bb4[j].w;
    }
    // fused pass-B epilogue
    float uv = uu[hq];
    const float covscale = 0.001f / 1024.0f;
    float nkv[4], skv[4];
    #pragma unroll
    for (int j = 0; j < 4; ++j) {
        int cg = hq * NT + m0 + tj + 16 * j;
        nkv[j] = nk[cg]; skv[j] = sk[cg];
    }
    float scos = 0.f, s2cos = 0.f, scov = 0.f, s2cov = 0.f;
    #pragma unroll
    for (int i = 0; i < 4; ++i) {
        int rg = hq * NT + n0 + ti * 4 + i;
        float nqv = nq[rg], muv = muq[rg], tv = tn[rg];
        float c1 = nqv + 1e-6f;
        float c2 = fmaxf(nqv, 1e-4f);
        float mrow = 0.f;
        float* R = raw + (size_t)rg * NT + m0;
        #pragma unroll
        for (int j = 0; j < 4; ++j) {
            float r = acc[i][j];
            float cosv = fminf(fmaxf(r / (c1 * (nkv[j] + 1e-6f)), -0.95f), 0.95f);
            float cs = fminf(fmaxf(r / (c2 * fmaxf(nkv[j], 1e-4f)), -0.95f), 0.95f);
            float marg = fminf(fmaxf(0.01f - cs, 0.0f), 15.0f);
            float cp = (r - tv - muv * skv[j] + muv * uv) / 8.0001f;
            float cov = fminf(fmaxf(covscale * cp, -50.0f), 50.0f);
            scos += cosv; s2cos += cosv * cosv;
            scov += cov;  s2cov += cov * cov;
            mrow += marg;
            R[tj + 16 * j] = r;
        }
        mrow += __shfl_down(mrow, 8, 16);
        mrow += __shfl_down(mrow, 4, 16);
        mrow += __shfl_down(mrow, 2, 16);
        mrow += __shfl_down(mrow, 1, 16);
        if (tj == 0) atomicAdd(&vcrow[rg], mrow);
    }
    for (int o = 32; o > 0; o >>= 1) {
        scos += __shfl_down(scos, o); s2cos += __shfl_down(s2cos, o);
        scov += __shfl_down(scov, o); s2cov += __shfl_down(s2cov, o);
    }
    int wid = t >> 6, lane = t & 63;
    if (lane == 0) { rsum[wid][0] = scos; rsum[wid][1] = s2cos;
                     rsum[wid][2] = scov; rsum[wid][3] = s2cov; }
    __syncthreads();
    if (t == 0) {
        int bid = (blockIdx.z * 16 + blockIdx.y) * 16 + blockIdx.x;
        pb[bid * 4 + 0] = rsum[0][0] + rsum[1][0] + rsum[2][0] + rsum[3][0];
        pb[bid * 4 + 1] = rsum[0][1] + rsum[1][1] + rsum[2][1] + rsum[3][1];
        pb[bid * 4 + 2] = rsum[0][2] + rsum[1][2] + rsum[2][2] + rsum[3][2];
        pb[bid * 4 + 3] = rsum[0][3] + rsum[1][3] + rsum[2][3] + rsum[3][3];
    }
}

__global__ __launch_bounds__(256) void k_fin1(const float* __restrict__ pb,
        const float* __restrict__ vcrow, float* __restrict__ scal) {
    int t = threadIdx.x;
    double s0 = 0, s1 = 0, s2 = 0, s3 = 0, s4 = 0, s5 = 0;
    for (int i = t; i < 8192; i += 256) {
        s0 += pb[i * 4 + 0]; s1 += pb[i * 4 + 1];
        s2 += pb[i * 4 + 2]; s3 += pb[i * 4 + 3];
    }
    for (int i = t; i < 32768; i += 256) {
        double rm = (double)vcrow[i] * (1.0 / 1024.0);
        s4 += rm; s5 += rm * rm;
    }
    for (int o = 32; o > 0; o >>= 1) {
        s0 += __shfl_down(s0, o); s1 += __shfl_down(s1, o); s2 += __shfl_down(s2, o);
        s3 += __shfl_down(s3, o); s4 += __shfl_down(s4, o); s5 += __shfl_down(s5, o);
    }
    __shared__ double red[6][4];
    int wid = t >> 6, lane = t & 63;
    if (lane == 0) { red[0][wid] = s0; red[1][wid] = s1; red[2][wid] = s2;
                     red[3][wid] = s3; red[4][wid] = s4; red[5][wid] = s5; }
    __syncthreads();
    if (t == 0) {
        double S0 = red[0][0] + red[0][1] + red[0][2] + red[0][3];
        double S1 = red[1][0] + red[1][1] + red[1][2] + red[1][3];
        double S2 = red[2][0] + red[2][1] + red[2][2] + red[2][3];
        double S3 = red[3][0] + red[3][1] + red[3][2] + red[3][3];
        double S4 = red[4][0] + red[4][1] + red[4][2] + red[4][3];
        double S5 = red[5][0] + red[5][1] + red[5][2] + red[5][3];
        const double cnt = 33554432.0;
        scal[0] = (float)sqrt(fmax(0.0, (S1 - S0 * S0 / cnt) / (cnt - 1.0)));
        scal[1] = (float)sqrt(fmax(0.0, (S3 - S2 * S2 / cnt) / (cnt - 1.0)));
        double V4 = S4 * 1024.0, V5 = S5 * 1024.0;
        scal[2] = (float)sqrt(fmax(0.0, (V5 - V4 * V4 / cnt) / (cnt - 1.0)));
    }
}

// dots in place over raw + global sum/sumsq partials + row max
__global__ __launch_bounds__(256) void k_passd(float* __restrict__ raw,
        const float* __restrict__ nq, const float* __restrict__ muq,
        const float* __restrict__ tn, const float* __restrict__ nk,
        const float* __restrict__ sk, const float* __restrict__ uu,
        const float* __restrict__ vcrow, const float* __restrict__ wv,
        const float* __restrict__ scal, float* __restrict__ rmax,
        float* __restrict__ pb2) {
    int t = threadIdx.x;
    float s1 = scal[0] + 1e-4f, s2v = scal[1] + 1e-4f, s3 = scal[2] + 1e-4f;
    const float covscale = 0.001f / 1024.0f;
    float sd = 0.f, s2d = 0.f;
    __shared__ float wred[4];
    __shared__ float fr[2][4];
    for (int row = blockIdx.x; row < 32768; row += 1024) {
        int hq = row >> 10, h = hq >> 2;
        float4* R4 = (float4*)(raw + (size_t)row * NT);
        const float4* nk4 = (const float4*)(nk + hq * NT);
        const float4* sk4 = (const float4*)(sk + hq * NT);
        float nqv = nq[row], muv = muq[row], tv = tn[row], uv = uu[hq];
        float c1 = nqv + 1e-6f;
        float vc = vcrow[row] * (1.0f / 1024.0f);
        float w0 = wv[h * 3], w1 = wv[h * 3 + 1], w2 = wv[h * 3 + 2];
        float addc = w2 * (vc / s3) * 0.3f;
        float fc1 = w0 / s1;
        float fc2 = w1 * 0.3f / s2v;
        float4 r = R4[t], nn = nk4[t], ss = sk4[t];
        float4 dd;
        dd.x = fc1 * fminf(fmaxf(r.x / (c1 * (nn.x + 1e-6f)), -0.95f), 0.95f)
             + fc2 * fminf(fmaxf(covscale * ((r.x - tv - muv * ss.x + muv * uv) / 8.0001f), -50.f), 50.f) + addc;
        dd.y = fc1 * fminf(fmaxf(r.y / (c1 * (nn.y + 1e-6f)), -0.95f), 0.95f)
             + fc2 * fminf(fmaxf(covscale * ((r.y - tv - muv * ss.y + muv * uv) / 8.0001f), -50.f), 50.f) + addc;
        dd.z = fc1 * fminf(fmaxf(r.z / (c1 * (nn.z + 1e-6f)), -0.95f), 0.95f)
             + fc2 * fminf(fmaxf(covscale * ((r.z - tv - muv * ss.z + muv * uv) / 8.0001f), -50.f), 50.f) + addc;
        dd.w = fc1 * fminf(fmaxf(r.w / (c1 * (nn.w + 1e-6f)), -0.95f), 0.95f)
             + fc2 * fminf(fmaxf(covscale * ((r.w - tv - muv * ss.w + muv * uv) / 8.0001f), -50.f), 50.f) + addc;
        R4[t] = dd;
        sd += dd.x + dd.y + dd.z + dd.w;
        s2d += dd.x * dd.x + dd.y * dd.y + dd.z * dd.z + dd.w * dd.w;
        float mx = fmaxf(fmaxf(dd.x, dd.y), fmaxf(dd.z, dd.w));
        for (int o = 32; o > 0; o >>= 1) mx = fmaxf(mx, __shfl_down(mx, o));
        if ((t & 63) == 0) wred[t >> 6] = mx;
        __syncthreads();
        if (t == 0) rmax[row] = fmaxf(fmaxf(wred[0], wred[1]), fmaxf(wred[2], wred[3]));
        __syncthreads();
    }
    for (int o = 32; o > 0; o >>= 1) { sd += __shfl_down(sd, o); s2d += __shfl_down(s2d, o); }
    int wid = t >> 6, lane = t & 63;
    if (lane == 0) { fr[0][wid] = sd; fr[1][wid] = s2d; }
    __syncthreads();
    if (t == 0) {
        pb2[blockIdx.x * 2 + 0] = fr[0][0] + fr[0][1] + fr[0][2] + fr[0][3];
        pb2[blockIdx.x * 2 + 1] = fr[1][0] + fr[1][1] + fr[1][2] + fr[1][3];
    }
}

__global__ __launch_bounds__(256) void k_fin2(const float* __restrict__ pb2,
        float* __restrict__ scal) {
    int t = threadIdx.x;
    double s6 = 0, s7 = 0;
    for (int i = t; i < 1024; i += 256) { s6 += pb2[i * 2]; s7 += pb2[i * 2 + 1]; }
    for (int o = 32; o > 0; o >>= 1) { s6 += __shfl_down(s6, o); s7 += __shfl_down(s7, o); }
    __shared__ double red[2][4];
    int wid = t >> 6, lane = t & 63;
    if (lane == 0) { red[0][wid] = s6; red[1][wid] = s7; }
    __syncthreads();
    if (t == 0) {
        double S6 = red[0][0] + red[0][1] + red[0][2] + red[0][3];
        double S7 = red[1][0] + red[1][1] + red[1][2] + red[1][3];
        const double cnt = 33554432.0;
        double ds = sqrt(fmax(0.0, (S7 - S6 * S6 / cnt) / (cnt - 1.0)));
        float temp = (ds < 1e-5) ? 0.01f : ((ds < 1e-3) ? 0.05f : (0.2f + (float)ds * 2.0f));
        temp = fminf(fmaxf(temp, 0.01f), 8.0f);
        scal[3] = temp;
    }
}

__global__ __launch_bounds__(256) void k_softmax(float* __restrict__ raw,
        const float* __restrict__ rmax, const float* __restrict__ scal) {
    int t = threadIdx.x;
    float inv = 1.0f / scal[3];
    __shared__ float wsum[4];
    for (int row = blockIdx.x; row < 32768; row += 2048) {
        float4* R4 = (float4*)(raw + (size_t)row * NT);
        float mx = rmax[row];
        float4 r = R4[t];
        float4 e;
        e.x = expf((r.x - mx) * inv);
        e.y = expf((r.y - mx) * inv);
        e.z = expf((r.z - mx) * inv);
        e.w = expf((r.w - mx) * inv);
        float s = e.x + e.y + e.z + e.w;
        for (int o = 32; o > 0; o >>= 1) s += __shfl_down(s, o);
        if ((t & 63) == 0) wsum[t >> 6] = s;
        __syncthreads();
        float itot = 1.0f / (wsum[0] + wsum[1] + wsum[2] + wsum[3]);
        e.x *= itot; e.y *= itot; e.z *= itot; e.w *= itot;
        R4[t] = e;
        __syncthreads();
    }
}

// attnv = attn @ fv, 64x64 tiles
__global__ __launch_bounds__(256) void k_pv(const float* __restrict__ attn,
        const float* __restrict__ fv, float* __restrict__ av) {
    __shared__ float Ps[64][68];
    __shared__ float Vt[64][68];
    int hq = blockIdx.y;
    int n0 = blockIdx.x * 64;
    const float* A = attn + (size_t)hq * NT * NT;
    const float* V = fv + (size_t)hq * NT * 64;
    int t = threadIdx.x;
    int ti = t >> 4, tj = t & 15;
    float acc[4][4] = {};
    for (int k0 = 0; k0 < NT; k0 += 64) {
        #pragma unroll
        for (int p = 0; p < 4; ++p) {
            int flat = p * 1024 + t * 4;
            int r = flat >> 6, c0 = flat & 63;
            *(float4*)&Ps[r][c0] = *(const float4*)&A[(size_t)(n0 + r) * NT + k0 + c0];
            float4 g = *(const float4*)&V[(size_t)(k0 + r) * 64 + c0];
            Vt[c0 + 0][r] = g.x; Vt[c0 + 1][r] = g.y;
            Vt[c0 + 2][r] = g.z; Vt[c0 + 3][r] = g.w;
        }
        __syncthreads();
        #pragma unroll
        for (int d = 0; d < 64; d += 4) {
            float4 aa[4], bb4[4];
            #pragma unroll
            for (int i = 0; i < 4; ++i) aa[i] = *(const float4*)&Ps[ti * 4 + i][d];
            #pragma unroll
            for (int j = 0; j < 4; ++j) bb4[j] = *(const float4*)&Vt[tj + 16 * j][d];
            #pragma unroll
            for (int i = 0; i < 4; ++i)
                #pragma unroll
                for (int j = 0; j < 4; ++j)
                    acc[i][j] += aa[i].x * bb4[j].x + aa[i].y * bb4[j].y
                               + aa[i].z * bb4[j].z + aa[i].w * bb4[j].w;
        }
        __syncthreads();
    }
    #pragma unroll
    for (int i = 0; i < 4; ++i) {
        float* dst = av + ((size_t)hq * NT + n0 + ti * 4 + i) * 64;
        dst[tj]      = acc[i][0];
        dst[tj + 16] = acc[i][1];
        dst[tj + 32] = acc[i][2];
        dst[tj + 48] = acc[i][3];
    }
}

// out = gather(attnv) @ Wout + bout, 64x64 tiles
__global__ __launch_bounds__(256) void k_out(const float* __restrict__ av,
        const float* __restrict__ Wout, const float* __restrict__ bout,
        float* __restrict__ out) {
    __shared__ float As[64][68];
    __shared__ float Bt[64][68];
    int col0 = blockIdx.x * 64, tok0 = blockIdx.y * 64;
    int t = threadIdx.x;
    int ti = t >> 4, tj = t & 15;
    float acc[4][4] = {};
    for (int k0 = 0; k0 < 512; k0 += 64) {
        int hk4 = (k0 >> 6) * 4;
        #pragma unroll
        for (int p = 0; p < 4; ++p) {
            int flat = p * 1024 + t * 4;
            int r = flat >> 6, c0 = flat & 63;
            int tok = tok0 + r, qi = tok >> 10, n = tok & 1023;
            *(float4*)&As[r][c0] = *(const float4*)&av[((size_t)(hk4 + qi) * NT + n) * 64 + c0];
            float4 g = *(const float4*)&Wout[(size_t)(k0 + r) * 512 + col0 + c0];
            Bt[c0 + 0][r] = g.x; Bt[c0 + 1][r] = g.y;
            Bt[c0 + 2][r] = g.z; Bt[c0 + 3][r] = g.w;
        }
        __syncthreads();
        #pragma unroll
        for (int d = 0; d < 64; d += 4) {
            float4 aa[4], bb4[4];
            #pragma unroll
            for (int i = 0; i < 4; ++i) aa[i] = *(const float4*)&As[ti * 4 + i][d];
            #pragma unroll
            for (int j = 0; j < 4; ++j) bb4[j] = *(const float4*)&Bt[tj + 16 * j][d];
            #pragma unroll
            for (int i = 0; i < 4; ++i)
                #pragma unroll
                for (int j = 0; j < 4; ++j)
                    acc[i][j] += aa[i].x * bb4[j].x + aa[i].y * bb4[j].y
                               + aa[i].z * bb4[j].z + aa[i].w * bb4[j].w;
        }
        __syncthreads();
    }
    #pragma unroll
    for (int i = 0; i < 4; ++i) {
        int tok = tok0 + ti * 4 + i;
        float* dst = out + (size_t)tok * 512 + col0;
        dst[tj]      = acc[i][0] + bout[col0 + tj];
        dst[tj + 16] = acc[i][1] + bout[col0 + tj + 16];
        dst[tj + 32] = acc[i][2] + bout[col0 + tj + 32];
        dst[tj + 48] = acc[i][3] + bout[col0 + tj + 48];
    }
}

extern "C" void kernel_launch(void* const* d_in, const int* in_sizes, int n_in,
                              void* d_out, int out_size, void* d_ws, size_t ws_size,
                              hipStream_t stream) {
    const float* q     = (const float*)d_in[0];
    const float* k     = (const float*)d_in[1];
    const float* v     = (const float*)d_in[2];
    const float* ln_w  = (const float*)d_in[3];
    const float* ln_b  = (const float*)d_in[4];
    const float* W_in  = (const float*)d_in[5];
    const float* W_out = (const float*)d_in[6];
    const float* b_out = (const float*)d_in[7];
    const float* wp_W1 = (const float*)d_in[8];
    const float* wp_b1 = (const float*)d_in[9];
    const float* wp_lw = (const float*)d_in[10];
    const float* wp_lb = (const float*)d_in[11];
    const float* wp_W2 = (const float*)d_in[12];
    const float* wp_b2 = (const float*)d_in[13];
    const float* wp_W3 = (const float*)d_in[14];
    const float* wp_b3 = (const float*)d_in[15];
    const float* wp_W4 = (const float*)d_in[16];
    const float* wp_b4 = (const float*)d_in[17];
    const float* wtemp = (const float*)d_in[18];

    float* ws = (float*)d_ws;
    float* fq    = ws + OFF_FQ;
    float* fk    = ws + OFF_FK;
    float* fv    = ws + OFF_FV;
    float* raw   = ws + OFF_RAW;
    float* mu    = ws + OFF_RAW;            // 12288, dead before raw is written
    float* rstd  = ws + OFF_RAW + 12288;    // 12288
    float* nq    = ws + OFF_NQ;
    float* muq   = ws + OFF_MUQ;
    float* tn    = ws + OFF_TN;
    float* nk    = ws + OFF_NK;
    float* sk    = ws + OFF_SK;
    float* vcrow = ws + OFF_VC;
    float* pb    = ws + OFF_PB;
    float* rmax  = ws + OFF_PB;             // reuse after fin1
    float* nu    = ws + OFF_PB2;            // nu dead after k_tn
    float* pb2   = ws + OFF_PB2;
    float* uu    = ws + OFF_UU;
    float* feat  = ws + OFF_FEAT;
    float* wv    = ws + OFF_WV;
    float* scal  = ws + OFF_SCAL;

    k_zero2<<<128, 256, 0, stream>>>(vcrow, feat);
    k_lnstats<<<3072, 256, 0, stream>>>(q, k, v, mu, rstd);
    k_proj<<<dim3(8, 64), 256, 0, stream>>>(q, mu, rstd, ln_w, ln_b, W_in, fq);
    k_proj<<<dim3(8, 64), 256, 0, stream>>>(k, mu + 4096, rstd + 4096, ln_w, ln_b, W_in, fk);
    k_proj<<<dim3(8, 64), 256, 0, stream>>>(v, mu + 8192, rstd + 8192, ln_w, ln_b, W_in, fv);
    k_rowstats<<<dim3(8192, 2), 256, 0, stream>>>(fq, fk, nq, muq, nk, sk);
    k_colmean<<<32, 64, 0, stream>>>(fk, nu, uu);
    k_tn<<<8192, 256, 0, stream>>>(fq, nu, tn);
    k_featacc<<<dim3(16, 8), 256, 0, stream>>>(fq, fk, feat);
    k_mlp<<<1, 256, 0, stream>>>(feat, wp_W1, wp_b1, wp_lw, wp_lb,
                                 wp_W2, wp_b2, wp_W3, wp_b3, wp_W4, wp_b4,
                                 wtemp, wv);
    k_qkt<<<dim3(16, 16, 32), 256, 0, stream>>>(fq, fk, nq, muq, tn, nk, sk, uu,
                                                raw, vcrow, pb);
    k_fin1<<<1, 256, 0, stream>>>(pb, vcrow, scal);
    k_passd<<<1024, 256, 0, stream>>>(raw, nq, muq, tn, nk, sk, uu, vcrow, wv,
                                      scal, rmax, pb2);
    k_fin2<<<1, 256, 0, stream>>>(pb2, scal);
    k_softmax<<<2048, 256, 0, stream>>>(raw, rmax, scal);
    k_pv<<<dim3(16, 32), 256, 0, stream>>>(raw, fv, fq);
    k_out<<<dim3(8, 64), 256, 0, stream>>>(fq, W_out, b_out, (float*)d_out);
}

// Round 3
// 497.169 us; speedup vs baseline: 22.8004x; 1.9589x over previous
//
#include <hip/hip_runtime.h>
#include <math.h>

typedef _Float16 f16;
typedef _Float16 v8h __attribute__((ext_vector_type(8)));
typedef _Float16 v4h __attribute__((ext_vector_type(4)));
typedef float    v4f __attribute__((ext_vector_type(4)));

#define MFMA(a, b, c) __builtin_amdgcn_mfma_f32_16x16x32_f16((a), (b), (c), 0, 0, 0)

// ---------------- workspace layout (float offsets) ----------------
// raw: 33554432 floats. ln16/lnlo live inside raw (dead before qkt writes it).
#define OFF_RAW     0u
#define OFF_LNLO    3145728u     // f16[4096*512] for v tokens (inside raw)
#define OFF_FQ16    33554432u    // f16[2097152]; aliased as avh after qkt
#define OFF_FK16    34603008u    // f16[2097152]; aliased as avl after qkt
#define OFF_FVHT    35651584u    // f16[2097152]  [hq][d][n]
#define OFF_FVLT    36700160u
#define OFF_WINT_H  37748736u    // f16[262144]   [col][k]
#define OFF_WINT_L  37879808u
#define OFF_WOUTT_H 38010880u
#define OFF_WOUTT_L 38141952u
#define OFF_NQ      38273024u
#define OFF_MUQ     38305792u
#define OFF_TN      38338560u
#define OFF_NK      38371328u
#define OFF_SK      38404096u
#define OFF_VC      38436864u
#define OFF_PB      38469632u    // 2048*4
#define OFF_PB2     38477824u    // 2048 (nu aliases, dead after k_tn16)
#define OFF_UU      38479872u
#define OFF_FEAT    38479904u
#define OFF_WV      38480928u
#define OFF_SCAL    38480952u

__global__ void k_zerofeat(float* feat) {
    int i = blockIdx.x * 256 + threadIdx.x;
    if (i < 1024) feat[i] = 0.0f;
}

// transpose + hi/lo split of a 512x512 weight: W[k][c] -> WT{h,l}[c][k]
__global__ __launch_bounds__(256) void k_wprep(const float* __restrict__ Win,
        const float* __restrict__ Wout, f16* __restrict__ WinTh, f16* __restrict__ WinTl,
        f16* __restrict__ WoutTh, f16* __restrict__ WoutTl) {
    __shared__ float lds[64][68];
    const float* W = blockIdx.z ? Wout : Win;
    f16* Th = blockIdx.z ? WoutTh : WinTh;
    f16* Tl = blockIdx.z ? WoutTl : WinTl;
    int k0 = blockIdx.y * 64, c0 = blockIdx.x * 64;
    int t = threadIdx.x;
    #pragma unroll
    for (int p = 0; p < 4; ++p) {
        int flat = p * 1024 + t * 4;
        int r = flat >> 6, c = flat & 63;
        *(float4*)&lds[r][c] = *(const float4*)&W[(size_t)(k0 + r) * 512 + c0 + c];
    }
    __syncthreads();
    int c = t >> 2, kk = (t & 3) * 16;
    #pragma unroll
    for (int half = 0; half < 2; ++half) {
        v8h h8, l8;
        #pragma unroll
        for (int ii = 0; ii < 8; ++ii) {
            float v = lds[kk + half * 8 + ii][c];
            f16 h = (f16)v;
            h8[ii] = h;
            l8[ii] = (f16)(v - (float)h);
        }
        *(v8h*)&Th[(size_t)(c0 + c) * 512 + k0 + kk + half * 8] = h8;
        *(v8h*)&Tl[(size_t)(c0 + c) * 512 + k0 + kk + half * 8] = l8;
    }
}

// LayerNorm all 12288 tokens -> ln16 f16; v tokens also get lo residual
__global__ __launch_bounds__(256) void k_ln16(const float* __restrict__ q,
        const float* __restrict__ kk, const float* __restrict__ v,
        const float* __restrict__ lnw, const float* __restrict__ lnb,
        f16* __restrict__ ln16, f16* __restrict__ lnlo) {
    int t = threadIdx.x, wid = t >> 6, lane = t & 63;
    int token = blockIdx.x * 4 + wid;
    int inp = token >> 12, lt = token & 4095;
    const float* xp = (inp == 0) ? q : ((inp == 1) ? kk : v);
    const float4* xr = (const float4*)(xp + (size_t)lt * 512);
    float4 a = xr[lane], b = xr[lane + 64];
    float s = a.x + a.y + a.z + a.w + b.x + b.y + b.z + b.w;
    float s2 = a.x*a.x + a.y*a.y + a.z*a.z + a.w*a.w
             + b.x*b.x + b.y*b.y + b.z*b.z + b.w*b.w;
    for (int o = 32; o > 0; o >>= 1) { s += __shfl_down(s, o); s2 += __shfl_down(s2, o); }
    float m_ = __shfl(s, 0) * (1.0f / 512.0f);
    float var = __shfl(s2, 0) * (1.0f / 512.0f) - m_ * m_;
    var = fmaxf(var, 0.0f);
    float rs = rsqrtf(var + 1e-5f);
    const float4* w4 = (const float4*)lnw;
    const float4* b4 = (const float4*)lnb;
    float4 wa = w4[lane], wb = w4[lane + 64], ba = b4[lane], bb = b4[lane + 64];
    float ga[4] = { (a.x - m_) * rs * wa.x + ba.x, (a.y - m_) * rs * wa.y + ba.y,
                    (a.z - m_) * rs * wa.z + ba.z, (a.w - m_) * rs * wa.w + ba.w };
    float gb[4] = { (b.x - m_) * rs * wb.x + bb.x, (b.y - m_) * rs * wb.y + bb.y,
                    (b.z - m_) * rs * wb.z + bb.z, (b.w - m_) * rs * wb.w + bb.w };
    f16* orow = ln16 + (size_t)token * 512;
    v4h ha, hb;
    #pragma unroll
    for (int i = 0; i < 4; ++i) { ha[i] = (f16)ga[i]; hb[i] = (f16)gb[i]; }
    *(v4h*)&orow[lane * 4] = ha;
    *(v4h*)&orow[lane * 4 + 256] = hb;
    if (inp == 2) {
        f16* lrow = lnlo + (size_t)lt * 512;
        v4h la, lb;
        #pragma unroll
        for (int i = 0; i < 4; ++i) {
            la[i] = (f16)(ga[i] - (float)ha[i]);
            lb[i] = (f16)(gb[i] - (float)hb[i]);
        }
        *(v4h*)&lrow[lane * 4] = la;
        *(v4h*)&lrow[lane * 4 + 256] = lb;
    }
}

// LN16 @ Win (MFMA). SPLIT=0: q/k, write f16 [hq][n][d]. SPLIT=1: v, 3-MFMA
// split, write hi/lo transposed [hq][d][n].
template<int SPLIT>
__global__ __launch_bounds__(256) void k_proj_mfma(const f16* __restrict__ A16,
        const f16* __restrict__ Alo,
        const f16* __restrict__ BTh, const f16* __restrict__ BTl,
        f16* __restrict__ fout16, f16* __restrict__ fhT, f16* __restrict__ flT) {
    int t = threadIdx.x, l = t & 63, w = t >> 6;
    int wr = w >> 1, wc = w & 1;
    int col0 = blockIdx.x * 128 + wc * 64;
    int tok0 = blockIdx.y * 128 + wr * 64;
    int lr = l & 15, kg = (l >> 4) * 8;
    v4f acc[4][4] = {};
    for (int ks = 0; ks < 512; ks += 32) {
        v8h a[4], b[4];
        #pragma unroll
        for (int i = 0; i < 4; ++i)
            a[i] = *(const v8h*)&A16[(size_t)(tok0 + i * 16 + lr) * 512 + ks + kg];
        #pragma unroll
        for (int j = 0; j < 4; ++j)
            b[j] = *(const v8h*)&BTh[(size_t)(col0 + j * 16 + lr) * 512 + ks + kg];
        if constexpr (SPLIT) {
            v8h al[4], bl[4];
            #pragma unroll
            for (int i = 0; i < 4; ++i)
                al[i] = *(const v8h*)&Alo[(size_t)(tok0 + i * 16 + lr) * 512 + ks + kg];
            #pragma unroll
            for (int j = 0; j < 4; ++j)
                bl[j] = *(const v8h*)&BTl[(size_t)(col0 + j * 16 + lr) * 512 + ks + kg];
            #pragma unroll
            for (int i = 0; i < 4; ++i)
                #pragma unroll
                for (int j = 0; j < 4; ++j) {
                    acc[i][j] = MFMA(a[i], b[j], acc[i][j]);
                    acc[i][j] = MFMA(a[i], bl[j], acc[i][j]);
                    acc[i][j] = MFMA(al[i], b[j], acc[i][j]);
                }
        } else {
            #pragma unroll
            for (int i = 0; i < 4; ++i)
                #pragma unroll
                for (int j = 0; j < 4; ++j)
                    acc[i][j] = MFMA(a[i], b[j], acc[i][j]);
        }
    }
    #pragma unroll
    for (int i = 0; i < 4; ++i)
        #pragma unroll
        for (int j = 0; j < 4; ++j)
            #pragma unroll
            for (int r = 0; r < 4; ++r) {
                int token = tok0 + i * 16 + (l >> 4) * 4 + r;
                int f = col0 + j * 16 + lr;
                int h = f >> 6, d = f & 63;
                int qi = token >> 10, n = token & 1023;
                float val = acc[i][j][r];
                if constexpr (!SPLIT) {
                    fout16[((size_t)((h << 2) + qi) * 1024 + n) * 64 + d] = (f16)val;
                } else {
                    f16 hi = (f16)val;
                    fhT[((size_t)((h << 2) + qi) * 64 + d) * 1024 + n] = hi;
                    flT[((size_t)((h << 2) + qi) * 64 + d) * 1024 + n] = (f16)(val - (float)hi);
                }
            }
}

// per-row norms / means / sums from f16 features
__global__ __launch_bounds__(256) void k_rowstats16(const f16* __restrict__ fq16,
        const f16* __restrict__ fk16, float* nq, float* muq, float* nk, float* sk) {
    int row = blockIdx.x * 4 + (threadIdx.x >> 6);
    int lane = threadIdx.x & 63;
    const f16* f = (blockIdx.y == 0) ? fq16 : fk16;
    float v = (float)f[(size_t)row * 64 + lane];
    float s = v, s2 = v * v;
    for (int o = 32; o > 0; o >>= 1) { s += __shfl_down(s, o); s2 += __shfl_down(s2, o); }
    if (lane == 0) {
        if (blockIdx.y == 0) { nq[row] = sqrtf(s2); muq[row] = s / 64.0f; }
        else                 { nk[row] = sqrtf(s2); sk[row] = s; }
    }
}

__global__ __launch_bounds__(64) void k_colmean16(const f16* __restrict__ fk16,
        float* nu, float* uu) {
    int hq = blockIdx.x; int d = threadIdx.x;
    const f16* base = fk16 + (size_t)hq * 65536;
    float s = 0.0f;
    for (int m = 0; m < 1024; ++m) s += (float)base[m * 64 + d];
    float nud = s / 1024.0f;
    nu[hq * 64 + d] = nud;
    float tsum = nud;
    for (int o = 32; o > 0; o >>= 1) tsum += __shfl_down(tsum, o);
    if (d == 0) uu[hq] = tsum;
}

__global__ __launch_bounds__(256) void k_tn16(const f16* __restrict__ fq16,
        const float* __restrict__ nu, float* tn) {
    int row = blockIdx.x * 4 + (threadIdx.x >> 6);
    int lane = threadIdx.x & 63;
    int hq = row >> 10;
    float p = (float)fq16[(size_t)row * 64 + lane] * nu[hq * 64 + lane];
    for (int o = 32; o > 0; o >>= 1) p += __shfl_down(p, o);
    if (lane == 0) tn[row] = p;
}

__global__ __launch_bounds__(256) void k_featacc16(const f16* __restrict__ fq16,
        const f16* __restrict__ fk16, float* feat) {
    __shared__ float l1[4][64], l2[4][64];
    int h = blockIdx.y, chunk = blockIdx.x;
    int t = threadIdx.x;
    int d = t & 63, rg = t >> 6;
    const f16* bq = fq16 + (size_t)h * 4096 * 64;
    const f16* bk = fk16 + (size_t)h * 4096 * 64;
    float sq = 0.0f, sk_ = 0.0f;
    for (int rr = 0; rr < 64; ++rr) {
        int idx = chunk * 256 + rg * 64 + rr;
        sq  += (float)bq[(size_t)idx * 64 + d];
        sk_ += (float)bk[(size_t)idx * 64 + d];
    }
    l1[rg][d] = sq; l2[rg][d] = sk_;
    __syncthreads();
    if (t < 64) {
        float a = l1[0][t] + l1[1][t] + l1[2][t] + l1[3][t];
        float b = l2[0][t] + l2[1][t] + l2[2][t] + l2[3][t];
        atomicAdd(&feat[h * 128 + t], a * (1.0f / 4096.0f));
        atomicAdd(&feat[h * 128 + 64 + t], b * (1.0f / 4096.0f));
    }
}

__global__ __launch_bounds__(256) void k_mlp(const float* __restrict__ feat,
        const float* __restrict__ W1, const float* __restrict__ b1,
        const float* __restrict__ lw, const float* __restrict__ lb,
        const float* __restrict__ W2, const float* __restrict__ b2,
        const float* __restrict__ W3, const float* __restrict__ b3,
        const float* __restrict__ W4, const float* __restrict__ b4,
        const float* __restrict__ wtemp, float* wv) {
    __shared__ float h1[256], h2[192], h3[64], red[8];
    int t = threadIdx.x;
    for (int h = 0; h < 8; ++h) {
        float p = 0.0f;
        for (int i = 0; i < 128; ++i) p += feat[h * 128 + i] * W1[i * 256 + t];
        p += b1[t];
        float s = p, s2 = p * p;
        for (int o = 32; o > 0; o >>= 1) { s += __shfl_down(s, o); s2 += __shfl_down(s2, o); }
        if ((t & 63) == 0) { red[t >> 6] = s; red[4 + (t >> 6)] = s2; }
        __syncthreads();
        float S = red[0] + red[1] + red[2] + red[3];
        float S2 = red[4] + red[5] + red[6] + red[7];
        float mu = S / 256.0f;
        float var = S2 / 256.0f - mu * mu; if (var < 0.0f) var = 0.0f;
        float xh = (p - mu) * rsqrtf(var + 1e-5f) * lw[t] + lb[t];
        h1[t] = fmaxf(xh, 0.0f);
        __syncthreads();
        if (t < 192) {
            float a = 0.0f;
            for (int i = 0; i < 256; ++i) a += h1[i] * W2[i * 192 + t];
            h2[t] = fmaxf(a + b2[t], 0.0f);
        }
        __syncthreads();
        if (t < 64) {
            float a = 0.0f;
            for (int i = 0; i < 192; ++i) a += h2[i] * W3[i * 64 + t];
            h3[t] = fmaxf(a + b3[t], 0.0f);
        }
        __syncthreads();
        if (t == 0) {
            float lg[3];
            for (int j = 0; j < 3; ++j) {
                float a = 0.0f;
                for (int i = 0; i < 64; ++i) a += h3[i] * W4[i * 3 + j];
                lg[j] = a + b4[j];
            }
            float mx = fmaxf(lg[0], fmaxf(lg[1], lg[2]));
            float e0 = expf(lg[0] - mx), e1 = expf(lg[1] - mx), e2 = expf(lg[2] - mx);
            float se = e0 + e1 + e2;
            float pr0 = e0 / se, pr1 = e1 / se, pr2 = e2 / se;
            float wt = wtemp[0]; wt = fminf(fmaxf(wt, 0.01f), 1.0f);
            float q0 = pr0 / wt, q1 = pr1 / wt, q2 = pr2 / wt;
            float m2 = fmaxf(q0, fmaxf(q1, q2));
            float f0 = expf(q0 - m2), f1 = expf(q1 - m2), f2 = expf(q2 - m2);
            float sf = f0 + f1 + f2; f0 /= sf; f1 /= sf; f2 /= sf;
            f0 = fminf(fmaxf(f0, 0.01f), 0.95f);
            f1 = fminf(fmaxf(f1, 0.01f), 0.95f);
            f2 = fminf(fmaxf(f2, 0.01f), 0.95f);
            float sw = f0 + f1 + f2;
            wv[h * 3 + 0] = f0 / sw; wv[h * 3 + 1] = f1 / sw; wv[h * 3 + 2] = f2 / sw;
        }
        __syncthreads();
    }
}

// raw = fq16 @ fk16^T (MFMA), fp32 out
__global__ __launch_bounds__(256) void k_qkt_mfma(const f16* __restrict__ fq16,
        const f16* __restrict__ fk16, float* __restrict__ raw) {
    int hq = blockIdx.z;
    int t = threadIdx.x, l = t & 63, w = t >> 6;
    int wr = w >> 1, wc = w & 1;
    int n0 = blockIdx.y * 128 + wr * 64;
    int m0 = blockIdx.x * 128 + wc * 64;
    const f16* A = fq16 + (size_t)hq * 65536;
    const f16* B = fk16 + (size_t)hq * 65536;
    int lr = l & 15, kg = (l >> 4) * 8;
    v4f acc[4][4] = {};
    #pragma unroll
    for (int ks = 0; ks < 64; ks += 32) {
        v8h a[4], b[4];
        #pragma unroll
        for (int i = 0; i < 4; ++i)
            a[i] = *(const v8h*)&A[(size_t)(n0 + i * 16 + lr) * 64 + ks + kg];
        #pragma unroll
        for (int j = 0; j < 4; ++j)
            b[j] = *(const v8h*)&B[(size_t)(m0 + j * 16 + lr) * 64 + ks + kg];
        #pragma unroll
        for (int i = 0; i < 4; ++i)
            #pragma unroll
            for (int j = 0; j < 4; ++j)
                acc[i][j] = MFMA(a[i], b[j], acc[i][j]);
    }
    float* R = raw + (size_t)hq * 1048576;
    #pragma unroll
    for (int i = 0; i < 4; ++i)
        #pragma unroll
        for (int j = 0; j < 4; ++j)
            #pragma unroll
            for (int r = 0; r < 4; ++r)
                R[(size_t)(n0 + i * 16 + (l >> 4) * 4 + r) * 1024 + m0 + j * 16 + lr]
                    = acc[i][j][r];
}

// pass B: global cos/cov sums + per-row margin mean (no contended atomics)
__global__ __launch_bounds__(256) void k_passb2(const float* __restrict__ raw,
        const float* __restrict__ nq, const float* __restrict__ muq,
        const float* __restrict__ tn, const float* __restrict__ nk,
        const float* __restrict__ sk, const float* __restrict__ uu,
        float* __restrict__ vcrow, float* __restrict__ pb) {
    int t = threadIdx.x, wid = t >> 6, lane = t & 63;
    __shared__ float wred[4];
    __shared__ float bsum[4][4];
    const float covscale = 0.001f / 1024.0f;
    float scos = 0.f, s2cos = 0.f, scov = 0.f, s2cov = 0.f;
    for (int rr = 0; rr < 16; ++rr) {
        int row = blockIdx.x * 16 + rr, hq = row >> 10;
        float4 r4 = ((const float4*)(raw + (size_t)row * 1024))[t];
        float4 nn = ((const float4*)(nk + hq * 1024))[t];
        float4 ss = ((const float4*)(sk + hq * 1024))[t];
        float nqv = nq[row], muv = muq[row], tv = tn[row], uv = uu[hq];
        float c1 = nqv + 1e-6f, c2 = fmaxf(nqv, 1e-4f);
        float smarg = 0.f;
        {
            float rv[4] = { r4.x, r4.y, r4.z, r4.w };
            float nv[4] = { nn.x, nn.y, nn.z, nn.w };
            float sv[4] = { ss.x, ss.y, ss.z, ss.w };
            #pragma unroll
            for (int e = 0; e < 4; ++e) {
                float r = rv[e];
                float cosv = fminf(fmaxf(r / (c1 * (nv[e] + 1e-6f)), -0.95f), 0.95f);
                float cs = fminf(fmaxf(r / (c2 * fmaxf(nv[e], 1e-4f)), -0.95f), 0.95f);
                float marg = fminf(fmaxf(0.01f - cs, 0.0f), 15.0f);
                float cp = (r - tv - muv * sv[e] + muv * uv) / 8.0001f;
                float cov = fminf(fmaxf(covscale * cp, -50.0f), 50.0f);
                scos += cosv; s2cos += cosv * cosv;
                scov += cov;  s2cov += cov * cov;
                smarg += marg;
            }
        }
        for (int o = 32; o > 0; o >>= 1) smarg += __shfl_down(smarg, o);
        if (lane == 0) wred[wid] = smarg;
        __syncthreads();
        if (t == 0) vcrow[row] = (wred[0] + wred[1] + wred[2] + wred[3]) * (1.0f / 1024.0f);
        __syncthreads();
    }
    for (int o = 32; o > 0; o >>= 1) {
        scos += __shfl_down(scos, o); s2cos += __shfl_down(s2cos, o);
        scov += __shfl_down(scov, o); s2cov += __shfl_down(s2cov, o);
    }
    if (lane == 0) { bsum[wid][0] = scos; bsum[wid][1] = s2cos;
                     bsum[wid][2] = scov; bsum[wid][3] = s2cov; }
    __syncthreads();
    if (t == 0) {
        pb[blockIdx.x * 4 + 0] = bsum[0][0] + bsum[1][0] + bsum[2][0] + bsum[3][0];
        pb[blockIdx.x * 4 + 1] = bsum[0][1] + bsum[1][1] + bsum[2][1] + bsum[3][1];
        pb[blockIdx.x * 4 + 2] = bsum[0][2] + bsum[1][2] + bsum[2][2] + bsum[3][2];
        pb[blockIdx.x * 4 + 3] = bsum[0][3] + bsum[1][3] + bsum[2][3] + bsum[3][3];
    }
}

__global__ __launch_bounds__(256) void k_fin1(const float* __restrict__ pb,
        const float* __restrict__ vcrow, float* __restrict__ scal) {
    int t = threadIdx.x;
    double s0 = 0, s1 = 0, s2 = 0, s3 = 0, s4 = 0, s5 = 0;
    for (int i = t; i < 2048; i += 256) {
        s0 += pb[i * 4 + 0]; s1 += pb[i * 4 + 1];
        s2 += pb[i * 4 + 2]; s3 += pb[i * 4 + 3];
    }
    for (int i = t; i < 32768; i += 256) {
        double rm = (double)vcrow[i];
        s4 += rm; s5 += rm * rm;
    }
    for (int o = 32; o > 0; o >>= 1) {
        s0 += __shfl_down(s0, o); s1 += __shfl_down(s1, o); s2 += __shfl_down(s2, o);
        s3 += __shfl_down(s3, o); s4 += __shfl_down(s4, o); s5 += __shfl_down(s5, o);
    }
    __shared__ double red[6][4];
    int wid = t >> 6, lane = t & 63;
    if (lane == 0) { red[0][wid] = s0; red[1][wid] = s1; red[2][wid] = s2;
                     red[3][wid] = s3; red[4][wid] = s4; red[5][wid] = s5; }
    __syncthreads();
    if (t == 0) {
        double S0 = red[0][0] + red[0][1] + red[0][2] + red[0][3];
        double S1 = red[1][0] + red[1][1] + red[1][2] + red[1][3];
        double S2 = red[2][0] + red[2][1] + red[2][2] + red[2][3];
        double S3 = red[3][0] + red[3][1] + red[3][2] + red[3][3];
        double S4 = red[4][0] + red[4][1] + red[4][2] + red[4][3];
        double S5 = red[5][0] + red[5][1] + red[5][2] + red[5][3];
        const double cnt = 33554432.0;
        scal[0] = (float)sqrt(fmax(0.0, (S1 - S0 * S0 / cnt) / (cnt - 1.0)));
        scal[1] = (float)sqrt(fmax(0.0, (S3 - S2 * S2 / cnt) / (cnt - 1.0)));
        double V4 = S4 * 1024.0, V5 = S5 * 1024.0;
        scal[2] = (float)sqrt(fmax(0.0, (V5 - V4 * V4 / cnt) / (cnt - 1.0)));
    }
}

// dots: read raw fp32, write f16 dots into the lower half of each row (in place)
__global__ __launch_bounds__(256) void k_passd2(float* __restrict__ raw,
        const float* __restrict__ nq, const float* __restrict__ muq,
        const float* __restrict__ tn, const float* __restrict__ nk,
        const float* __restrict__ sk, const float* __restrict__ uu,
        const float* __restrict__ vcrow, const float* __restrict__ wv,
        const float* __restrict__ scal, float* __restrict__ pb2) {
    int t = threadIdx.x, wid = t >> 6, lane = t & 63;
    float s1 = scal[0] + 1e-4f, s2v = scal[1] + 1e-4f, s3 = scal[2] + 1e-4f;
    const float covscale = 0.001f / 1024.0f;
    float sd = 0.f, s2d = 0.f;
    __shared__ float fr[2][4];
    for (int rr = 0; rr < 32; ++rr) {
        int row = blockIdx.x * 32 + rr;
        int hq = row >> 10, h = hq >> 2;
        float* Rf = raw + (size_t)row * 1024;
        float4 r = ((const float4*)Rf)[t];
        float4 nn = ((const float4*)(nk + hq * 1024))[t];
        float4 ss = ((const float4*)(sk + hq * 1024))[t];
        float nqv = nq[row], muv = muq[row], tv = tn[row], uv = uu[hq];
        float c1 = nqv + 1e-6f;
        float vc = vcrow[row];
        float w0 = wv[h * 3], w1 = wv[h * 3 + 1], w2 = wv[h * 3 + 2];
        float addc = w2 * (vc / s3) * 0.3f;
        float fc1 = w0 / s1;
        float fc2 = w1 * 0.3f / s2v;
        float dd[4];
        float rv[4] = { r.x, r.y, r.z, r.w };
        float nv[4] = { nn.x, nn.y, nn.z, nn.w };
        float sv[4] = { ss.x, ss.y, ss.z, ss.w };
        #pragma unroll
        for (int e = 0; e < 4; ++e) {
            float cosv = fminf(fmaxf(rv[e] / (c1 * (nv[e] + 1e-6f)), -0.95f), 0.95f);
            float cp = (rv[e] - tv - muv * sv[e] + muv * uv) / 8.0001f;
            float cov = fminf(fmaxf(covscale * cp, -50.f), 50.f);
            dd[e] = fc1 * cosv + fc2 * cov + addc;
            sd += dd[e]; s2d += dd[e] * dd[e];
        }
        __syncthreads();   // all reads of this row done before f16 overwrite
        v4h hd;
        #pragma unroll
        for (int e = 0; e < 4; ++e) hd[e] = (f16)dd[e];
        *(v4h*)((f16*)Rf + t * 4) = hd;
    }
    for (int o = 32; o > 0; o >>= 1) { sd += __shfl_down(sd, o); s2d += __shfl_down(s2d, o); }
    if (lane == 0) { fr[0][wid] = sd; fr[1][wid] = s2d; }
    __syncthreads();
    if (t == 0) {
        pb2[blockIdx.x * 2 + 0] = fr[0][0] + fr[0][1] + fr[0][2] + fr[0][3];
        pb2[blockIdx.x * 2 + 1] = fr[1][0] + fr[1][1] + fr[1][2] + fr[1][3];
    }
}

__global__ __launch_bounds__(256) void k_fin2(const float* __restrict__ pb2,
        float* __restrict__ scal) {
    int t = threadIdx.x;
    double s6 = 0, s7 = 0;
    for (int i = t; i < 1024; i += 256) { s6 += pb2[i * 2]; s7 += pb2[i * 2 + 1]; }
    for (int o = 32; o > 0; o >>= 1) { s6 += __shfl_down(s6, o); s7 += __shfl_down(s7, o); }
    __shared__ double red[2][4];
    int wid = t >> 6, lane = t & 63;
    if (lane == 0) { red[0][wid] = s6; red[1][wid] = s7; }
    __syncthreads();
    if (t == 0) {
        double S6 = red[0][0] + red[0][1] + red[0][2] + red[0][3];
        double S7 = red[1][0] + red[1][1] + red[1][2] + red[1][3];
        const double cnt = 33554432.0;
        double ds = sqrt(fmax(0.0, (S7 - S6 * S6 / cnt) / (cnt - 1.0)));
        float temp = (ds < 1e-5) ? 0.01f : ((ds < 1e-3) ? 0.05f : (0.2f + (float)ds * 2.0f));
        temp = fminf(fmaxf(temp, 0.01f), 8.0f);
        scal[3] = temp;
    }
}

// softmax over f16 dots rows (in place), incl. row max
__global__ __launch_bounds__(256) void k_softmax2(float* __restrict__ raw,
        const float* __restrict__ scal) {
    int t = threadIdx.x, wid = t >> 6, lane = t & 63;
    float inv = 1.0f / scal[3];
    __shared__ float wred[4];
    __shared__ float sbc;
    for (int rr = 0; rr < 16; ++rr) {
        int row = blockIdx.x * 16 + rr;
        f16* dp = (f16*)(raw + (size_t)row * 1024);
        v4h h4 = *(v4h*)&dp[t * 4];
        float d0 = (float)h4[0], d1 = (float)h4[1], d2 = (float)h4[2], d3 = (float)h4[3];
        float mx = fmaxf(fmaxf(d0, d1), fmaxf(d2, d3));
        for (int o = 32; o > 0; o >>= 1) mx = fmaxf(mx, __shfl_down(mx, o));
        if (lane == 0) wred[wid] = mx;
        __syncthreads();
        if (t == 0) sbc = fmaxf(fmaxf(wred[0], wred[1]), fmaxf(wred[2], wred[3]));
        __syncthreads();
        float bm = sbc;
        float e0 = __expf((d0 - bm) * inv), e1 = __expf((d1 - bm) * inv);
        float e2 = __expf((d2 - bm) * inv), e3 = __expf((d3 - bm) * inv);
        float s = e0 + e1 + e2 + e3;
        for (int o = 32; o > 0; o >>= 1) s += __shfl_down(s, o);
        __syncthreads();
        if (lane == 0) wred[wid] = s;
        __syncthreads();
        if (t == 0) sbc = wred[0] + wred[1] + wred[2] + wred[3];
        __syncthreads();
        float itot = 1.0f / sbc;
        v4h ho;
        ho[0] = (f16)(e0 * itot); ho[1] = (f16)(e1 * itot);
        ho[2] = (f16)(e2 * itot); ho[3] = (f16)(e3 * itot);
        *(v4h*)&dp[t * 4] = ho;
        __syncthreads();
    }
}

// av = attn16 @ fv (MFMA, fv split hi/lo), write av hi/lo f16
__global__ __launch_bounds__(256) void k_pv_mfma(const float* __restrict__ raw,
        const f16* __restrict__ fvhT, const f16* __restrict__ fvlT,
        f16* __restrict__ avh, f16* __restrict__ avl) {
    __shared__ float red[2][2][4][4][64];
    int hq = blockIdx.y, n0 = blockIdx.x * 64;
    int t = threadIdx.x, l = t & 63, w = t >> 6;
    int rg = w & 1, kh = w >> 1;
    int lr = l & 15, kg = (l >> 4) * 8;
    const char* rawb = (const char*)raw;
    v4f acc[2][4] = {};
    for (int ks = kh * 512; ks < kh * 512 + 512; ks += 32) {
        v8h a[2], bh[4], bl[4];
        #pragma unroll
        for (int i = 0; i < 2; ++i)
            a[i] = *(const v8h*)((const f16*)(rawb +
                    (size_t)(hq * 1024 + n0 + rg * 32 + i * 16 + lr) * 4096) + ks + kg);
        #pragma unroll
        for (int j = 0; j < 4; ++j) {
            bh[j] = *(const v8h*)&fvhT[((size_t)hq * 64 + j * 16 + lr) * 1024 + ks + kg];
            bl[j] = *(const v8h*)&fvlT[((size_t)hq * 64 + j * 16 + lr) * 1024 + ks + kg];
        }
        #pragma unroll
        for (int i = 0; i < 2; ++i)
            #pragma unroll
            for (int j = 0; j < 4; ++j) {
                acc[i][j] = MFMA(a[i], bh[j], acc[i][j]);
                acc[i][j] = MFMA(a[i], bl[j], acc[i][j]);
            }
    }
    if (kh == 0) {
        #pragma unroll
        for (int i = 0; i < 2; ++i)
            #pragma unroll
            for (int j = 0; j < 4; ++j)
                #pragma unroll
                for (int r = 0; r < 4; ++r)
                    red[rg][i][j][r][l] = acc[i][j][r];
    }
    __syncthreads();
    if (kh == 1) {
        #pragma unroll
        for (int i = 0; i < 2; ++i)
            #pragma unroll
            for (int j = 0; j < 4; ++j)
                #pragma unroll
                for (int r = 0; r < 4; ++r) {
                    float val = acc[i][j][r] + red[rg][i][j][r][l];
                    int n = n0 + rg * 32 + i * 16 + (l >> 4) * 4 + r;
                    int d = j * 16 + lr;
                    f16 hi = (f16)val;
                    avh[((size_t)hq * 1024 + n) * 64 + d] = hi;
                    avl[((size_t)hq * 1024 + n) * 64 + d] = (f16)(val - (float)hi);
                }
    }
}

// out = av @ Wout + bout (MFMA, 3-way split)
__global__ __launch_bounds__(256) void k_out_mfma(const f16* __restrict__ avh,
        const f16* __restrict__ avl,
        const f16* __restrict__ WoutTh, const f16* __restrict__ WoutTl,
        const float* __restrict__ bout, float* __restrict__ out) {
    __shared__ float red[2][4][4][4][64];
    int t = threadIdx.x, l = t & 63, w = t >> 6;
    int wc = w & 1, kh = w >> 1;
    int col0 = blockIdx.x * 128 + wc * 64;
    int tok0 = blockIdx.y * 64;
    int qi = tok0 >> 10, nb = tok0 & 1023;
    int lr = l & 15, kg = (l >> 4) * 8;
    v4f acc[4][4] = {};
    for (int ks8 = 0; ks8 < 8; ++ks8) {
        int ks = kh * 256 + ks8 * 32;
        int f = ks + kg;
        int h = f >> 6, d = f & 63;
        size_t hb = (size_t)((h << 2) + qi) * 1024;
        v8h ah[4], al4[4], bh[4], bl4[4];
        #pragma unroll
        for (int i = 0; i < 4; ++i) {
            int n = nb + i * 16 + lr;
            ah[i]  = *(const v8h*)&avh[(hb + n) * 64 + d];
            al4[i] = *(const v8h*)&avl[(hb + n) * 64 + d];
        }
        #pragma unroll
        for (int j = 0; j < 4; ++j) {
            bh[j]  = *(const v8h*)&WoutTh[(size_t)(col0 + j * 16 + lr) * 512 + ks + kg];
            bl4[j] = *(const v8h*)&WoutTl[(size_t)(col0 + j * 16 + lr) * 512 + ks + kg];
        }
        #pragma unroll
        for (int i = 0; i < 4; ++i)
            #pragma unroll
            for (int j = 0; j < 4; ++j) {
                acc[i][j] = MFMA(ah[i], bh[j], acc[i][j]);
                acc[i][j] = MFMA(ah[i], bl4[j], acc[i][j]);
                acc[i][j] = MFMA(al4[i], bh[j], acc[i][j]);
            }
    }
    if (kh == 0) {
        #pragma unroll
        for (int i = 0; i < 4; ++i)
            #pragma unroll
            for (int j = 0; j < 4; ++j)
                #pragma unroll
                for (int r = 0; r < 4; ++r)
                    red[wc][i][j][r][l] = acc[i][j][r];
    }
    __syncthreads();
    if (kh == 1) {
        #pragma unroll
        for (int i = 0; i < 4; ++i)
            #pragma unroll
            for (int j = 0; j < 4; ++j) {
                int col = col0 + j * 16 + lr;
                float bo = bout[col];
                #pragma unroll
                for (int r = 0; r < 4; ++r) {
                    float val = acc[i][j][r] + red[wc][i][j][r][l] + bo;
                    int token = tok0 + i * 16 + (l >> 4) * 4 + r;
                    out[(size_t)token * 512 + col] = val;
                }
            }
    }
}

extern "C" void kernel_launch(void* const* d_in, const int* in_sizes, int n_in,
                              void* d_out, int out_size, void* d_ws, size_t ws_size,
                              hipStream_t stream) {
    const float* q     = (const float*)d_in[0];
    const float* k     = (const float*)d_in[1];
    const float* v     = (const float*)d_in[2];
    const float* ln_w  = (const float*)d_in[3];
    const float* ln_b  = (const float*)d_in[4];
    const float* W_in  = (const float*)d_in[5];
    const float* W_out = (const float*)d_in[6];
    const float* b_out = (const float*)d_in[7];
    const float* wp_W1 = (const float*)d_in[8];
    const float* wp_b1 = (const float*)d_in[9];
    const float* wp_lw = (const float*)d_in[10];
    const float* wp_lb = (const float*)d_in[11];
    const float* wp_W2 = (const float*)d_in[12];
    const float* wp_b2 = (const float*)d_in[13];
    const float* wp_W3 = (const float*)d_in[14];
    const float* wp_b3 = (const float*)d_in[15];
    const float* wp_W4 = (const float*)d_in[16];
    const float* wp_b4 = (const float*)d_in[17];
    const float* wtemp = (const float*)d_in[18];

    float* ws = (float*)d_ws;
    float* raw    = ws + OFF_RAW;
    f16* ln16     = (f16*)(ws + OFF_RAW);
    f16* lnlo     = (f16*)(ws + OFF_LNLO);
    f16* fq16     = (f16*)(ws + OFF_FQ16);
    f16* fk16     = (f16*)(ws + OFF_FK16);
    f16* fvhT     = (f16*)(ws + OFF_FVHT);
    f16* fvlT     = (f16*)(ws + OFF_FVLT);
    f16* WinTh    = (f16*)(ws + OFF_WINT_H);
    f16* WinTl    = (f16*)(ws + OFF_WINT_L);
    f16* WoutTh   = (f16*)(ws + OFF_WOUTT_H);
    f16* WoutTl   = (f16*)(ws + OFF_WOUTT_L);
    f16* avh      = (f16*)(ws + OFF_FQ16);   // alias, fq16 dead after qkt
    f16* avl      = (f16*)(ws + OFF_FK16);   // alias
    float* nq     = ws + OFF_NQ;
    float* muq    = ws + OFF_MUQ;
    float* tn     = ws + OFF_TN;
    float* nk     = ws + OFF_NK;
    float* sk     = ws + OFF_SK;
    float* vcrow  = ws + OFF_VC;
    float* pb     = ws + OFF_PB;
    float* nu     = ws + OFF_PB2;   // alias, dead after k_tn16
    float* pb2    = ws + OFF_PB2;
    float* uu     = ws + OFF_UU;
    float* feat   = ws + OFF_FEAT;
    float* wv     = ws + OFF_WV;
    float* scal   = ws + OFF_SCAL;

    k_zerofeat<<<4, 256, 0, stream>>>(feat);
    k_wprep<<<dim3(8, 8, 2), 256, 0, stream>>>(W_in, W_out, WinTh, WinTl, WoutTh, WoutTl);
    k_ln16<<<3072, 256, 0, stream>>>(q, k, v, ln_w, ln_b, ln16, lnlo);
    k_proj_mfma<0><<<dim3(4, 32), 256, 0, stream>>>(ln16, nullptr, WinTh, WinTl,
                                                    fq16, nullptr, nullptr);
    k_proj_mfma<0><<<dim3(4, 32), 256, 0, stream>>>(ln16 + (size_t)4096 * 512, nullptr,
                                                    WinTh, WinTl, fk16, nullptr, nullptr);
    k_proj_mfma<1><<<dim3(4, 32), 256, 0, stream>>>(ln16 + (size_t)8192 * 512, lnlo,
                                                    WinTh, WinTl, nullptr, fvhT, fvlT);
    k_rowstats16<<<dim3(8192, 2), 256, 0, stream>>>(fq16, fk16, nq, muq, nk, sk);
    k_colmean16<<<32, 64, 0, stream>>>(fk16, nu, uu);
    k_tn16<<<8192, 256, 0, stream>>>(fq16, nu, tn);
    k_featacc16<<<dim3(16, 8), 256, 0, stream>>>(fq16, fk16, feat);
    k_mlp<<<1, 256, 0, stream>>>(feat, wp_W1, wp_b1, wp_lw, wp_lb,
                                 wp_W2, wp_b2, wp_W3, wp_b3, wp_W4, wp_b4,
                                 wtemp, wv);
    k_qkt_mfma<<<dim3(8, 8, 32), 256, 0, stream>>>(fq16, fk16, raw);
    k_passb2<<<2048, 256, 0, stream>>>(raw, nq, muq, tn, nk, sk, uu, vcrow, pb);
    k_fin1<<<1, 256, 0, stream>>>(pb, vcrow, scal);
    k_passd2<<<1024, 256, 0, stream>>>(raw, nq, muq, tn, nk, sk, uu, vcrow, wv, scal, pb2);
    k_fin2<<<1, 256, 0, stream>>>(pb2, scal);
    k_softmax2<<<2048, 256, 0, stream>>>(raw, scal);
    k_pv_mfma<<<dim3(16, 32), 256, 0, stream>>>(raw, fvhT, fvlT, avh, avl);
    k_out_mfma<<<dim3(4, 64), 256, 0, stream>>>(avh, avl, WoutTh, WoutTl, b_out,
                                                (float*)d_out);
}

// Round 5
// 386.986 us; speedup vs baseline: 29.2921x; 1.2847x over previous
//
#include <hip/hip_runtime.h>
#include <math.h>

typedef _Float16 f16;
typedef _Float16 v8h __attribute__((ext_vector_type(8)));
typedef _Float16 v4h __attribute__((ext_vector_type(4)));
typedef float    v4f __attribute__((ext_vector_type(4)));

#define MFMA(a, b, c) __builtin_amdgcn_mfma_f32_16x16x32_f16((a), (b), (c), 0, 0, 0)

// ---------------- workspace layout (float offsets) ----------------
// sizes: ln16 f16[12288*512]=3145728f, lnlo f16[4096*512]=1048576f,
// fq16/fk16/fvhT/fvlT f16[2097152]=1048576f each,
// W*T* f16[262144]=131072f each, avh/avl 1048576f each.
#define OFF_LN16    0u
#define OFF_LNLO    3145728u
#define OFF_FQ16    4194304u
#define OFF_FK16    5242880u
#define OFF_FVHT    6291456u
#define OFF_FVLT    7340032u
#define OFF_WINTH   8388608u
#define OFF_WINTL   8519680u
#define OFF_WOUTTH  8650752u
#define OFF_WOUTTL  8781824u
#define OFF_AVH     8912896u
#define OFF_AVL     9961472u
#define OFF_NQ      11010048u
#define OFF_MUQ     11042816u
#define OFF_NK      11075584u
#define OFF_SK      11108352u
#define OFF_VC      11141120u
#define OFF_RMAX    11173888u
#define OFF_NUACC   11206656u   // 2048
#define OFF_PB      11208704u   // 256*4
#define OFF_PB2     11209728u   // 256*2
#define OFF_FEAT    11210240u   // 1024
#define OFF_WV      11211264u   // 24
#define OFF_SCAL    11211288u   // 8

__device__ __forceinline__ float clampf(float x, float lo, float hi) {
    return fminf(fmaxf(x, lo), hi);
}

__global__ void k_zero(float* feat, float* nuacck) {
    int i = blockIdx.x * 256 + threadIdx.x;
    if (i < 1024) feat[i] = 0.0f;
    if (i < 2048) nuacck[i] = 0.0f;
}

// transpose + hi/lo split of a 512x512 weight: W[k][c] -> WT{h,l}[c][k]
__global__ __launch_bounds__(256) void k_wprep(const float* __restrict__ Win,
        const float* __restrict__ Wout, f16* __restrict__ WinTh, f16* __restrict__ WinTl,
        f16* __restrict__ WoutTh, f16* __restrict__ WoutTl) {
    __shared__ float lds[64][68];
    const float* W = blockIdx.z ? Wout : Win;
    f16* Th = blockIdx.z ? WoutTh : WinTh;
    f16* Tl = blockIdx.z ? WoutTl : WinTl;
    int k0 = blockIdx.y * 64, c0 = blockIdx.x * 64;
    int t = threadIdx.x;
    #pragma unroll
    for (int p = 0; p < 4; ++p) {
        int flat = p * 1024 + t * 4;
        int r = flat >> 6, c = flat & 63;
        *(float4*)&lds[r][c] = *(const float4*)&W[(size_t)(k0 + r) * 512 + c0 + c];
    }
    __syncthreads();
    int c = t >> 2, kk = (t & 3) * 16;
    #pragma unroll
    for (int half = 0; half < 2; ++half) {
        v8h h8, l8;
        #pragma unroll
        for (int ii = 0; ii < 8; ++ii) {
            float v = lds[kk + half * 8 + ii][c];
            f16 h = (f16)v;
            h8[ii] = h;
            l8[ii] = (f16)(v - (float)h);
        }
        *(v8h*)&Th[(size_t)(c0 + c) * 512 + k0 + kk + half * 8] = h8;
        *(v8h*)&Tl[(size_t)(c0 + c) * 512 + k0 + kk + half * 8] = l8;
    }
}

// LayerNorm all 12288 tokens -> ln16 f16; v tokens also get lo residual
__global__ __launch_bounds__(256) void k_ln16(const float* __restrict__ q,
        const float* __restrict__ kk, const float* __restrict__ v,
        const float* __restrict__ lnw, const float* __restrict__ lnb,
        f16* __restrict__ ln16, f16* __restrict__ lnlo) {
    int t = threadIdx.x, wid = t >> 6, lane = t & 63;
    int token = blockIdx.x * 4 + wid;
    int inp = token >> 12, lt = token & 4095;
    const float* xp = (inp == 0) ? q : ((inp == 1) ? kk : v);
    const float4* xr = (const float4*)(xp + (size_t)lt * 512);
    float4 a = xr[lane], b = xr[lane + 64];
    float s = a.x + a.y + a.z + a.w + b.x + b.y + b.z + b.w;
    float s2 = a.x*a.x + a.y*a.y + a.z*a.z + a.w*a.w
             + b.x*b.x + b.y*b.y + b.z*b.z + b.w*b.w;
    for (int o = 32; o > 0; o >>= 1) { s += __shfl_down(s, o); s2 += __shfl_down(s2, o); }
    float m_ = __shfl(s, 0) * (1.0f / 512.0f);
    float var = __shfl(s2, 0) * (1.0f / 512.0f) - m_ * m_;
    var = fmaxf(var, 0.0f);
    float rs = rsqrtf(var + 1e-5f);
    const float4* w4 = (const float4*)lnw;
    const float4* b4 = (const float4*)lnb;
    float4 wa = w4[lane], wb = w4[lane + 64], ba = b4[lane], bb = b4[lane + 64];
    float ga[4] = { (a.x - m_) * rs * wa.x + ba.x, (a.y - m_) * rs * wa.y + ba.y,
                    (a.z - m_) * rs * wa.z + ba.z, (a.w - m_) * rs * wa.w + ba.w };
    float gb[4] = { (b.x - m_) * rs * wb.x + bb.x, (b.y - m_) * rs * wb.y + bb.y,
                    (b.z - m_) * rs * wb.z + bb.z, (b.w - m_) * rs * wb.w + bb.w };
    f16* orow = ln16 + (size_t)token * 512;
    v4h ha, hb;
    #pragma unroll
    for (int i = 0; i < 4; ++i) { ha[i] = (f16)ga[i]; hb[i] = (f16)gb[i]; }
    *(v4h*)&orow[lane * 4] = ha;
    *(v4h*)&orow[lane * 4 + 256] = hb;
    if (inp == 2) {
        f16* lrow = lnlo + (size_t)lt * 512;
        v4h la, lb;
        #pragma unroll
        for (int i = 0; i < 4; ++i) {
            la[i] = (f16)(ga[i] - (float)ha[i]);
            lb[i] = (f16)(gb[i] - (float)hb[i]);
        }
        *(v4h*)&lrow[lane * 4] = la;
        *(v4h*)&lrow[lane * 4 + 256] = lb;
    }
}

// LN16 @ Win (MFMA). MODE 0: q (fq16 + nq/muq + feat). MODE 1: k (fk16 +
// nk/sk + feat + nuacck). MODE 2: v (hi/lo split, transposed write).
template<int MODE>
__global__ __launch_bounds__(256) void k_proj_mfma(const f16* __restrict__ A16,
        const f16* __restrict__ Alo,
        const f16* __restrict__ BTh, const f16* __restrict__ BTl,
        f16* __restrict__ fout16, f16* __restrict__ fhT, f16* __restrict__ flT,
        float* __restrict__ rsA, float* __restrict__ rsB,
        float* __restrict__ feat, float* __restrict__ nuacck) {
    int t = threadIdx.x, l = t & 63, w = t >> 6;
    int wr = w >> 1, wc = w & 1;
    int col0 = blockIdx.x * 128 + wc * 64;
    int tok0 = blockIdx.y * 128 + wr * 64;
    int lr = l & 15, kg = (l >> 4) * 8;
    int rg4 = (l >> 4) * 4;
    v4f acc[4][4] = {};
    for (int ks = 0; ks < 512; ks += 32) {
        v8h a[4], b[4];
        #pragma unroll
        for (int i = 0; i < 4; ++i)
            a[i] = *(const v8h*)&A16[(size_t)(tok0 + i * 16 + lr) * 512 + ks + kg];
        #pragma unroll
        for (int j = 0; j < 4; ++j)
            b[j] = *(const v8h*)&BTh[(size_t)(col0 + j * 16 + lr) * 512 + ks + kg];
        if constexpr (MODE == 2) {
            v8h al[4], bl[4];
            #pragma unroll
            for (int i = 0; i < 4; ++i)
                al[i] = *(const v8h*)&Alo[(size_t)(tok0 + i * 16 + lr) * 512 + ks + kg];
            #pragma unroll
            for (int j = 0; j < 4; ++j)
                bl[j] = *(const v8h*)&BTl[(size_t)(col0 + j * 16 + lr) * 512 + ks + kg];
            #pragma unroll
            for (int i = 0; i < 4; ++i)
                #pragma unroll
                for (int j = 0; j < 4; ++j) {
                    acc[i][j] = MFMA(a[i], b[j], acc[i][j]);
                    acc[i][j] = MFMA(a[i], bl[j], acc[i][j]);
                    acc[i][j] = MFMA(al[i], b[j], acc[i][j]);
                }
        } else {
            #pragma unroll
            for (int i = 0; i < 4; ++i)
                #pragma unroll
                for (int j = 0; j < 4; ++j)
                    acc[i][j] = MFMA(a[i], b[j], acc[i][j]);
        }
    }
    int h = col0 >> 6;
    #pragma unroll
    for (int i = 0; i < 4; ++i)
        #pragma unroll
        for (int j = 0; j < 4; ++j)
            #pragma unroll
            for (int r = 0; r < 4; ++r) {
                int token = tok0 + i * 16 + rg4 + r;
                int d = j * 16 + lr;
                int qi = token >> 10, n = token & 1023;
                float val = acc[i][j][r];
                if constexpr (MODE != 2) {
                    fout16[((size_t)((h << 2) + qi) * 1024 + n) * 64 + d] = (f16)val;
                } else {
                    f16 hi = (f16)val;
                    fhT[((size_t)((h << 2) + qi) * 64 + d) * 1024 + n] = hi;
                    flT[((size_t)((h << 2) + qi) * 64 + d) * 1024 + n] = (f16)(val - (float)hi);
                }
            }
    if constexpr (MODE != 2) {
        // row stats (per token-row of this head)
        #pragma unroll
        for (int i = 0; i < 4; ++i)
            #pragma unroll
            for (int r = 0; r < 4; ++r) {
                float s = 0.f, s2 = 0.f;
                #pragma unroll
                for (int j = 0; j < 4; ++j) { float v = acc[i][j][r]; s += v; s2 += v * v; }
                #pragma unroll
                for (int mk = 1; mk <= 8; mk <<= 1) {
                    s += __shfl_xor(s, mk); s2 += __shfl_xor(s2, mk);
                }
                if (lr == 0) {
                    int token = tok0 + i * 16 + rg4 + r;
                    int qi = token >> 10, n = token & 1023;
                    int row = ((h << 2) + qi) * 1024 + n;
                    if constexpr (MODE == 0) { rsA[row] = sqrtf(s2); rsB[row] = s * (1.0f / 64.0f); }
                    else                     { rsA[row] = sqrtf(s2); rsB[row] = s; }
                }
            }
        // column sums (feat + nu)
        float cs[4];
        #pragma unroll
        for (int j = 0; j < 4; ++j) {
            float c = 0.f;
            #pragma unroll
            for (int i = 0; i < 4; ++i)
                #pragma unroll
                for (int r = 0; r < 4; ++r) c += acc[i][j][r];
            c += __shfl_xor(c, 16); c += __shfl_xor(c, 32);
            cs[j] = c;
        }
        if (l < 16) {
            #pragma unroll
            for (int j = 0; j < 4; ++j)
                atomicAdd(&feat[h * 128 + (MODE == 1 ? 64 : 0) + j * 16 + l],
                          cs[j] * (1.0f / 4096.0f));
            if constexpr (MODE == 1) {
                int qi = tok0 >> 10;
                #pragma unroll
                for (int j = 0; j < 4; ++j)
                    atomicAdd(&nuacck[((h << 2) + qi) * 64 + j * 16 + l], cs[j]);
            }
        }
    }
}

// tiny MLP weight predictor, one block per head -> wv[h][3]
__global__ __launch_bounds__(256) void k_mlp(const float* __restrict__ feat,
        const float* __restrict__ W1, const float* __restrict__ b1,
        const float* __restrict__ lw, const float* __restrict__ lb,
        const float* __restrict__ W2, const float* __restrict__ b2,
        const float* __restrict__ W3, const float* __restrict__ b3,
        const float* __restrict__ W4, const float* __restrict__ b4,
        const float* __restrict__ wtemp, float* wv) {
    __shared__ float h1[256], h2[192], h3[64], red[8];
    int t = threadIdx.x;
    int h = blockIdx.x;
    float p = 0.0f;
    for (int i = 0; i < 128; ++i) p += feat[h * 128 + i] * W1[i * 256 + t];
    p += b1[t];
    float s = p, s2 = p * p;
    for (int o = 32; o > 0; o >>= 1) { s += __shfl_down(s, o); s2 += __shfl_down(s2, o); }
    if ((t & 63) == 0) { red[t >> 6] = s; red[4 + (t >> 6)] = s2; }
    __syncthreads();
    float S = red[0] + red[1] + red[2] + red[3];
    float S2 = red[4] + red[5] + red[6] + red[7];
    float mu = S / 256.0f;
    float var = S2 / 256.0f - mu * mu; if (var < 0.0f) var = 0.0f;
    float xh = (p - mu) * rsqrtf(var + 1e-5f) * lw[t] + lb[t];
    h1[t] = fmaxf(xh, 0.0f);
    __syncthreads();
    if (t < 192) {
        float a = 0.0f;
        for (int i = 0; i < 256; ++i) a += h1[i] * W2[i * 192 + t];
        h2[t] = fmaxf(a + b2[t], 0.0f);
    }
    __syncthreads();
    if (t < 64) {
        float a = 0.0f;
        for (int i = 0; i < 192; ++i) a += h2[i] * W3[i * 64 + t];
        h3[t] = fmaxf(a + b3[t], 0.0f);
    }
    __syncthreads();
    if (t == 0) {
        float lg[3];
        for (int j = 0; j < 3; ++j) {
            float a = 0.0f;
            for (int i = 0; i < 64; ++i) a += h3[i] * W4[i * 3 + j];
            lg[j] = a + b4[j];
        }
        float mx = fmaxf(lg[0], fmaxf(lg[1], lg[2]));
        float e0 = expf(lg[0] - mx), e1 = expf(lg[1] - mx), e2 = expf(lg[2] - mx);
        float se = e0 + e1 + e2;
        float pr0 = e0 / se, pr1 = e1 / se, pr2 = e2 / se;
        float wt = wtemp[0]; wt = fminf(fmaxf(wt, 0.01f), 1.0f);
        float q0 = pr0 / wt, q1 = pr1 / wt, q2 = pr2 / wt;
        float m2 = fmaxf(q0, fmaxf(q1, q2));
        float f0 = expf(q0 - m2), f1 = expf(q1 - m2), f2 = expf(q2 - m2);
        float sf = f0 + f1 + f2; f0 /= sf; f1 /= sf; f2 /= sf;
        f0 = fminf(fmaxf(f0, 0.01f), 0.95f);
        f1 = fminf(fmaxf(f1, 0.01f), 0.95f);
        f2 = fminf(fmaxf(f2, 0.01f), 0.95f);
        float sw = f0 + f1 + f2;
        wv[h * 3 + 0] = f0 / sw; wv[h * 3 + 1] = f1 / sw; wv[h * 3 + 2] = f2 / sw;
    }
}

// ---- shared per-pass preamble (macro to keep A/B/C identical) ----
#define PASS_PREAMBLE                                                          \
    int hq = blockIdx.y;                                                       \
    int t = threadIdx.x, l = t & 63, w = t >> 6;                               \
    int lr = l & 15, kg = (l >> 4) * 8, rg4 = (l >> 4) * 4;                    \
    int nb = blockIdx.x * 128 + w * 32;                                        \
    const f16* Q = fq16 + (size_t)hq * 65536;                                  \
    const f16* K = fk16 + (size_t)hq * 65536;                                  \
    v8h aq[2][2];                                                              \
    _Pragma("unroll")                                                          \
    for (int g = 0; g < 2; ++g) {                                              \
        aq[g][0] = *(const v8h*)&Q[(size_t)(nb + g * 16 + lr) * 64 + kg];      \
        aq[g][1] = *(const v8h*)&Q[(size_t)(nb + g * 16 + lr) * 64 + 32 + kg]; \
    }                                                                          \
    const float inv1024 = 1.0f / 1024.0f;                                      \
    float uvp = nuacck[hq * 64 + l] * inv1024;                                 \
    _Pragma("unroll")                                                          \
    for (int o = 32; o > 0; o >>= 1) uvp += __shfl_xor(uvp, o);                \
    float uv = uvp;                                                            \
    float nu0[8], nu1[8];                                                      \
    _Pragma("unroll")                                                          \
    for (int e = 0; e < 8; ++e) {                                              \
        nu0[e] = nuacck[hq * 64 + kg + e] * inv1024;                           \
        nu1[e] = nuacck[hq * 64 + 32 + kg + e] * inv1024;                      \
    }                                                                          \
    float tnr[2];                                                              \
    _Pragma("unroll")                                                          \
    for (int g = 0; g < 2; ++g) {                                              \
        float tp = 0.f;                                                        \
        _Pragma("unroll")                                                      \
        for (int e = 0; e < 8; ++e)                                            \
            tp += (float)aq[g][0][e] * nu0[e] + (float)aq[g][1][e] * nu1[e];   \
        tp += __shfl_xor(tp, 16);                                              \
        tp += __shfl_xor(tp, 32);                                              \
        tnr[g] = tp;                                                           \
    }                                                                          \
    float nqv[2][4], muv[2][4], tv[2][4];                                      \
    _Pragma("unroll")                                                          \
    for (int g = 0; g < 2; ++g)                                                \
        _Pragma("unroll")                                                      \
        for (int r = 0; r < 4; ++r) {                                          \
            int row = hq * 1024 + nb + g * 16 + rg4 + r;                       \
            nqv[g][r] = nq[row]; muv[g][r] = muq[row];                         \
            tv[g][r] = __shfl(tnr[g], rg4 + r);                                \
        }                                                                      \
    const float covscale = 0.001f / 1024.0f;                                   \
    const float i8 = 1.0f / 8.0001f;

#define LOAD_KTILE                                                             \
    v8h b0[4], b1[4];                                                          \
    float nkv[4], skv[4];                                                      \
    _Pragma("unroll")                                                          \
    for (int j = 0; j < 4; ++j) {                                              \
        b0[j] = *(const v8h*)&K[(size_t)(m0 + j * 16 + lr) * 64 + kg];         \
        b1[j] = *(const v8h*)&K[(size_t)(m0 + j * 16 + lr) * 64 + 32 + kg];    \
        int cg = hq * 1024 + m0 + j * 16 + lr;                                 \
        nkv[j] = nk[cg]; skv[j] = sk[cg];                                      \
    }

// pass A: cos/cov global sums + per-row margin means
__global__ __launch_bounds__(256) void k_passA(const f16* __restrict__ fq16,
        const f16* __restrict__ fk16, const float* __restrict__ nq,
        const float* __restrict__ muq, const float* __restrict__ nk,
        const float* __restrict__ sk, const float* __restrict__ nuacck,
        float* __restrict__ vcrow, float* __restrict__ pb) {
    PASS_PREAMBLE
    float scos = 0, s2cos = 0, scov = 0, s2cov = 0;
    float mp[2][4] = {};
    for (int m0 = 0; m0 < 1024; m0 += 64) {
        LOAD_KTILE
        #pragma unroll
        for (int g = 0; g < 2; ++g) {
            v4f acc[4] = {};
            #pragma unroll
            for (int j = 0; j < 4; ++j) {
                acc[j] = MFMA(aq[g][0], b0[j], acc[j]);
                acc[j] = MFMA(aq[g][1], b1[j], acc[j]);
            }
            #pragma unroll
            for (int j = 0; j < 4; ++j)
                #pragma unroll
                for (int r = 0; r < 4; ++r) {
                    float rv = acc[j][r];
                    float c1 = nqv[g][r] + 1e-6f;
                    float c2 = fmaxf(nqv[g][r], 1e-4f);
                    float cosv = clampf(rv / (c1 * (nkv[j] + 1e-6f)), -0.95f, 0.95f);
                    float csv  = clampf(rv / (c2 * fmaxf(nkv[j], 1e-4f)), -0.95f, 0.95f);
                    float marg = clampf(0.01f - csv, 0.0f, 15.0f);
                    float cp = (rv - tv[g][r] - muv[g][r] * skv[j] + muv[g][r] * uv) * i8;
                    float cov = clampf(covscale * cp, -50.0f, 50.0f);
                    scos += cosv; s2cos += cosv * cosv;
                    scov += cov;  s2cov += cov * cov;
                    mp[g][r] += marg;
                }
        }
    }
    #pragma unroll
    for (int g = 0; g < 2; ++g)
        #pragma unroll
        for (int r = 0; r < 4; ++r) {
            float m_ = mp[g][r];
            m_ += __shfl_xor(m_, 1); m_ += __shfl_xor(m_, 2);
            m_ += __shfl_xor(m_, 4); m_ += __shfl_xor(m_, 8);
            if (lr == 0) vcrow[hq * 1024 + nb + g * 16 + rg4 + r] = m_ * inv1024;
        }
    for (int o = 32; o > 0; o >>= 1) {
        scos += __shfl_down(scos, o); s2cos += __shfl_down(s2cos, o);
        scov += __shfl_down(scov, o); s2cov += __shfl_down(s2cov, o);
    }
    __shared__ float bs[4][4];
    if (l == 0) { bs[w][0] = scos; bs[w][1] = s2cos; bs[w][2] = scov; bs[w][3] = s2cov; }
    __syncthreads();
    if (t == 0) {
        int bid = hq * 8 + blockIdx.x;
        pb[bid * 4 + 0] = bs[0][0] + bs[1][0] + bs[2][0] + bs[3][0];
        pb[bid * 4 + 1] = bs[0][1] + bs[1][1] + bs[2][1] + bs[3][1];
        pb[bid * 4 + 2] = bs[0][2] + bs[1][2] + bs[2][2] + bs[3][2];
        pb[bid * 4 + 3] = bs[0][3] + bs[1][3] + bs[2][3] + bs[3][3];
    }
}

__global__ __launch_bounds__(256) void k_fin1(const float* __restrict__ pb,
        const float* __restrict__ vcrow, float* __restrict__ scal) {
    int t = threadIdx.x;
    double s0 = 0, s1 = 0, s2 = 0, s3 = 0, s4 = 0, s5 = 0;
    for (int i = t; i < 256; i += 256) {
        s0 += pb[i * 4 + 0]; s1 += pb[i * 4 + 1];
        s2 += pb[i * 4 + 2]; s3 += pb[i * 4 + 3];
    }
    for (int i = t; i < 32768; i += 256) {
        double rm = (double)vcrow[i];
        s4 += rm; s5 += rm * rm;
    }
    for (int o = 32; o > 0; o >>= 1) {
        s0 += __shfl_down(s0, o); s1 += __shfl_down(s1, o); s2 += __shfl_down(s2, o);
        s3 += __shfl_down(s3, o); s4 += __shfl_down(s4, o); s5 += __shfl_down(s5, o);
    }
    __shared__ double red[6][4];
    int wid = t >> 6, lane = t & 63;
    if (lane == 0) { red[0][wid] = s0; red[1][wid] = s1; red[2][wid] = s2;
                     red[3][wid] = s3; red[4][wid] = s4; red[5][wid] = s5; }
    __syncthreads();
    if (t == 0) {
        double S0 = red[0][0] + red[0][1] + red[0][2] + red[0][3];
        double S1 = red[1][0] + red[1][1] + red[1][2] + red[1][3];
        double S2 = red[2][0] + red[2][1] + red[2][2] + red[2][3];
        double S3 = red[3][0] + red[3][1] + red[3][2] + red[3][3];
        double S4 = red[4][0] + red[4][1] + red[4][2] + red[4][3];
        double S5 = red[5][0] + red[5][1] + red[5][2] + red[5][3];
        const double cnt = 33554432.0;
        scal[0] = (float)sqrt(fmax(0.0, (S1 - S0 * S0 / cnt) / (cnt - 1.0)));
        scal[1] = (float)sqrt(fmax(0.0, (S3 - S2 * S2 / cnt) / (cnt - 1.0)));
        double V4 = S4 * 1024.0, V5 = S5 * 1024.0;
        scal[2] = (float)sqrt(fmax(0.0, (V5 - V4 * V4 / cnt) / (cnt - 1.0)));
    }
}

// pass B: dots sum/sumsq + row max
__global__ __launch_bounds__(256) void k_passB(const f16* __restrict__ fq16,
        const f16* __restrict__ fk16, const float* __restrict__ nq,
        const float* __restrict__ muq, const float* __restrict__ nk,
        const float* __restrict__ sk, const float* __restrict__ nuacck,
        const float* __restrict__ vcrow, const float* __restrict__ wv,
        const float* __restrict__ scal, float* __restrict__ rmax,
        float* __restrict__ pb2) {
    PASS_PREAMBLE
    int h = hq >> 2;
    float s1 = scal[0] + 1e-4f, s2v = scal[1] + 1e-4f, s3 = scal[2] + 1e-4f;
    float w0 = wv[h * 3], w1 = wv[h * 3 + 1], w2 = wv[h * 3 + 2];
    float fc1 = w0 / s1;
    float fc2 = w1 * 0.3f / s2v;
    float addc[2][4];
    #pragma unroll
    for (int g = 0; g < 2; ++g)
        #pragma unroll
        for (int r = 0; r < 4; ++r)
            addc[g][r] = w2 * (vcrow[hq * 1024 + nb + g * 16 + rg4 + r] / s3) * 0.3f;
    float sd = 0.f, s2d = 0.f;
    float dmax[2][4];
    #pragma unroll
    for (int g = 0; g < 2; ++g)
        #pragma unroll
        for (int r = 0; r < 4; ++r) dmax[g][r] = -1e30f;
    for (int m0 = 0; m0 < 1024; m0 += 64) {
        LOAD_KTILE
        #pragma unroll
        for (int g = 0; g < 2; ++g) {
            v4f acc[4] = {};
            #pragma unroll
            for (int j = 0; j < 4; ++j) {
                acc[j] = MFMA(aq[g][0], b0[j], acc[j]);
                acc[j] = MFMA(aq[g][1], b1[j], acc[j]);
            }
            #pragma unroll
            for (int j = 0; j < 4; ++j)
                #pragma unroll
                for (int r = 0; r < 4; ++r) {
                    float rv = acc[j][r];
                    float c1 = nqv[g][r] + 1e-6f;
                    float cosv = clampf(rv / (c1 * (nkv[j] + 1e-6f)), -0.95f, 0.95f);
                    float cp = (rv - tv[g][r] - muv[g][r] * skv[j] + muv[g][r] * uv) * i8;
                    float cov = clampf(covscale * cp, -50.0f, 50.0f);
                    float dd = fc1 * cosv + fc2 * cov + addc[g][r];
                    sd += dd; s2d += dd * dd;
                    dmax[g][r] = fmaxf(dmax[g][r], dd);
                }
        }
    }
    #pragma unroll
    for (int g = 0; g < 2; ++g)
        #pragma unroll
        for (int r = 0; r < 4; ++r) {
            float m_ = dmax[g][r];
            m_ = fmaxf(m_, __shfl_xor(m_, 1)); m_ = fmaxf(m_, __shfl_xor(m_, 2));
            m_ = fmaxf(m_, __shfl_xor(m_, 4)); m_ = fmaxf(m_, __shfl_xor(m_, 8));
            if (lr == 0) rmax[hq * 1024 + nb + g * 16 + rg4 + r] = m_;
        }
    for (int o = 32; o > 0; o >>= 1) { sd += __shfl_down(sd, o); s2d += __shfl_down(s2d, o); }
    __shared__ float fr[2][4];
    if (l == 0) { fr[0][w] = sd; fr[1][w] = s2d; }
    __syncthreads();
    if (t == 0) {
        int bid = hq * 8 + blockIdx.x;
        pb2[bid * 2 + 0] = fr[0][0] + fr[0][1] + fr[0][2] + fr[0][3];
        pb2[bid * 2 + 1] = fr[1][0] + fr[1][1] + fr[1][2] + fr[1][3];
    }
}

__global__ __launch_bounds__(256) void k_fin2(const float* __restrict__ pb2,
        float* __restrict__ scal) {
    int t = threadIdx.x;
    double s6 = 0, s7 = 0;
    for (int i = t; i < 256; i += 256) { s6 += pb2[i * 2]; s7 += pb2[i * 2 + 1]; }
    for (int o = 32; o > 0; o >>= 1) { s6 += __shfl_down(s6, o); s7 += __shfl_down(s7, o); }
    __shared__ double red[2][4];
    int wid = t >> 6, lane = t & 63;
    if (lane == 0) { red[0][wid] = s6; red[1][wid] = s7; }
    __syncthreads();
    if (t == 0) {
        double S6 = red[0][0] + red[0][1] + red[0][2] + red[0][3];
        double S7 = red[1][0] + red[1][1] + red[1][2] + red[1][3];
        const double cnt = 33554432.0;
        double ds = sqrt(fmax(0.0, (S7 - S6 * S6 / cnt) / (cnt - 1.0)));
        float temp = (ds < 1e-5) ? 0.01f : ((ds < 1e-3) ? 0.05f : (0.2f + (float)ds * 2.0f));
        temp = fminf(fmaxf(temp, 0.01f), 8.0f);
        scal[3] = temp;
    }
}

// pass C: dots -> exp -> in-LDS P -> fused PV (hi/lo V), normalized epilogue
__global__ __launch_bounds__(256) void k_passC(const f16* __restrict__ fq16,
        const f16* __restrict__ fk16, const float* __restrict__ nq,
        const float* __restrict__ muq, const float* __restrict__ nk,
        const float* __restrict__ sk, const float* __restrict__ nuacck,
        const float* __restrict__ vcrow, const float* __restrict__ wv,
        const float* __restrict__ scal, const float* __restrict__ rmax,
        const f16* __restrict__ fvhT, const f16* __restrict__ fvlT,
        f16* __restrict__ avh, f16* __restrict__ avl) {
    __shared__ f16 P[4][32][72];
    PASS_PREAMBLE
    int h = hq >> 2;
    float s1 = scal[0] + 1e-4f, s2v = scal[1] + 1e-4f, s3 = scal[2] + 1e-4f;
    float w0 = wv[h * 3], w1 = wv[h * 3 + 1], w2 = wv[h * 3 + 2];
    float fc1 = w0 / s1;
    float fc2 = w1 * 0.3f / s2v;
    float invt = 1.0f / scal[3];
    float addc[2][4], rmx[2][4];
    #pragma unroll
    for (int g = 0; g < 2; ++g)
        #pragma unroll
        for (int r = 0; r < 4; ++r) {
            int row = hq * 1024 + nb + g * 16 + rg4 + r;
            addc[g][r] = w2 * (vcrow[row] / s3) * 0.3f;
            rmx[g][r] = rmax[row];
        }
    v4f accpv[2][4] = {};
    float rsum[2][4] = {};
    for (int m0 = 0; m0 < 1024; m0 += 64) {
        LOAD_KTILE
        #pragma unroll
        for (int g = 0; g < 2; ++g) {
            v4f acc[4] = {};
            #pragma unroll
            for (int j = 0; j < 4; ++j) {
                acc[j] = MFMA(aq[g][0], b0[j], acc[j]);
                acc[j] = MFMA(aq[g][1], b1[j], acc[j]);
            }
            #pragma unroll
            for (int j = 0; j < 4; ++j)
                #pragma unroll
                for (int r = 0; r < 4; ++r) {
                    float rv = acc[j][r];
                    float c1 = nqv[g][r] + 1e-6f;
                    float cosv = clampf(rv / (c1 * (nkv[j] + 1e-6f)), -0.95f, 0.95f);
                    float cp = (rv - tv[g][r] - muv[g][r] * skv[j] + muv[g][r] * uv) * i8;
                    float cov = clampf(covscale * cp, -50.0f, 50.0f);
                    float dd = fc1 * cosv + fc2 * cov + addc[g][r];
                    float pe = __expf((dd - rmx[g][r]) * invt);
                    f16 p16 = (f16)pe;
                    rsum[g][r] += (float)p16;
                    P[w][g * 16 + rg4 + r][j * 16 + lr] = p16;
                }
        }
        __syncthreads();
        v8h pa[2][2];
        #pragma unroll
        for (int g = 0; g < 2; ++g) {
            pa[g][0] = *(const v8h*)&P[w][g * 16 + lr][kg];
            pa[g][1] = *(const v8h*)&P[w][g * 16 + lr][32 + kg];
        }
        #pragma unroll
        for (int j = 0; j < 4; ++j) {
            size_t vb = ((size_t)hq * 64 + j * 16 + lr) * 1024 + m0;
            v8h vh0 = *(const v8h*)&fvhT[vb + kg];
            v8h vh1 = *(const v8h*)&fvhT[vb + 32 + kg];
            v8h vl0 = *(const v8h*)&fvlT[vb + kg];
            v8h vl1 = *(const v8h*)&fvlT[vb + 32 + kg];
            #pragma unroll
            for (int g = 0; g < 2; ++g) {
                accpv[g][j] = MFMA(pa[g][0], vh0, accpv[g][j]);
                accpv[g][j] = MFMA(pa[g][1], vh1, accpv[g][j]);
                accpv[g][j] = MFMA(pa[g][0], vl0, accpv[g][j]);
                accpv[g][j] = MFMA(pa[g][1], vl1, accpv[g][j]);
            }
        }
        __syncthreads();
    }
    #pragma unroll
    for (int g = 0; g < 2; ++g)
        #pragma unroll
        for (int r = 0; r < 4; ++r) {
            float s = rsum[g][r];
            s += __shfl_xor(s, 1); s += __shfl_xor(s, 2);
            s += __shfl_xor(s, 4); s += __shfl_xor(s, 8);
            rsum[g][r] = 1.0f / s;
        }
    #pragma unroll
    for (int g = 0; g < 2; ++g)
        #pragma unroll
        for (int j = 0; j < 4; ++j)
            #pragma unroll
            for (int r = 0; r < 4; ++r) {
                float val = accpv[g][j][r] * rsum[g][r];
                size_t idx = ((size_t)(hq * 1024 + nb + g * 16 + rg4 + r)) * 64 + j * 16 + lr;
                f16 hi = (f16)val;
                avh[idx] = hi;
                avl[idx] = (f16)(val - (float)hi);
            }
}

// out = av @ Wout + bout (MFMA, 3-way split)
__global__ __launch_bounds__(256) void k_out_mfma(const f16* __restrict__ avh,
        const f16* __restrict__ avl,
        const f16* __restrict__ WoutTh, const f16* __restrict__ WoutTl,
        const float* __restrict__ bout, float* __restrict__ out) {
    __shared__ float red[2][4][4][4][64];
    int t = threadIdx.x, l = t & 63, w = t >> 6;
    int wc = w & 1, kh = w >> 1;
    int col0 = blockIdx.x * 128 + wc * 64;
    int tok0 = blockIdx.y * 64;
    int qi = tok0 >> 10, nb = tok0 & 1023;
    int lr = l & 15, kg = (l >> 4) * 8;
    v4f acc[4][4] = {};
    for (int ks8 = 0; ks8 < 8; ++ks8) {
        int ks = kh * 256 + ks8 * 32;
        int f = ks + kg;
        int h = f >> 6, d = f & 63;
        size_t hb = (size_t)((h << 2) + qi) * 1024;
        v8h ah[4], al4[4], bh[4], bl4[4];
        #pragma unroll
        for (int i = 0; i < 4; ++i) {
            int n = nb + i * 16 + lr;
            ah[i]  = *(const v8h*)&avh[(hb + n) * 64 + d];
            al4[i] = *(const v8h*)&avl[(hb + n) * 64 + d];
        }
        #pragma unroll
        for (int j = 0; j < 4; ++j) {
            bh[j]  = *(const v8h*)&WoutTh[(size_t)(col0 + j * 16 + lr) * 512 + ks + kg];
            bl4[j] = *(const v8h*)&WoutTl[(size_t)(col0 + j * 16 + lr) * 512 + ks + kg];
        }
        #pragma unroll
        for (int i = 0; i < 4; ++i)
            #pragma unroll
            for (int j = 0; j < 4; ++j) {
                acc[i][j] = MFMA(ah[i], bh[j], acc[i][j]);
                acc[i][j] = MFMA(ah[i], bl4[j], acc[i][j]);
                acc[i][j] = MFMA(al4[i], bh[j], acc[i][j]);
            }
    }
    if (kh == 0) {
        #pragma unroll
        for (int i = 0; i < 4; ++i)
            #pragma unroll
            for (int j = 0; j < 4; ++j)
                #pragma unroll
                for (int r = 0; r < 4; ++r)
                    red[wc][i][j][r][l] = acc[i][j][r];
    }
    __syncthreads();
    if (kh == 1) {
        #pragma unroll
        for (int i = 0; i < 4; ++i)
            #pragma unroll
            for (int j = 0; j < 4; ++j) {
                int col = col0 + j * 16 + lr;
                float bo = bout[col];
                #pragma unroll
                for (int r = 0; r < 4; ++r) {
                    float val = acc[i][j][r] + red[wc][i][j][r][l] + bo;
                    int token = tok0 + i * 16 + (l >> 4) * 4 + r;
                    out[(size_t)token * 512 + col] = val;
                }
            }
    }
}

extern "C" void kernel_launch(void* const* d_in, const int* in_sizes, int n_in,
                              void* d_out, int out_size, void* d_ws, size_t ws_size,
                              hipStream_t stream) {
    const float* q     = (const float*)d_in[0];
    const float* k     = (const float*)d_in[1];
    const float* v     = (const float*)d_in[2];
    const float* ln_w  = (const float*)d_in[3];
    const float* ln_b  = (const float*)d_in[4];
    const float* W_in  = (const float*)d_in[5];
    const float* W_out = (const float*)d_in[6];
    const float* b_out = (const float*)d_in[7];
    const float* wp_W1 = (const float*)d_in[8];
    const float* wp_b1 = (const float*)d_in[9];
    const float* wp_lw = (const float*)d_in[10];
    const float* wp_lb = (const float*)d_in[11];
    const float* wp_W2 = (const float*)d_in[12];
    const float* wp_b2 = (const float*)d_in[13];
    const float* wp_W3 = (const float*)d_in[14];
    const float* wp_b3 = (const float*)d_in[15];
    const float* wp_W4 = (const float*)d_in[16];
    const float* wp_b4 = (const float*)d_in[17];
    const float* wtemp = (const float*)d_in[18];

    float* ws = (float*)d_ws;
    f16* ln16     = (f16*)(ws + OFF_LN16);
    f16* lnlo     = (f16*)(ws + OFF_LNLO);
    f16* fq16     = (f16*)(ws + OFF_FQ16);
    f16* fk16     = (f16*)(ws + OFF_FK16);
    f16* fvhT     = (f16*)(ws + OFF_FVHT);
    f16* fvlT     = (f16*)(ws + OFF_FVLT);
    f16* WinTh    = (f16*)(ws + OFF_WINTH);
    f16* WinTl    = (f16*)(ws + OFF_WINTL);
    f16* WoutTh   = (f16*)(ws + OFF_WOUTTH);
    f16* WoutTl   = (f16*)(ws + OFF_WOUTTL);
    f16* avh      = (f16*)(ws + OFF_AVH);
    f16* avl      = (f16*)(ws + OFF_AVL);
    float* nq     = ws + OFF_NQ;
    float* muq    = ws + OFF_MUQ;
    float* nk     = ws + OFF_NK;
    float* sk     = ws + OFF_SK;
    float* vcrow  = ws + OFF_VC;
    float* rmax   = ws + OFF_RMAX;
    float* nuacck = ws + OFF_NUACC;
    float* pb     = ws + OFF_PB;
    float* pb2    = ws + OFF_PB2;
    float* feat   = ws + OFF_FEAT;
    float* wv     = ws + OFF_WV;
    float* scal   = ws + OFF_SCAL;

    k_zero<<<8, 256, 0, stream>>>(feat, nuacck);
    k_wprep<<<dim3(8, 8, 2), 256, 0, stream>>>(W_in, W_out, WinTh, WinTl, WoutTh, WoutTl);
    k_ln16<<<3072, 256, 0, stream>>>(q, k, v, ln_w, ln_b, ln16, lnlo);
    k_proj_mfma<0><<<dim3(4, 32), 256, 0, stream>>>(ln16, nullptr, WinTh, WinTl,
            fq16, nullptr, nullptr, nq, muq, feat, nullptr);
    k_proj_mfma<1><<<dim3(4, 32), 256, 0, stream>>>(ln16 + (size_t)4096 * 512, nullptr,
            WinTh, WinTl, fk16, nullptr, nullptr, nk, sk, feat, nuacck);
    k_proj_mfma<2><<<dim3(4, 32), 256, 0, stream>>>(ln16 + (size_t)8192 * 512, lnlo,
            WinTh, WinTl, nullptr, fvhT, fvlT, nullptr, nullptr, nullptr, nullptr);
    k_mlp<<<8, 256, 0, stream>>>(feat, wp_W1, wp_b1, wp_lw, wp_lb,
                                 wp_W2, wp_b2, wp_W3, wp_b3, wp_W4, wp_b4,
                                 wtemp, wv);
    k_passA<<<dim3(8, 32), 256, 0, stream>>>(fq16, fk16, nq, muq, nk, sk, nuacck,
                                             vcrow, pb);
    k_fin1<<<1, 256, 0, stream>>>(pb, vcrow, scal);
    k_passB<<<dim3(8, 32), 256, 0, stream>>>(fq16, fk16, nq, muq, nk, sk, nuacck,
                                             vcrow, wv, scal, rmax, pb2);
    k_fin2<<<1, 256, 0, stream>>>(pb2, scal);
    k_passC<<<dim3(8, 32), 256, 0, stream>>>(fq16, fk16, nq, muq, nk, sk, nuacck,
                                             vcrow, wv, scal, rmax, fvhT, fvlT,
                                             avh, avl);
    k_out_mfma<<<dim3(4, 64), 256, 0, stream>>>(avh, avl, WoutTh, WoutTl, b_out,
                                                (float*)d_out);
}

// Round 6
// 333.927 us; speedup vs baseline: 33.9465x; 1.1589x over previous
//
#include <hip/hip_runtime.h>
#include <math.h>

typedef _Float16 f16;
typedef _Float16 v8h __attribute__((ext_vector_type(8)));
typedef _Float16 v4h __attribute__((ext_vector_type(4)));
typedef float    v4f __attribute__((ext_vector_type(4)));

#define MFMA(a, b, c) __builtin_amdgcn_mfma_f32_16x16x32_f16((a), (b), (c), 0, 0, 0)

// ---------------- workspace layout (float offsets) ----------------
#define OFF_LN16    0u
#define OFF_LNLO    3145728u
#define OFF_FQ16    4194304u
#define OFF_FK16    5242880u
#define OFF_FVHT    6291456u
#define OFF_FVLT    7340032u
#define OFF_WINTH   8388608u
#define OFF_WINTL   8519680u
#define OFF_WOUTTH  8650752u
#define OFF_WOUTTL  8781824u
#define OFF_AVH     8912896u
#define OFF_AVL     9961472u
#define OFF_RQ1     11010048u
#define OFF_RQ2     11042816u
#define OFF_MUQ     11075584u
#define OFF_RK1     11108352u
#define OFF_RK2     11141120u
#define OFF_SK      11173888u
#define OFF_VC      11206656u
#define OFF_RMAX    11239424u
#define OFF_NUACC   11272192u   // 2048
#define OFF_PB      11274240u   // 512*4
#define OFF_PB2     11276288u   // 512*2
#define OFF_FEAT    11277312u   // 1024
#define OFF_WV      11278336u   // 24
#define OFF_SCAL    11278360u   // 8
#define OFF_DOTS    11278368u   // f16[32*1024*1024] = 16777216 floats

__device__ __forceinline__ float clampf(float x, float lo, float hi) {
    return fminf(fmaxf(x, lo), hi);
}

__global__ void k_zero(float* feat, float* nuacck) {
    int i = blockIdx.x * 256 + threadIdx.x;
    if (i < 1024) feat[i] = 0.0f;
    if (i < 2048) nuacck[i] = 0.0f;
}

// transpose + hi/lo split of a 512x512 weight: W[k][c] -> WT{h,l}[c][k]
__global__ __launch_bounds__(256) void k_wprep(const float* __restrict__ Win,
        const float* __restrict__ Wout, f16* __restrict__ WinTh, f16* __restrict__ WinTl,
        f16* __restrict__ WoutTh, f16* __restrict__ WoutTl) {
    __shared__ float lds[64][68];
    const float* W = blockIdx.z ? Wout : Win;
    f16* Th = blockIdx.z ? WoutTh : WinTh;
    f16* Tl = blockIdx.z ? WoutTl : WinTl;
    int k0 = blockIdx.y * 64, c0 = blockIdx.x * 64;
    int t = threadIdx.x;
    #pragma unroll
    for (int p = 0; p < 4; ++p) {
        int flat = p * 1024 + t * 4;
        int r = flat >> 6, c = flat & 63;
        *(float4*)&lds[r][c] = *(const float4*)&W[(size_t)(k0 + r) * 512 + c0 + c];
    }
    __syncthreads();
    int c = t >> 2, kk = (t & 3) * 16;
    #pragma unroll
    for (int half = 0; half < 2; ++half) {
        v8h h8, l8;
        #pragma unroll
        for (int ii = 0; ii < 8; ++ii) {
            float v = lds[kk + half * 8 + ii][c];
            f16 h = (f16)v;
            h8[ii] = h;
            l8[ii] = (f16)(v - (float)h);
        }
        *(v8h*)&Th[(size_t)(c0 + c) * 512 + k0 + kk + half * 8] = h8;
        *(v8h*)&Tl[(size_t)(c0 + c) * 512 + k0 + kk + half * 8] = l8;
    }
}

// LayerNorm all 12288 tokens -> ln16 f16; v tokens also get lo residual
__global__ __launch_bounds__(256) void k_ln16(const float* __restrict__ q,
        const float* __restrict__ kk, const float* __restrict__ v,
        const float* __restrict__ lnw, const float* __restrict__ lnb,
        f16* __restrict__ ln16, f16* __restrict__ lnlo) {
    int t = threadIdx.x, wid = t >> 6, lane = t & 63;
    int token = blockIdx.x * 4 + wid;
    int inp = token >> 12, lt = token & 4095;
    const float* xp = (inp == 0) ? q : ((inp == 1) ? kk : v);
    const float4* xr = (const float4*)(xp + (size_t)lt * 512);
    float4 a = xr[lane], b = xr[lane + 64];
    float s = a.x + a.y + a.z + a.w + b.x + b.y + b.z + b.w;
    float s2 = a.x*a.x + a.y*a.y + a.z*a.z + a.w*a.w
             + b.x*b.x + b.y*b.y + b.z*b.z + b.w*b.w;
    for (int o = 32; o > 0; o >>= 1) { s += __shfl_down(s, o); s2 += __shfl_down(s2, o); }
    float m_ = __shfl(s, 0) * (1.0f / 512.0f);
    float var = __shfl(s2, 0) * (1.0f / 512.0f) - m_ * m_;
    var = fmaxf(var, 0.0f);
    float rs = rsqrtf(var + 1e-5f);
    const float4* w4 = (const float4*)lnw;
    const float4* b4 = (const float4*)lnb;
    float4 wa = w4[lane], wb = w4[lane + 64], ba = b4[lane], bb = b4[lane + 64];
    float ga[4] = { (a.x - m_) * rs * wa.x + ba.x, (a.y - m_) * rs * wa.y + ba.y,
                    (a.z - m_) * rs * wa.z + ba.z, (a.w - m_) * rs * wa.w + ba.w };
    float gb[4] = { (b.x - m_) * rs * wb.x + bb.x, (b.y - m_) * rs * wb.y + bb.y,
                    (b.z - m_) * rs * wb.z + bb.z, (b.w - m_) * rs * wb.w + bb.w };
    f16* orow = ln16 + (size_t)token * 512;
    v4h ha, hb;
    #pragma unroll
    for (int i = 0; i < 4; ++i) { ha[i] = (f16)ga[i]; hb[i] = (f16)gb[i]; }
    *(v4h*)&orow[lane * 4] = ha;
    *(v4h*)&orow[lane * 4 + 256] = hb;
    if (inp == 2) {
        f16* lrow = lnlo + (size_t)lt * 512;
        v4h la, lb;
        #pragma unroll
        for (int i = 0; i < 4; ++i) {
            la[i] = (f16)(ga[i] - (float)ha[i]);
            lb[i] = (f16)(gb[i] - (float)hb[i]);
        }
        *(v4h*)&lrow[lane * 4] = la;
        *(v4h*)&lrow[lane * 4 + 256] = lb;
    }
}

// LN16 @ Win (MFMA). MODE 0: q (fq16 + recip stats). MODE 1: k. MODE 2: v.
template<int MODE>
__global__ __launch_bounds__(256) void k_proj_mfma(const f16* __restrict__ A16,
        const f16* __restrict__ Alo,
        const f16* __restrict__ BTh, const f16* __restrict__ BTl,
        f16* __restrict__ fout16, f16* __restrict__ fhT, f16* __restrict__ flT,
        float* __restrict__ oA, float* __restrict__ oB, float* __restrict__ oC,
        float* __restrict__ feat, float* __restrict__ nuacck) {
    int t = threadIdx.x, l = t & 63, w = t >> 6;
    int wr = w >> 1, wc = w & 1;
    int col0 = blockIdx.x * 128 + wc * 64;
    int tok0 = blockIdx.y * 128 + wr * 64;
    int lr = l & 15, kg = (l >> 4) * 8;
    int rg4 = (l >> 4) * 4;
    v4f acc[4][4] = {};
    for (int ks = 0; ks < 512; ks += 32) {
        v8h a[4], b[4];
        #pragma unroll
        for (int i = 0; i < 4; ++i)
            a[i] = *(const v8h*)&A16[(size_t)(tok0 + i * 16 + lr) * 512 + ks + kg];
        #pragma unroll
        for (int j = 0; j < 4; ++j)
            b[j] = *(const v8h*)&BTh[(size_t)(col0 + j * 16 + lr) * 512 + ks + kg];
        if constexpr (MODE == 2) {
            v8h al[4], bl[4];
            #pragma unroll
            for (int i = 0; i < 4; ++i)
                al[i] = *(const v8h*)&Alo[(size_t)(tok0 + i * 16 + lr) * 512 + ks + kg];
            #pragma unroll
            for (int j = 0; j < 4; ++j)
                bl[j] = *(const v8h*)&BTl[(size_t)(col0 + j * 16 + lr) * 512 + ks + kg];
            #pragma unroll
            for (int i = 0; i < 4; ++i)
                #pragma unroll
                for (int j = 0; j < 4; ++j) {
                    acc[i][j] = MFMA(a[i], b[j], acc[i][j]);
                    acc[i][j] = MFMA(a[i], bl[j], acc[i][j]);
                    acc[i][j] = MFMA(al[i], b[j], acc[i][j]);
                }
        } else {
            #pragma unroll
            for (int i = 0; i < 4; ++i)
                #pragma unroll
                for (int j = 0; j < 4; ++j)
                    acc[i][j] = MFMA(a[i], b[j], acc[i][j]);
        }
    }
    int h = col0 >> 6;
    #pragma unroll
    for (int i = 0; i < 4; ++i)
        #pragma unroll
        for (int j = 0; j < 4; ++j)
            #pragma unroll
            for (int r = 0; r < 4; ++r) {
                int token = tok0 + i * 16 + rg4 + r;
                int d = j * 16 + lr;
                int qi = token >> 10, n = token & 1023;
                float val = acc[i][j][r];
                if constexpr (MODE != 2) {
                    fout16[((size_t)((h << 2) + qi) * 1024 + n) * 64 + d] = (f16)val;
                } else {
                    f16 hi = (f16)val;
                    fhT[((size_t)((h << 2) + qi) * 64 + d) * 1024 + n] = hi;
                    flT[((size_t)((h << 2) + qi) * 64 + d) * 1024 + n] = (f16)(val - (float)hi);
                }
            }
    if constexpr (MODE != 2) {
        #pragma unroll
        for (int i = 0; i < 4; ++i)
            #pragma unroll
            for (int r = 0; r < 4; ++r) {
                float s = 0.f, s2 = 0.f;
                #pragma unroll
                for (int j = 0; j < 4; ++j) { float v = acc[i][j][r]; s += v; s2 += v * v; }
                #pragma unroll
                for (int mk = 1; mk <= 8; mk <<= 1) {
                    s += __shfl_xor(s, mk); s2 += __shfl_xor(s2, mk);
                }
                if (lr == 0) {
                    int token = tok0 + i * 16 + rg4 + r;
                    int qi = token >> 10, n = token & 1023;
                    int row = ((h << 2) + qi) * 1024 + n;
                    float nv = sqrtf(s2);
                    oA[row] = 1.0f / (nv + 1e-6f);
                    oB[row] = 1.0f / fmaxf(nv, 1e-4f);
                    oC[row] = (MODE == 0) ? s * (1.0f / 64.0f) : s;
                }
            }
        float cs[4];
        #pragma unroll
        for (int j = 0; j < 4; ++j) {
            float c = 0.f;
            #pragma unroll
            for (int i = 0; i < 4; ++i)
                #pragma unroll
                for (int r = 0; r < 4; ++r) c += acc[i][j][r];
            c += __shfl_xor(c, 16); c += __shfl_xor(c, 32);
            cs[j] = c;
        }
        if (l < 16) {
            #pragma unroll
            for (int j = 0; j < 4; ++j)
                atomicAdd(&feat[h * 128 + (MODE == 1 ? 64 : 0) + j * 16 + l],
                          cs[j] * (1.0f / 4096.0f));
            if constexpr (MODE == 1) {
                int qi = tok0 >> 10;
                #pragma unroll
                for (int j = 0; j < 4; ++j)
                    atomicAdd(&nuacck[((h << 2) + qi) * 64 + j * 16 + l], cs[j]);
            }
        }
    }
}

// tiny MLP weight predictor, one block per head -> wv[h][3]
__global__ __launch_bounds__(256) void k_mlp(const float* __restrict__ feat,
        const float* __restrict__ W1, const float* __restrict__ b1,
        const float* __restrict__ lw, const float* __restrict__ lb,
        const float* __restrict__ W2, const float* __restrict__ b2,
        const float* __restrict__ W3, const float* __restrict__ b3,
        const float* __restrict__ W4, const float* __restrict__ b4,
        const float* __restrict__ wtemp, float* wv) {
    __shared__ float h1[256], h2[192], h3[64], red[8];
    int t = threadIdx.x;
    int h = blockIdx.x;
    float p = 0.0f;
    for (int i = 0; i < 128; ++i) p += feat[h * 128 + i] * W1[i * 256 + t];
    p += b1[t];
    float s = p, s2 = p * p;
    for (int o = 32; o > 0; o >>= 1) { s += __shfl_down(s, o); s2 += __shfl_down(s2, o); }
    if ((t & 63) == 0) { red[t >> 6] = s; red[4 + (t >> 6)] = s2; }
    __syncthreads();
    float S = red[0] + red[1] + red[2] + red[3];
    float S2 = red[4] + red[5] + red[6] + red[7];
    float mu = S / 256.0f;
    float var = S2 / 256.0f - mu * mu; if (var < 0.0f) var = 0.0f;
    float xh = (p - mu) * rsqrtf(var + 1e-5f) * lw[t] + lb[t];
    h1[t] = fmaxf(xh, 0.0f);
    __syncthreads();
    if (t < 192) {
        float a = 0.0f;
        for (int i = 0; i < 256; ++i) a += h1[i] * W2[i * 192 + t];
        h2[t] = fmaxf(a + b2[t], 0.0f);
    }
    __syncthreads();
    if (t < 64) {
        float a = 0.0f;
        for (int i = 0; i < 192; ++i) a += h2[i] * W3[i * 64 + t];
        h3[t] = fmaxf(a + b3[t], 0.0f);
    }
    __syncthreads();
    if (t == 0) {
        float lg[3];
        for (int j = 0; j < 3; ++j) {
            float a = 0.0f;
            for (int i = 0; i < 64; ++i) a += h3[i] * W4[i * 3 + j];
            lg[j] = a + b4[j];
        }
        float mx = fmaxf(lg[0], fmaxf(lg[1], lg[2]));
        float e0 = expf(lg[0] - mx), e1 = expf(lg[1] - mx), e2 = expf(lg[2] - mx);
        float se = e0 + e1 + e2;
        float pr0 = e0 / se, pr1 = e1 / se, pr2 = e2 / se;
        float wt = wtemp[0]; wt = fminf(fmaxf(wt, 0.01f), 1.0f);
        float q0 = pr0 / wt, q1 = pr1 / wt, q2 = pr2 / wt;
        float m2 = fmaxf(q0, fmaxf(q1, q2));
        float f0 = expf(q0 - m2), f1 = expf(q1 - m2), f2 = expf(q2 - m2);
        float sf = f0 + f1 + f2; f0 /= sf; f1 /= sf; f2 /= sf;
        f0 = fminf(fmaxf(f0, 0.01f), 0.95f);
        f1 = fminf(fmaxf(f1, 0.01f), 0.95f);
        f2 = fminf(fmaxf(f2, 0.01f), 0.95f);
        float sw = f0 + f1 + f2;
        wv[h * 3 + 0] = f0 / sw; wv[h * 3 + 1] = f1 / sw; wv[h * 3 + 2] = f2 / sw;
    }
}

// ---- shared per-pass preamble: 16 rows per wave, grid (16, 32) ----
#define PASS_PREAMBLE                                                          \
    int hq = blockIdx.y;                                                       \
    int t = threadIdx.x, l = t & 63, w = t >> 6;                               \
    int lr = l & 15, kg = (l >> 4) * 8, rg4 = (l >> 4) * 4;                    \
    int nb = blockIdx.x * 64 + w * 16;                                         \
    const f16* Q = fq16 + (size_t)hq * 65536;                                  \
    const f16* K = fk16 + (size_t)hq * 65536;                                  \
    v8h aq0 = *(const v8h*)&Q[(size_t)(nb + lr) * 64 + kg];                    \
    v8h aq1 = *(const v8h*)&Q[(size_t)(nb + lr) * 64 + 32 + kg];               \
    const float inv1024 = 1.0f / 1024.0f;                                      \
    float uvp = nuacck[hq * 64 + l] * inv1024;                                 \
    _Pragma("unroll")                                                          \
    for (int o = 32; o > 0; o >>= 1) uvp += __shfl_xor(uvp, o);                \
    float uv = uvp;                                                            \
    float tp = 0.f;                                                            \
    _Pragma("unroll")                                                          \
    for (int e = 0; e < 8; ++e)                                                \
        tp += (float)aq0[e] * nuacck[hq * 64 + kg + e]                         \
            + (float)aq1[e] * nuacck[hq * 64 + 32 + kg + e];                   \
    tp *= inv1024;                                                             \
    tp += __shfl_xor(tp, 16);                                                  \
    tp += __shfl_xor(tp, 32);                                                  \
    float muv[4], tv[4];                                                       \
    _Pragma("unroll")                                                          \
    for (int r = 0; r < 4; ++r) {                                              \
        muv[r] = muq[hq * 1024 + nb + rg4 + r];                                \
        tv[r] = __shfl(tp, rg4 + r);                                           \
    }                                                                          \
    const float Acs = (0.001f / 1024.0f) / 8.0001f;                            \
    float Pr[4], Gr[4];                                                        \
    _Pragma("unroll")                                                          \
    for (int r = 0; r < 4; ++r) {                                              \
        Gr[r] = Acs * muv[r];                                                  \
        Pr[r] = Acs * fmaf(muv[r], uv, -tv[r]);                                \
    }

#define LOAD_KTILE                                                             \
    v8h b0[4], b1[4];                                                          \
    _Pragma("unroll")                                                          \
    for (int j = 0; j < 4; ++j) {                                              \
        b0[j] = *(const v8h*)&K[(size_t)(m0 + j * 16 + lr) * 64 + kg];         \
        b1[j] = *(const v8h*)&K[(size_t)(m0 + j * 16 + lr) * 64 + 32 + kg];    \
    }

// pass A: cos/cov global sums + per-row margin means
__global__ __launch_bounds__(256) void k_passA(const f16* __restrict__ fq16,
        const f16* __restrict__ fk16, const float* __restrict__ rq1,
        const float* __restrict__ rq2, const float* __restrict__ muq,
        const float* __restrict__ rk1, const float* __restrict__ rk2,
        const float* __restrict__ sk, const float* __restrict__ nuacck,
        float* __restrict__ vcrow, float* __restrict__ pb) {
    PASS_PREAMBLE
    float rq1v[4], rq2v[4];
    #pragma unroll
    for (int r = 0; r < 4; ++r) {
        rq1v[r] = rq1[hq * 1024 + nb + rg4 + r];
        rq2v[r] = rq2[hq * 1024 + nb + rg4 + r];
    }
    float scos = 0, s2cos = 0, scov = 0, s2cov = 0;
    float mp[4] = {};
    for (int m0 = 0; m0 < 1024; m0 += 64) {
        LOAD_KTILE
        float rk1v[4], rk2v[4], skv[4];
        #pragma unroll
        for (int j = 0; j < 4; ++j) {
            int cg = hq * 1024 + m0 + j * 16 + lr;
            rk1v[j] = rk1[cg]; rk2v[j] = rk2[cg]; skv[j] = sk[cg];
        }
        v4f acc[4] = {};
        #pragma unroll
        for (int j = 0; j < 4; ++j) {
            acc[j] = MFMA(aq0, b0[j], acc[j]);
            acc[j] = MFMA(aq1, b1[j], acc[j]);
        }
        #pragma unroll
        for (int j = 0; j < 4; ++j)
            #pragma unroll
            for (int r = 0; r < 4; ++r) {
                float rv = acc[j][r];
                float cosv = clampf(rv * rq1v[r] * rk1v[j], -0.95f, 0.95f);
                float x2 = rv * rq2v[r] * rk2v[j];
                float marg = fmaxf(0.01f - fmaxf(x2, -0.95f), 0.0f);
                float cov = clampf(fmaf(-Gr[r], skv[j], fmaf(Acs, rv, Pr[r])),
                                   -50.0f, 50.0f);
                scos += cosv; s2cos = fmaf(cosv, cosv, s2cos);
                scov += cov;  s2cov = fmaf(cov, cov, s2cov);
                mp[r] += marg;
            }
    }
    #pragma unroll
    for (int r = 0; r < 4; ++r) {
        float m_ = mp[r];
        m_ += __shfl_xor(m_, 1); m_ += __shfl_xor(m_, 2);
        m_ += __shfl_xor(m_, 4); m_ += __shfl_xor(m_, 8);
        if (lr == 0) vcrow[hq * 1024 + nb + rg4 + r] = m_ * inv1024;
    }
    for (int o = 32; o > 0; o >>= 1) {
        scos += __shfl_down(scos, o); s2cos += __shfl_down(s2cos, o);
        scov += __shfl_down(scov, o); s2cov += __shfl_down(s2cov, o);
    }
    __shared__ float bs[4][4];
    if (l == 0) { bs[w][0] = scos; bs[w][1] = s2cos; bs[w][2] = scov; bs[w][3] = s2cov; }
    __syncthreads();
    if (t == 0) {
        int bid = hq * 16 + blockIdx.x;
        pb[bid * 4 + 0] = bs[0][0] + bs[1][0] + bs[2][0] + bs[3][0];
        pb[bid * 4 + 1] = bs[0][1] + bs[1][1] + bs[2][1] + bs[3][1];
        pb[bid * 4 + 2] = bs[0][2] + bs[1][2] + bs[2][2] + bs[3][2];
        pb[bid * 4 + 3] = bs[0][3] + bs[1][3] + bs[2][3] + bs[3][3];
    }
}

__global__ __launch_bounds__(256) void k_fin1(const float* __restrict__ pb,
        const float* __restrict__ vcrow, float* __restrict__ scal) {
    int t = threadIdx.x;
    double s0 = 0, s1 = 0, s2 = 0, s3 = 0, s4 = 0, s5 = 0;
    for (int i = t; i < 512; i += 256) {
        s0 += pb[i * 4 + 0]; s1 += pb[i * 4 + 1];
        s2 += pb[i * 4 + 2]; s3 += pb[i * 4 + 3];
    }
    for (int i = t; i < 32768; i += 256) {
        double rm = (double)vcrow[i];
        s4 += rm; s5 += rm * rm;
    }
    for (int o = 32; o > 0; o >>= 1) {
        s0 += __shfl_down(s0, o); s1 += __shfl_down(s1, o); s2 += __shfl_down(s2, o);
        s3 += __shfl_down(s3, o); s4 += __shfl_down(s4, o); s5 += __shfl_down(s5, o);
    }
    __shared__ double red[6][4];
    int wid = t >> 6, lane = t & 63;
    if (lane == 0) { red[0][wid] = s0; red[1][wid] = s1; red[2][wid] = s2;
                     red[3][wid] = s3; red[4][wid] = s4; red[5][wid] = s5; }
    __syncthreads();
    if (t == 0) {
        double S0 = red[0][0] + red[0][1] + red[0][2] + red[0][3];
        double S1 = red[1][0] + red[1][1] + red[1][2] + red[1][3];
        double S2 = red[2][0] + red[2][1] + red[2][2] + red[2][3];
        double S3 = red[3][0] + red[3][1] + red[3][2] + red[3][3];
        double S4 = red[4][0] + red[4][1] + red[4][2] + red[4][3];
        double S5 = red[5][0] + red[5][1] + red[5][2] + red[5][3];
        const double cnt = 33554432.0;
        scal[0] = (float)sqrt(fmax(0.0, (S1 - S0 * S0 / cnt) / (cnt - 1.0)));
        scal[1] = (float)sqrt(fmax(0.0, (S3 - S2 * S2 / cnt) / (cnt - 1.0)));
        double V4 = S4 * 1024.0, V5 = S5 * 1024.0;
        scal[2] = (float)sqrt(fmax(0.0, (V5 - V4 * V4 / cnt) / (cnt - 1.0)));
    }
}

// pass B: dots -> f16 buffer (coalesced via wave-private LDS), sum/sumsq, row max
__global__ __launch_bounds__(256) void k_passB(const f16* __restrict__ fq16,
        const f16* __restrict__ fk16, const float* __restrict__ rq1,
        const float* __restrict__ muq, const float* __restrict__ rk1,
        const float* __restrict__ sk, const float* __restrict__ nuacck,
        const float* __restrict__ vcrow, const float* __restrict__ wv,
        const float* __restrict__ scal, float* __restrict__ rmax,
        f16* __restrict__ dots, float* __restrict__ pb2) {
    __shared__ f16 P[4][16][72];
    PASS_PREAMBLE
    int h = hq >> 2;
    float s1 = scal[0] + 1e-4f, s2v = scal[1] + 1e-4f, s3 = scal[2] + 1e-4f;
    float w0 = wv[h * 3], w1 = wv[h * 3 + 1], w2 = wv[h * 3 + 2];
    float fc1 = w0 / s1;
    float fc2 = w1 * 0.3f / s2v;
    float c3 = w2 * 0.3f / s3;
    float rq1v[4], addc[4];
    #pragma unroll
    for (int r = 0; r < 4; ++r) {
        int row = hq * 1024 + nb + rg4 + r;
        rq1v[r] = rq1[row];
        addc[r] = vcrow[row] * c3;
    }
    float sd = 0.f, s2d = 0.f;
    float dmax[4] = { -1e30f, -1e30f, -1e30f, -1e30f };
    int rr = l & 15, cg = (l >> 4) * 8;
    for (int m0 = 0; m0 < 1024; m0 += 64) {
        LOAD_KTILE
        float rk1v[4], skv[4];
        #pragma unroll
        for (int j = 0; j < 4; ++j) {
            int cgl = hq * 1024 + m0 + j * 16 + lr;
            rk1v[j] = rk1[cgl]; skv[j] = sk[cgl];
        }
        v4f acc[4] = {};
        #pragma unroll
        for (int j = 0; j < 4; ++j) {
            acc[j] = MFMA(aq0, b0[j], acc[j]);
            acc[j] = MFMA(aq1, b1[j], acc[j]);
        }
        #pragma unroll
        for (int j = 0; j < 4; ++j)
            #pragma unroll
            for (int r = 0; r < 4; ++r) {
                float rv = acc[j][r];
                float cosv = clampf(rv * rq1v[r] * rk1v[j], -0.95f, 0.95f);
                float cov = clampf(fmaf(-Gr[r], skv[j], fmaf(Acs, rv, Pr[r])),
                                   -50.0f, 50.0f);
                float dd = fmaf(fc2, cov, fmaf(fc1, cosv, addc[r]));
                sd += dd; s2d = fmaf(dd, dd, s2d);
                dmax[r] = fmaxf(dmax[r], dd);
                P[w][rg4 + r][j * 16 + lr] = (f16)dd;
            }
        // coalesced store of this wave's 16x64 dots tile
        v8h d0 = *(const v8h*)&P[w][rr][cg];
        v8h d1 = *(const v8h*)&P[w][rr][32 + cg];
        f16* DP = dots + ((size_t)(hq * 1024 + nb + rr)) * 1024 + m0;
        *(v8h*)&DP[cg] = d0;
        *(v8h*)&DP[32 + cg] = d1;
    }
    #pragma unroll
    for (int r = 0; r < 4; ++r) {
        float m_ = dmax[r];
        m_ = fmaxf(m_, __shfl_xor(m_, 1)); m_ = fmaxf(m_, __shfl_xor(m_, 2));
        m_ = fmaxf(m_, __shfl_xor(m_, 4)); m_ = fmaxf(m_, __shfl_xor(m_, 8));
        if (lr == 0) rmax[hq * 1024 + nb + rg4 + r] = m_;
    }
    for (int o = 32; o > 0; o >>= 1) { sd += __shfl_down(sd, o); s2d += __shfl_down(s2d, o); }
    __shared__ float fr[2][4];
    if (l == 0) { fr[0][w] = sd; fr[1][w] = s2d; }
    __syncthreads();
    if (t == 0) {
        int bid = hq * 16 + blockIdx.x;
        pb2[bid * 2 + 0] = fr[0][0] + fr[0][1] + fr[0][2] + fr[0][3];
        pb2[bid * 2 + 1] = fr[1][0] + fr[1][1] + fr[1][2] + fr[1][3];
    }
}

__global__ __launch_bounds__(256) void k_fin2(const float* __restrict__ pb2,
        float* __restrict__ scal) {
    int t = threadIdx.x;
    double s6 = 0, s7 = 0;
    for (int i = t; i < 512; i += 256) { s6 += pb2[i * 2]; s7 += pb2[i * 2 + 1]; }
    for (int o = 32; o > 0; o >>= 1) { s6 += __shfl_down(s6, o); s7 += __shfl_down(s7, o); }
    __shared__ double red[2][4];
    int wid = t >> 6, lane = t & 63;
    if (lane == 0) { red[0][wid] = s6; red[1][wid] = s7; }
    __syncthreads();
    if (t == 0) {
        double S6 = red[0][0] + red[0][1] + red[0][2] + red[0][3];
        double S7 = red[1][0] + red[1][1] + red[1][2] + red[1][3];
        const double cnt = 33554432.0;
        double ds = sqrt(fmax(0.0, (S7 - S6 * S6 / cnt) / (cnt - 1.0)));
        float temp = (ds < 1e-5) ? 0.01f : ((ds < 1e-3) ? 0.05f : (0.2f + (float)ds * 2.0f));
        temp = fminf(fmaxf(temp, 0.01f), 8.0f);
        scal[3] = temp;
    }
}

// pass C: read f16 dots -> exp -> PV MFMA (hi/lo V) -> normalized av
__global__ __launch_bounds__(256) void k_passC(const f16* __restrict__ dots,
        const float* __restrict__ rmax, const float* __restrict__ scal,
        const f16* __restrict__ fvhT, const f16* __restrict__ fvlT,
        f16* __restrict__ avh, f16* __restrict__ avl) {
    int hq = blockIdx.y;
    int t = threadIdx.x, l = t & 63, w = t >> 6;
    int lr = l & 15, kg = (l >> 4) * 8, rg4 = (l >> 4) * 4;
    int nb = blockIdx.x * 64 + w * 16;
    int row = hq * 1024 + nb + lr;
    float invt = 1.0f / scal[3];
    float rmi = rmax[row] * invt;
    const f16* D = dots + (size_t)row * 1024;
    v4f acc[4] = {};
    float rs = 0.f;
    for (int ks = 0; ks < 1024; ks += 32) {
        v8h dv = *(const v8h*)&D[ks + kg];
        v8h pa;
        #pragma unroll
        for (int e = 0; e < 8; ++e) {
            float pe = __expf(fmaf((float)dv[e], invt, -rmi));
            f16 p16 = (f16)pe;
            pa[e] = p16;
            rs += (float)p16;
        }
        #pragma unroll
        for (int j = 0; j < 4; ++j) {
            size_t vb = ((size_t)hq * 64 + j * 16 + lr) * 1024 + ks + kg;
            v8h vh = *(const v8h*)&fvhT[vb];
            v8h vl = *(const v8h*)&fvlT[vb];
            acc[j] = MFMA(pa, vh, acc[j]);
            acc[j] = MFMA(pa, vl, acc[j]);
        }
    }
    rs += __shfl_xor(rs, 16);
    rs += __shfl_xor(rs, 32);
    float rinv[4];
    #pragma unroll
    for (int r = 0; r < 4; ++r) rinv[r] = 1.0f / __shfl(rs, rg4 + r);
    #pragma unroll
    for (int j = 0; j < 4; ++j)
        #pragma unroll
        for (int r = 0; r < 4; ++r) {
            float val = acc[j][r] * rinv[r];
            size_t idx = ((size_t)(hq * 1024 + nb + rg4 + r)) * 64 + j * 16 + lr;
            f16 hi = (f16)val;
            avh[idx] = hi;
            avl[idx] = (f16)(val - (float)hi);
        }
}

// out = av @ Wout + bout (MFMA, 3-way split)
__global__ __launch_bounds__(256) void k_out_mfma(const f16* __restrict__ avh,
        const f16* __restrict__ avl,
        const f16* __restrict__ WoutTh, const f16* __restrict__ WoutTl,
        const float* __restrict__ bout, float* __restrict__ out) {
    __shared__ float red[2][4][4][4][64];
    int t = threadIdx.x, l = t & 63, w = t >> 6;
    int wc = w & 1, kh = w >> 1;
    int col0 = blockIdx.x * 128 + wc * 64;
    int tok0 = blockIdx.y * 64;
    int qi = tok0 >> 10, nb = tok0 & 1023;
    int lr = l & 15, kg = (l >> 4) * 8;
    v4f acc[4][4] = {};
    for (int ks8 = 0; ks8 < 8; ++ks8) {
        int ks = kh * 256 + ks8 * 32;
        int f = ks + kg;
        int h = f >> 6, d = f & 63;
        size_t hb = (size_t)((h << 2) + qi) * 1024;
        v8h ah[4], al4[4], bh[4], bl4[4];
        #pragma unroll
        for (int i = 0; i < 4; ++i) {
            int n = nb + i * 16 + lr;
            ah[i]  = *(const v8h*)&avh[(hb + n) * 64 + d];
            al4[i] = *(const v8h*)&avl[(hb + n) * 64 + d];
        }
        #pragma unroll
        for (int j = 0; j < 4; ++j) {
            bh[j]  = *(const v8h*)&WoutTh[(size_t)(col0 + j * 16 + lr) * 512 + ks + kg];
            bl4[j] = *(const v8h*)&WoutTl[(size_t)(col0 + j * 16 + lr) * 512 + ks + kg];
        }
        #pragma unroll
        for (int i = 0; i < 4; ++i)
            #pragma unroll
            for (int j = 0; j < 4; ++j) {
                acc[i][j] = MFMA(ah[i], bh[j], acc[i][j]);
                acc[i][j] = MFMA(ah[i], bl4[j], acc[i][j]);
                acc[i][j] = MFMA(al4[i], bh[j], acc[i][j]);
            }
    }
    if (kh == 0) {
        #pragma unroll
        for (int i = 0; i < 4; ++i)
            #pragma unroll
            for (int j = 0; j < 4; ++j)
                #pragma unroll
                for (int r = 0; r < 4; ++r)
                    red[wc][i][j][r][l] = acc[i][j][r];
    }
    __syncthreads();
    if (kh == 1) {
        #pragma unroll
        for (int i = 0; i < 4; ++i)
            #pragma unroll
            for (int j = 0; j < 4; ++j) {
                int col = col0 + j * 16 + lr;
                float bo = bout[col];
                #pragma unroll
                for (int r = 0; r < 4; ++r) {
                    float val = acc[i][j][r] + red[wc][i][j][r][l] + bo;
                    int token = tok0 + i * 16 + (l >> 4) * 4 + r;
                    out[(size_t)token * 512 + col] = val;
                }
            }
    }
}

extern "C" void kernel_launch(void* const* d_in, const int* in_sizes, int n_in,
                              void* d_out, int out_size, void* d_ws, size_t ws_size,
                              hipStream_t stream) {
    const float* q     = (const float*)d_in[0];
    const float* k     = (const float*)d_in[1];
    const float* v     = (const float*)d_in[2];
    const float* ln_w  = (const float*)d_in[3];
    const float* ln_b  = (const float*)d_in[4];
    const float* W_in  = (const float*)d_in[5];
    const float* W_out = (const float*)d_in[6];
    const float* b_out = (const float*)d_in[7];
    const float* wp_W1 = (const float*)d_in[8];
    const float* wp_b1 = (const float*)d_in[9];
    const float* wp_lw = (const float*)d_in[10];
    const float* wp_lb = (const float*)d_in[11];
    const float* wp_W2 = (const float*)d_in[12];
    const float* wp_b2 = (const float*)d_in[13];
    const float* wp_W3 = (const float*)d_in[14];
    const float* wp_b3 = (const float*)d_in[15];
    const float* wp_W4 = (const float*)d_in[16];
    const float* wp_b4 = (const float*)d_in[17];
    const float* wtemp = (const float*)d_in[18];

    float* ws = (float*)d_ws;
    f16* ln16     = (f16*)(ws + OFF_LN16);
    f16* lnlo     = (f16*)(ws + OFF_LNLO);
    f16* fq16     = (f16*)(ws + OFF_FQ16);
    f16* fk16     = (f16*)(ws + OFF_FK16);
    f16* fvhT     = (f16*)(ws + OFF_FVHT);
    f16* fvlT     = (f16*)(ws + OFF_FVLT);
    f16* WinTh    = (f16*)(ws + OFF_WINTH);
    f16* WinTl    = (f16*)(ws + OFF_WINTL);
    f16* WoutTh   = (f16*)(ws + OFF_WOUTTH);
    f16* WoutTl   = (f16*)(ws + OFF_WOUTTL);
    f16* avh      = (f16*)(ws + OFF_AVH);
    f16* avl      = (f16*)(ws + OFF_AVL);
    f16* dots     = (f16*)(ws + OFF_DOTS);
    float* rq1    = ws + OFF_RQ1;
    float* rq2    = ws + OFF_RQ2;
    float* muq    = ws + OFF_MUQ;
    float* rk1    = ws + OFF_RK1;
    float* rk2    = ws + OFF_RK2;
    float* sk     = ws + OFF_SK;
    float* vcrow  = ws + OFF_VC;
    float* rmax   = ws + OFF_RMAX;
    float* nuacck = ws + OFF_NUACC;
    float* pb     = ws + OFF_PB;
    float* pb2    = ws + OFF_PB2;
    float* feat   = ws + OFF_FEAT;
    float* wv     = ws + OFF_WV;
    float* scal   = ws + OFF_SCAL;

    k_zero<<<8, 256, 0, stream>>>(feat, nuacck);
    k_wprep<<<dim3(8, 8, 2), 256, 0, stream>>>(W_in, W_out, WinTh, WinTl, WoutTh, WoutTl);
    k_ln16<<<3072, 256, 0, stream>>>(q, k, v, ln_w, ln_b, ln16, lnlo);
    k_proj_mfma<0><<<dim3(4, 32), 256, 0, stream>>>(ln16, nullptr, WinTh, WinTl,
            fq16, nullptr, nullptr, rq1, rq2, muq, feat, nullptr);
    k_proj_mfma<1><<<dim3(4, 32), 256, 0, stream>>>(ln16 + (size_t)4096 * 512, nullptr,
            WinTh, WinTl, fk16, nullptr, nullptr, rk1, rk2, sk, feat, nuacck);
    k_proj_mfma<2><<<dim3(4, 32), 256, 0, stream>>>(ln16 + (size_t)8192 * 512, lnlo,
            WinTh, WinTl, nullptr, fvhT, fvlT, nullptr, nullptr, nullptr,
            nullptr, nullptr);
    k_mlp<<<8, 256, 0, stream>>>(feat, wp_W1, wp_b1, wp_lw, wp_lb,
                                 wp_W2, wp_b2, wp_W3, wp_b3, wp_W4, wp_b4,
                                 wtemp, wv);
    k_passA<<<dim3(16, 32), 256, 0, stream>>>(fq16, fk16, rq1, rq2, muq, rk1, rk2,
                                              sk, nuacck, vcrow, pb);
    k_fin1<<<1, 256, 0, stream>>>(pb, vcrow, scal);
    k_passB<<<dim3(16, 32), 256, 0, stream>>>(fq16, fk16, rq1, muq, rk1, sk, nuacck,
                                              vcrow, wv, scal, rmax, dots, pb2);
    k_fin2<<<1, 256, 0, stream>>>(pb2, scal);
    k_passC<<<dim3(16, 32), 256, 0, stream>>>(dots, rmax, scal, fvhT, fvlT, avh, avl);
    k_out_mfma<<<dim3(4, 64), 256, 0, stream>>>(avh, avl, WoutTh, WoutTl, b_out,
                                                (float*)d_out);
}

// Round 7
// 327.351 us; speedup vs baseline: 34.6284x; 1.0201x over previous
//
#include <hip/hip_runtime.h>
#include <math.h>

typedef _Float16 f16;
typedef _Float16 v8h __attribute__((ext_vector_type(8)));
typedef _Float16 v4h __attribute__((ext_vector_type(4)));
typedef float    v4f __attribute__((ext_vector_type(4)));

#define MFMA(a, b, c) __builtin_amdgcn_mfma_f32_16x16x32_f16((a), (b), (c), 0, 0, 0)

// ---------------- workspace layout (float offsets) ----------------
#define OFF_LN16    0u
#define OFF_LNLO    3145728u
#define OFF_FQ16    4194304u
#define OFF_FK16    5242880u
#define OFF_FVHT    6291456u
#define OFF_FVLT    7340032u
#define OFF_WINTH   8388608u
#define OFF_WINTL   8519680u
#define OFF_WOUTTH  8650752u
#define OFF_WOUTTL  8781824u
#define OFF_AVH     8912896u
#define OFF_AVL     9961472u
#define OFF_RQ1     11010048u
#define OFF_RQ2     11042816u
#define OFF_MUQ     11075584u
#define OFF_RK1     11108352u
#define OFF_RK2     11141120u
#define OFF_SK      11173888u
#define OFF_VC      11206656u
#define OFF_RMAX    11239424u
#define OFF_NUACC   11272192u   // 2048
#define OFF_PB      11274240u   // 512*4
#define OFF_PB2     11276288u   // 512*2
#define OFF_FEAT    11277312u   // 1024
#define OFF_WV      11278336u   // 24
#define OFF_SCAL    11278360u   // 8
#define OFF_DOTS    11278368u   // f16[32*1024*1024] = 16777216 floats

__device__ __forceinline__ float clampf(float x, float lo, float hi) {
    return fminf(fmaxf(x, lo), hi);
}

__global__ void k_zero(float* feat, float* nuacck) {
    int i = blockIdx.x * 256 + threadIdx.x;
    if (i < 1024) feat[i] = 0.0f;
    if (i < 2048) nuacck[i] = 0.0f;
}

// transpose + hi/lo split of a 512x512 weight: W[k][c] -> WT{h,l}[c][k]
__global__ __launch_bounds__(256) void k_wprep(const float* __restrict__ Win,
        const float* __restrict__ Wout, f16* __restrict__ WinTh, f16* __restrict__ WinTl,
        f16* __restrict__ WoutTh, f16* __restrict__ WoutTl) {
    __shared__ float lds[64][68];
    const float* W = blockIdx.z ? Wout : Win;
    f16* Th = blockIdx.z ? WoutTh : WinTh;
    f16* Tl = blockIdx.z ? WoutTl : WinTl;
    int k0 = blockIdx.y * 64, c0 = blockIdx.x * 64;
    int t = threadIdx.x;
    #pragma unroll
    for (int p = 0; p < 4; ++p) {
        int flat = p * 1024 + t * 4;
        int r = flat >> 6, c = flat & 63;
        *(float4*)&lds[r][c] = *(const float4*)&W[(size_t)(k0 + r) * 512 + c0 + c];
    }
    __syncthreads();
    int c = t >> 2, kk = (t & 3) * 16;
    #pragma unroll
    for (int half = 0; half < 2; ++half) {
        v8h h8, l8;
        #pragma unroll
        for (int ii = 0; ii < 8; ++ii) {
            float v = lds[kk + half * 8 + ii][c];
            f16 h = (f16)v;
            h8[ii] = h;
            l8[ii] = (f16)(v - (float)h);
        }
        *(v8h*)&Th[(size_t)(c0 + c) * 512 + k0 + kk + half * 8] = h8;
        *(v8h*)&Tl[(size_t)(c0 + c) * 512 + k0 + kk + half * 8] = l8;
    }
}

// LayerNorm all 12288 tokens -> ln16 f16; v tokens also get lo residual
__global__ __launch_bounds__(256) void k_ln16(const float* __restrict__ q,
        const float* __restrict__ kk, const float* __restrict__ v,
        const float* __restrict__ lnw, const float* __restrict__ lnb,
        f16* __restrict__ ln16, f16* __restrict__ lnlo) {
    int t = threadIdx.x, wid = t >> 6, lane = t & 63;
    int token = blockIdx.x * 4 + wid;
    int inp = token >> 12, lt = token & 4095;
    const float* xp = (inp == 0) ? q : ((inp == 1) ? kk : v);
    const float4* xr = (const float4*)(xp + (size_t)lt * 512);
    float4 a = xr[lane], b = xr[lane + 64];
    float s = a.x + a.y + a.z + a.w + b.x + b.y + b.z + b.w;
    float s2 = a.x*a.x + a.y*a.y + a.z*a.z + a.w*a.w
             + b.x*b.x + b.y*b.y + b.z*b.z + b.w*b.w;
    for (int o = 32; o > 0; o >>= 1) { s += __shfl_down(s, o); s2 += __shfl_down(s2, o); }
    float m_ = __shfl(s, 0) * (1.0f / 512.0f);
    float var = __shfl(s2, 0) * (1.0f / 512.0f) - m_ * m_;
    var = fmaxf(var, 0.0f);
    float rs = rsqrtf(var + 1e-5f);
    const float4* w4 = (const float4*)lnw;
    const float4* b4 = (const float4*)lnb;
    float4 wa = w4[lane], wb = w4[lane + 64], ba = b4[lane], bb = b4[lane + 64];
    float ga[4] = { (a.x - m_) * rs * wa.x + ba.x, (a.y - m_) * rs * wa.y + ba.y,
                    (a.z - m_) * rs * wa.z + ba.z, (a.w - m_) * rs * wa.w + ba.w };
    float gb[4] = { (b.x - m_) * rs * wb.x + bb.x, (b.y - m_) * rs * wb.y + bb.y,
                    (b.z - m_) * rs * wb.z + bb.z, (b.w - m_) * rs * wb.w + bb.w };
    f16* orow = ln16 + (size_t)token * 512;
    v4h ha, hb;
    #pragma unroll
    for (int i = 0; i < 4; ++i) { ha[i] = (f16)ga[i]; hb[i] = (f16)gb[i]; }
    *(v4h*)&orow[lane * 4] = ha;
    *(v4h*)&orow[lane * 4 + 256] = hb;
    if (inp == 2) {
        f16* lrow = lnlo + (size_t)lt * 512;
        v4h la, lb;
        #pragma unroll
        for (int i = 0; i < 4; ++i) {
            la[i] = (f16)(ga[i] - (float)ha[i]);
            lb[i] = (f16)(gb[i] - (float)hb[i]);
        }
        *(v4h*)&lrow[lane * 4] = la;
        *(v4h*)&lrow[lane * 4 + 256] = lb;
    }
}

// LN16 @ Win (MFMA). MODE 0: q (fq16 + recip stats). MODE 1: k. MODE 2: v.
template<int MODE>
__global__ __launch_bounds__(256) void k_proj_mfma(const f16* __restrict__ A16,
        const f16* __restrict__ Alo,
        const f16* __restrict__ BTh, const f16* __restrict__ BTl,
        f16* __restrict__ fout16, f16* __restrict__ fhT, f16* __restrict__ flT,
        float* __restrict__ oA, float* __restrict__ oB, float* __restrict__ oC,
        float* __restrict__ feat, float* __restrict__ nuacck) {
    int t = threadIdx.x, l = t & 63, w = t >> 6;
    int wr = w >> 1, wc = w & 1;
    int col0 = blockIdx.x * 128 + wc * 64;
    int tok0 = blockIdx.y * 128 + wr * 64;
    int lr = l & 15, kg = (l >> 4) * 8;
    int rg4 = (l >> 4) * 4;
    v4f acc[4][4] = {};
    for (int ks = 0; ks < 512; ks += 32) {
        v8h a[4], b[4];
        #pragma unroll
        for (int i = 0; i < 4; ++i)
            a[i] = *(const v8h*)&A16[(size_t)(tok0 + i * 16 + lr) * 512 + ks + kg];
        #pragma unroll
        for (int j = 0; j < 4; ++j)
            b[j] = *(const v8h*)&BTh[(size_t)(col0 + j * 16 + lr) * 512 + ks + kg];
        if constexpr (MODE == 2) {
            v8h al[4], bl[4];
            #pragma unroll
            for (int i = 0; i < 4; ++i)
                al[i] = *(const v8h*)&Alo[(size_t)(tok0 + i * 16 + lr) * 512 + ks + kg];
            #pragma unroll
            for (int j = 0; j < 4; ++j)
                bl[j] = *(const v8h*)&BTl[(size_t)(col0 + j * 16 + lr) * 512 + ks + kg];
            #pragma unroll
            for (int i = 0; i < 4; ++i)
                #pragma unroll
                for (int j = 0; j < 4; ++j) {
                    acc[i][j] = MFMA(a[i], b[j], acc[i][j]);
                    acc[i][j] = MFMA(a[i], bl[j], acc[i][j]);
                    acc[i][j] = MFMA(al[i], b[j], acc[i][j]);
                }
        } else {
            #pragma unroll
            for (int i = 0; i < 4; ++i)
                #pragma unroll
                for (int j = 0; j < 4; ++j)
                    acc[i][j] = MFMA(a[i], b[j], acc[i][j]);
        }
    }
    int h = col0 >> 6;
    #pragma unroll
    for (int i = 0; i < 4; ++i)
        #pragma unroll
        for (int j = 0; j < 4; ++j)
            #pragma unroll
            for (int r = 0; r < 4; ++r) {
                int token = tok0 + i * 16 + rg4 + r;
                int d = j * 16 + lr;
                int qi = token >> 10, n = token & 1023;
                float val = acc[i][j][r];
                if constexpr (MODE != 2) {
                    fout16[((size_t)((h << 2) + qi) * 1024 + n) * 64 + d] = (f16)val;
                } else {
                    f16 hi = (f16)val;
                    fhT[((size_t)((h << 2) + qi) * 64 + d) * 1024 + n] = hi;
                    flT[((size_t)((h << 2) + qi) * 64 + d) * 1024 + n] = (f16)(val - (float)hi);
                }
            }
    if constexpr (MODE != 2) {
        #pragma unroll
        for (int i = 0; i < 4; ++i)
            #pragma unroll
            for (int r = 0; r < 4; ++r) {
                float s = 0.f, s2 = 0.f;
                #pragma unroll
                for (int j = 0; j < 4; ++j) { float v = acc[i][j][r]; s += v; s2 += v * v; }
                #pragma unroll
                for (int mk = 1; mk <= 8; mk <<= 1) {
                    s += __shfl_xor(s, mk); s2 += __shfl_xor(s2, mk);
                }
                if (lr == 0) {
                    int token = tok0 + i * 16 + rg4 + r;
                    int qi = token >> 10, n = token & 1023;
                    int row = ((h << 2) + qi) * 1024 + n;
                    float nv = sqrtf(s2);
                    oA[row] = 1.0f / (nv + 1e-6f);
                    oB[row] = 1.0f / fmaxf(nv, 1e-4f);
                    oC[row] = (MODE == 0) ? s * (1.0f / 64.0f) : s;
                }
            }
        float cs[4];
        #pragma unroll
        for (int j = 0; j < 4; ++j) {
            float c = 0.f;
            #pragma unroll
            for (int i = 0; i < 4; ++i)
                #pragma unroll
                for (int r = 0; r < 4; ++r) c += acc[i][j][r];
            c += __shfl_xor(c, 16); c += __shfl_xor(c, 32);
            cs[j] = c;
        }
        if (l < 16) {
            #pragma unroll
            for (int j = 0; j < 4; ++j)
                atomicAdd(&feat[h * 128 + (MODE == 1 ? 64 : 0) + j * 16 + l],
                          cs[j] * (1.0f / 4096.0f));
            if constexpr (MODE == 1) {
                int qi = tok0 >> 10;
                #pragma unroll
                for (int j = 0; j < 4; ++j)
                    atomicAdd(&nuacck[((h << 2) + qi) * 64 + j * 16 + l], cs[j]);
            }
        }
    }
}

// tiny MLP weight predictor, one block per head -> wv[h][3]
__global__ __launch_bounds__(256) void k_mlp(const float* __restrict__ feat,
        const float* __restrict__ W1, const float* __restrict__ b1,
        const float* __restrict__ lw, const float* __restrict__ lb,
        const float* __restrict__ W2, const float* __restrict__ b2,
        const float* __restrict__ W3, const float* __restrict__ b3,
        const float* __restrict__ W4, const float* __restrict__ b4,
        const float* __restrict__ wtemp, float* wv) {
    __shared__ float h1[256], h2[192], h3[64], red[8];
    int t = threadIdx.x;
    int h = blockIdx.x;
    float p = 0.0f;
    for (int i = 0; i < 128; ++i) p += feat[h * 128 + i] * W1[i * 256 + t];
    p += b1[t];
    float s = p, s2 = p * p;
    for (int o = 32; o > 0; o >>= 1) { s += __shfl_down(s, o); s2 += __shfl_down(s2, o); }
    if ((t & 63) == 0) { red[t >> 6] = s; red[4 + (t >> 6)] = s2; }
    __syncthreads();
    float S = red[0] + red[1] + red[2] + red[3];
    float S2 = red[4] + red[5] + red[6] + red[7];
    float mu = S / 256.0f;
    float var = S2 / 256.0f - mu * mu; if (var < 0.0f) var = 0.0f;
    float xh = (p - mu) * rsqrtf(var + 1e-5f) * lw[t] + lb[t];
    h1[t] = fmaxf(xh, 0.0f);
    __syncthreads();
    if (t < 192) {
        float a = 0.0f;
        for (int i = 0; i < 256; ++i) a += h1[i] * W2[i * 192 + t];
        h2[t] = fmaxf(a + b2[t], 0.0f);
    }
    __syncthreads();
    if (t < 64) {
        float a = 0.0f;
        for (int i = 0; i < 192; ++i) a += h2[i] * W3[i * 64 + t];
        h3[t] = fmaxf(a + b3[t], 0.0f);
    }
    __syncthreads();
    if (t == 0) {
        float lg[3];
        for (int j = 0; j < 3; ++j) {
            float a = 0.0f;
            for (int i = 0; i < 64; ++i) a += h3[i] * W4[i * 3 + j];
            lg[j] = a + b4[j];
        }
        float mx = fmaxf(lg[0], fmaxf(lg[1], lg[2]));
        float e0 = expf(lg[0] - mx), e1 = expf(lg[1] - mx), e2 = expf(lg[2] - mx);
        float se = e0 + e1 + e2;
        float pr0 = e0 / se, pr1 = e1 / se, pr2 = e2 / se;
        float wt = wtemp[0]; wt = fminf(fmaxf(wt, 0.01f), 1.0f);
        float q0 = pr0 / wt, q1 = pr1 / wt, q2 = pr2 / wt;
        float m2 = fmaxf(q0, fmaxf(q1, q2));
        float f0 = expf(q0 - m2), f1 = expf(q1 - m2), f2 = expf(q2 - m2);
        float sf = f0 + f1 + f2; f0 /= sf; f1 /= sf; f2 /= sf;
        f0 = fminf(fmaxf(f0, 0.01f), 0.95f);
        f1 = fminf(fmaxf(f1, 0.01f), 0.95f);
        f2 = fminf(fmaxf(f2, 0.01f), 0.95f);
        float sw = f0 + f1 + f2;
        wv[h * 3 + 0] = f0 / sw; wv[h * 3 + 1] = f1 / sw; wv[h * 3 + 2] = f2 / sw;
    }
}

// ---- shared per-pass preamble: 16 rows per wave, grid (16, 32) ----
#define PASS_PREAMBLE                                                          \
    int hq = blockIdx.y;                                                       \
    int t = threadIdx.x, l = t & 63, w = t >> 6;                               \
    int lr = l & 15, kg = (l >> 4) * 8, rg4 = (l >> 4) * 4;                    \
    int nb = blockIdx.x * 64 + w * 16;                                         \
    const f16* Q = fq16 + (size_t)hq * 65536;                                  \
    const f16* K = fk16 + (size_t)hq * 65536;                                  \
    v8h aq0 = *(const v8h*)&Q[(size_t)(nb + lr) * 64 + kg];                    \
    v8h aq1 = *(const v8h*)&Q[(size_t)(nb + lr) * 64 + 32 + kg];               \
    const float inv1024 = 1.0f / 1024.0f;                                      \
    float uvp = nuacck[hq * 64 + l] * inv1024;                                 \
    _Pragma("unroll")                                                          \
    for (int o = 32; o > 0; o >>= 1) uvp += __shfl_xor(uvp, o);                \
    float uv = uvp;                                                            \
    float tp = 0.f;                                                            \
    _Pragma("unroll")                                                          \
    for (int e = 0; e < 8; ++e)                                                \
        tp += (float)aq0[e] * nuacck[hq * 64 + kg + e]                         \
            + (float)aq1[e] * nuacck[hq * 64 + 32 + kg + e];                   \
    tp *= inv1024;                                                             \
    tp += __shfl_xor(tp, 16);                                                  \
    tp += __shfl_xor(tp, 32);                                                  \
    float muv[4], tv[4];                                                       \
    _Pragma("unroll")                                                          \
    for (int r = 0; r < 4; ++r) {                                              \
        muv[r] = muq[hq * 1024 + nb + rg4 + r];                                \
        tv[r] = __shfl(tp, rg4 + r);                                           \
    }                                                                          \
    const float Acs = (0.001f / 1024.0f) / 8.0001f;                            \
    float Pr[4], Gr[4];                                                        \
    _Pragma("unroll")                                                          \
    for (int r = 0; r < 4; ++r) {                                              \
        Gr[r] = Acs * muv[r];                                                  \
        Pr[r] = Acs * fmaf(muv[r], uv, -tv[r]);                                \
    }

#define LOAD_KTILE                                                             \
    v8h b0[4], b1[4];                                                          \
    _Pragma("unroll")                                                          \
    for (int j = 0; j < 4; ++j) {                                              \
        b0[j] = *(const v8h*)&K[(size_t)(m0 + j * 16 + lr) * 64 + kg];         \
        b1[j] = *(const v8h*)&K[(size_t)(m0 + j * 16 + lr) * 64 + 32 + kg];    \
    }

// pass A: cos/cov global sums + per-row margin means (K stats in LDS)
__global__ __launch_bounds__(256) void k_passA(const f16* __restrict__ fq16,
        const f16* __restrict__ fk16, const float* __restrict__ rq1,
        const float* __restrict__ rq2, const float* __restrict__ muq,
        const float* __restrict__ rk1, const float* __restrict__ rk2,
        const float* __restrict__ sk, const float* __restrict__ nuacck,
        float* __restrict__ vcrow, float* __restrict__ pb) {
    __shared__ float rk1s[1024], rk2s[1024], sks[1024];
    PASS_PREAMBLE
    {
        int i4 = t * 4;
        *(float4*)&rk1s[i4] = *(const float4*)&rk1[hq * 1024 + i4];
        *(float4*)&rk2s[i4] = *(const float4*)&rk2[hq * 1024 + i4];
        *(float4*)&sks[i4]  = *(const float4*)&sk[hq * 1024 + i4];
    }
    __syncthreads();
    float rq1v[4], rq2v[4];
    #pragma unroll
    for (int r = 0; r < 4; ++r) {
        rq1v[r] = rq1[hq * 1024 + nb + rg4 + r];
        rq2v[r] = rq2[hq * 1024 + nb + rg4 + r];
    }
    float scos = 0, s2cos = 0, scov = 0, s2cov = 0;
    float mp[4] = {};
    #pragma unroll 2
    for (int m0 = 0; m0 < 1024; m0 += 64) {
        LOAD_KTILE
        float rk1v[4], rk2v[4], skv[4];
        #pragma unroll
        for (int j = 0; j < 4; ++j) {
            int cg = m0 + j * 16 + lr;
            rk1v[j] = rk1s[cg]; rk2v[j] = rk2s[cg]; skv[j] = sks[cg];
        }
        v4f acc[4] = {};
        #pragma unroll
        for (int j = 0; j < 4; ++j) {
            acc[j] = MFMA(aq0, b0[j], acc[j]);
            acc[j] = MFMA(aq1, b1[j], acc[j]);
        }
        #pragma unroll
        for (int j = 0; j < 4; ++j)
            #pragma unroll
            for (int r = 0; r < 4; ++r) {
                float rv = acc[j][r];
                float cosv = clampf(rv * rq1v[r] * rk1v[j], -0.95f, 0.95f);
                float x2 = rv * rq2v[r] * rk2v[j];
                float marg = fmaxf(0.01f - fmaxf(x2, -0.95f), 0.0f);
                float cov = clampf(fmaf(-Gr[r], skv[j], fmaf(Acs, rv, Pr[r])),
                                   -50.0f, 50.0f);
                scos += cosv; s2cos = fmaf(cosv, cosv, s2cos);
                scov += cov;  s2cov = fmaf(cov, cov, s2cov);
                mp[r] += marg;
            }
    }
    #pragma unroll
    for (int r = 0; r < 4; ++r) {
        float m_ = mp[r];
        m_ += __shfl_xor(m_, 1); m_ += __shfl_xor(m_, 2);
        m_ += __shfl_xor(m_, 4); m_ += __shfl_xor(m_, 8);
        if (lr == 0) vcrow[hq * 1024 + nb + rg4 + r] = m_ * inv1024;
    }
    for (int o = 32; o > 0; o >>= 1) {
        scos += __shfl_down(scos, o); s2cos += __shfl_down(s2cos, o);
        scov += __shfl_down(scov, o); s2cov += __shfl_down(s2cov, o);
    }
    __shared__ float bs[4][4];
    if (l == 0) { bs[w][0] = scos; bs[w][1] = s2cos; bs[w][2] = scov; bs[w][3] = s2cov; }
    __syncthreads();
    if (t == 0) {
        int bid = hq * 16 + blockIdx.x;
        pb[bid * 4 + 0] = bs[0][0] + bs[1][0] + bs[2][0] + bs[3][0];
        pb[bid * 4 + 1] = bs[0][1] + bs[1][1] + bs[2][1] + bs[3][1];
        pb[bid * 4 + 2] = bs[0][2] + bs[1][2] + bs[2][2] + bs[3][2];
        pb[bid * 4 + 3] = bs[0][3] + bs[1][3] + bs[2][3] + bs[3][3];
    }
}

__global__ __launch_bounds__(256) void k_fin1(const float* __restrict__ pb,
        const float* __restrict__ vcrow, float* __restrict__ scal) {
    int t = threadIdx.x;
    double s0 = 0, s1 = 0, s2 = 0, s3 = 0, s4 = 0, s5 = 0;
    for (int i = t; i < 512; i += 256) {
        s0 += pb[i * 4 + 0]; s1 += pb[i * 4 + 1];
        s2 += pb[i * 4 + 2]; s3 += pb[i * 4 + 3];
    }
    for (int i = t; i < 32768; i += 256) {
        double rm = (double)vcrow[i];
        s4 += rm; s5 += rm * rm;
    }
    for (int o = 32; o > 0; o >>= 1) {
        s0 += __shfl_down(s0, o); s1 += __shfl_down(s1, o); s2 += __shfl_down(s2, o);
        s3 += __shfl_down(s3, o); s4 += __shfl_down(s4, o); s5 += __shfl_down(s5, o);
    }
    __shared__ double red[6][4];
    int wid = t >> 6, lane = t & 63;
    if (lane == 0) { red[0][wid] = s0; red[1][wid] = s1; red[2][wid] = s2;
                     red[3][wid] = s3; red[4][wid] = s4; red[5][wid] = s5; }
    __syncthreads();
    if (t == 0) {
        double S0 = red[0][0] + red[0][1] + red[0][2] + red[0][3];
        double S1 = red[1][0] + red[1][1] + red[1][2] + red[1][3];
        double S2 = red[2][0] + red[2][1] + red[2][2] + red[2][3];
        double S3 = red[3][0] + red[3][1] + red[3][2] + red[3][3];
        double S4 = red[4][0] + red[4][1] + red[4][2] + red[4][3];
        double S5 = red[5][0] + red[5][1] + red[5][2] + red[5][3];
        const double cnt = 33554432.0;
        scal[0] = (float)sqrt(fmax(0.0, (S1 - S0 * S0 / cnt) / (cnt - 1.0)));
        scal[1] = (float)sqrt(fmax(0.0, (S3 - S2 * S2 / cnt) / (cnt - 1.0)));
        double V4 = S4 * 1024.0, V5 = S5 * 1024.0;
        scal[2] = (float)sqrt(fmax(0.0, (V5 - V4 * V4 / cnt) / (cnt - 1.0)));
    }
}

// pass B: dots -> f16 buffer (coalesced via wave-private LDS), sum/sumsq, row max
__global__ __launch_bounds__(256) void k_passB(const f16* __restrict__ fq16,
        const f16* __restrict__ fk16, const float* __restrict__ rq1,
        const float* __restrict__ muq, const float* __restrict__ rk1,
        const float* __restrict__ sk, const float* __restrict__ nuacck,
        const float* __restrict__ vcrow, const float* __restrict__ wv,
        const float* __restrict__ scal, float* __restrict__ rmax,
        f16* __restrict__ dots, float* __restrict__ pb2) {
    __shared__ f16 P[4][16][72];
    __shared__ float rk1s[1024], sks[1024];
    PASS_PREAMBLE
    {
        int i4 = t * 4;
        *(float4*)&rk1s[i4] = *(const float4*)&rk1[hq * 1024 + i4];
        *(float4*)&sks[i4]  = *(const float4*)&sk[hq * 1024 + i4];
    }
    __syncthreads();
    int h = hq >> 2;
    float s1 = scal[0] + 1e-4f, s2v = scal[1] + 1e-4f, s3 = scal[2] + 1e-4f;
    float w0 = wv[h * 3], w1 = wv[h * 3 + 1], w2 = wv[h * 3 + 2];
    float fc1 = w0 / s1;
    float fc2 = w1 * 0.3f / s2v;
    float c3 = w2 * 0.3f / s3;
    float rq1v[4], addc[4];
    #pragma unroll
    for (int r = 0; r < 4; ++r) {
        int row = hq * 1024 + nb + rg4 + r;
        rq1v[r] = rq1[row];
        addc[r] = vcrow[row] * c3;
    }
    float sd = 0.f, s2d = 0.f;
    float dmax[4] = { -1e30f, -1e30f, -1e30f, -1e30f };
    int rr = l & 15, cg = (l >> 4) * 8;
    for (int m0 = 0; m0 < 1024; m0 += 64) {
        LOAD_KTILE
        float rk1v[4], skv[4];
        #pragma unroll
        for (int j = 0; j < 4; ++j) {
            int cgl = m0 + j * 16 + lr;
            rk1v[j] = rk1s[cgl]; skv[j] = sks[cgl];
        }
        v4f acc[4] = {};
        #pragma unroll
        for (int j = 0; j < 4; ++j) {
            acc[j] = MFMA(aq0, b0[j], acc[j]);
            acc[j] = MFMA(aq1, b1[j], acc[j]);
        }
        #pragma unroll
        for (int j = 0; j < 4; ++j)
            #pragma unroll
            for (int r = 0; r < 4; ++r) {
                float rv = acc[j][r];
                float cosv = clampf(rv * rq1v[r] * rk1v[j], -0.95f, 0.95f);
                float cov = clampf(fmaf(-Gr[r], skv[j], fmaf(Acs, rv, Pr[r])),
                                   -50.0f, 50.0f);
                float dd = fmaf(fc2, cov, fmaf(fc1, cosv, addc[r]));
                sd += dd; s2d = fmaf(dd, dd, s2d);
                dmax[r] = fmaxf(dmax[r], dd);
                P[w][rg4 + r][j * 16 + lr] = (f16)dd;
            }
        // coalesced store of this wave's 16x64 dots tile
        v8h d0 = *(const v8h*)&P[w][rr][cg];
        v8h d1 = *(const v8h*)&P[w][rr][32 + cg];
        f16* DP = dots + ((size_t)(hq * 1024 + nb + rr)) * 1024 + m0;
        *(v8h*)&DP[cg] = d0;
        *(v8h*)&DP[32 + cg] = d1;
    }
    #pragma unroll
    for (int r = 0; r < 4; ++r) {
        float m_ = dmax[r];
        m_ = fmaxf(m_, __shfl_xor(m_, 1)); m_ = fmaxf(m_, __shfl_xor(m_, 2));
        m_ = fmaxf(m_, __shfl_xor(m_, 4)); m_ = fmaxf(m_, __shfl_xor(m_, 8));
        if (lr == 0) rmax[hq * 1024 + nb + rg4 + r] = m_;
    }
    for (int o = 32; o > 0; o >>= 1) { sd += __shfl_down(sd, o); s2d += __shfl_down(s2d, o); }
    __shared__ float fr[2][4];
    if (l == 0) { fr[0][w] = sd; fr[1][w] = s2d; }
    __syncthreads();
    if (t == 0) {
        int bid = hq * 16 + blockIdx.x;
        pb2[bid * 2 + 0] = fr[0][0] + fr[0][1] + fr[0][2] + fr[0][3];
        pb2[bid * 2 + 1] = fr[1][0] + fr[1][1] + fr[1][2] + fr[1][3];
    }
}

__global__ __launch_bounds__(256) void k_fin2(const float* __restrict__ pb2,
        float* __restrict__ scal) {
    int t = threadIdx.x;
    double s6 = 0, s7 = 0;
    for (int i = t; i < 512; i += 256) { s6 += pb2[i * 2]; s7 += pb2[i * 2 + 1]; }
    for (int o = 32; o > 0; o >>= 1) { s6 += __shfl_down(s6, o); s7 += __shfl_down(s7, o); }
    __shared__ double red[2][4];
    int wid = t >> 6, lane = t & 63;
    if (lane == 0) { red[0][wid] = s6; red[1][wid] = s7; }
    __syncthreads();
    if (t == 0) {
        double S6 = red[0][0] + red[0][1] + red[0][2] + red[0][3];
        double S7 = red[1][0] + red[1][1] + red[1][2] + red[1][3];
        const double cnt = 33554432.0;
        double ds = sqrt(fmax(0.0, (S7 - S6 * S6 / cnt) / (cnt - 1.0)));
        float temp = (ds < 1e-5) ? 0.01f : ((ds < 1e-3) ? 0.05f : (0.2f + (float)ds * 2.0f));
        temp = fminf(fmaxf(temp, 0.01f), 8.0f);
        scal[3] = temp;
    }
}

// pass C: read f16 dots -> exp -> PV MFMA (hi/lo V) -> normalized av.
// 64-key software-pipelined steps: all loads issued before the exp block.
__global__ __launch_bounds__(256) void k_passC(const f16* __restrict__ dots,
        const float* __restrict__ rmax, const float* __restrict__ scal,
        const f16* __restrict__ fvhT, const f16* __restrict__ fvlT,
        f16* __restrict__ avh, f16* __restrict__ avl) {
    int hq = blockIdx.y;
    int t = threadIdx.x, l = t & 63, w = t >> 6;
    int lr = l & 15, kg = (l >> 4) * 8, rg4 = (l >> 4) * 4;
    int nb = blockIdx.x * 64 + w * 16;
    int row = hq * 1024 + nb + lr;
    float invt = 1.0f / scal[3];
    float rmi = rmax[row] * invt;
    const f16* D = dots + (size_t)row * 1024;
    const f16* VH = fvhT + ((size_t)hq * 64 + lr) * 1024;
    const f16* VL = fvlT + ((size_t)hq * 64 + lr) * 1024;
    v4f acc[4] = {};
    float rs = 0.f;
    for (int ks = 0; ks < 1024; ks += 64) {
        v8h dv0 = *(const v8h*)&D[ks + kg];
        v8h dv1 = *(const v8h*)&D[ks + 32 + kg];
        v8h vh0[4], vl0[4], vh1[4], vl1[4];
        #pragma unroll
        for (int j = 0; j < 4; ++j) {
            size_t vb = (size_t)j * 16384 + ks + kg;
            vh0[j] = *(const v8h*)&VH[vb];
            vl0[j] = *(const v8h*)&VL[vb];
            vh1[j] = *(const v8h*)&VH[vb + 32];
            vl1[j] = *(const v8h*)&VL[vb + 32];
        }
        v8h pa0, pa1;
        #pragma unroll
        for (int e = 0; e < 8; ++e) {
            float p0 = __expf(fmaf((float)dv0[e], invt, -rmi));
            float p1 = __expf(fmaf((float)dv1[e], invt, -rmi));
            f16 q0 = (f16)p0, q1 = (f16)p1;
            pa0[e] = q0; pa1[e] = q1;
            rs += (float)q0 + (float)q1;
        }
        #pragma unroll
        for (int j = 0; j < 4; ++j) {
            acc[j] = MFMA(pa0, vh0[j], acc[j]);
            acc[j] = MFMA(pa0, vl0[j], acc[j]);
            acc[j] = MFMA(pa1, vh1[j], acc[j]);
            acc[j] = MFMA(pa1, vl1[j], acc[j]);
        }
    }
    rs += __shfl_xor(rs, 16);
    rs += __shfl_xor(rs, 32);
    float rinv[4];
    #pragma unroll
    for (int r = 0; r < 4; ++r) rinv[r] = 1.0f / __shfl(rs, rg4 + r);
    #pragma unroll
    for (int j = 0; j < 4; ++j)
        #pragma unroll
        for (int r = 0; r < 4; ++r) {
            float val = acc[j][r] * rinv[r];
            size_t idx = ((size_t)(hq * 1024 + nb + rg4 + r)) * 64 + j * 16 + lr;
            f16 hi = (f16)val;
            avh[idx] = hi;
            avl[idx] = (f16)(val - (float)hi);
        }
}

// out = av @ Wout + bout (MFMA, 3-way split)
__global__ __launch_bounds__(256) void k_out_mfma(const f16* __restrict__ avh,
        const f16* __restrict__ avl,
        const f16* __restrict__ WoutTh, const f16* __restrict__ WoutTl,
        const float* __restrict__ bout, float* __restrict__ out) {
    __shared__ float red[2][4][4][4][64];
    int t = threadIdx.x, l = t & 63, w = t >> 6;
    int wc = w & 1, kh = w >> 1;
    int col0 = blockIdx.x * 128 + wc * 64;
    int tok0 = blockIdx.y * 64;
    int qi = tok0 >> 10, nb = tok0 & 1023;
    int lr = l & 15, kg = (l >> 4) * 8;
    v4f acc[4][4] = {};
    for (int ks8 = 0; ks8 < 8; ++ks8) {
        int ks = kh * 256 + ks8 * 32;
        int f = ks + kg;
        int h = f >> 6, d = f & 63;
        size_t hb = (size_t)((h << 2) + qi) * 1024;
        v8h ah[4], al4[4], bh[4], bl4[4];
        #pragma unroll
        for (int i = 0; i < 4; ++i) {
            int n = nb + i * 16 + lr;
            ah[i]  = *(const v8h*)&avh[(hb + n) * 64 + d];
            al4[i] = *(const v8h*)&avl[(hb + n) * 64 + d];
        }
        #pragma unroll
        for (int j = 0; j < 4; ++j) {
            bh[j]  = *(const v8h*)&WoutTh[(size_t)(col0 + j * 16 + lr) * 512 + ks + kg];
            bl4[j] = *(const v8h*)&WoutTl[(size_t)(col0 + j * 16 + lr) * 512 + ks + kg];
        }
        #pragma unroll
        for (int i = 0; i < 4; ++i)
            #pragma unroll
            for (int j = 0; j < 4; ++j) {
                acc[i][j] = MFMA(ah[i], bh[j], acc[i][j]);
                acc[i][j] = MFMA(ah[i], bl4[j], acc[i][j]);
                acc[i][j] = MFMA(al4[i], bh[j], acc[i][j]);
            }
    }
    if (kh == 0) {
        #pragma unroll
        for (int i = 0; i < 4; ++i)
            #pragma unroll
            for (int j = 0; j < 4; ++j)
                #pragma unroll
                for (int r = 0; r < 4; ++r)
                    red[wc][i][j][r][l] = acc[i][j][r];
    }
    __syncthreads();
    if (kh == 1) {
        #pragma unroll
        for (int i = 0; i < 4; ++i)
            #pragma unroll
            for (int j = 0; j < 4; ++j) {
                int col = col0 + j * 16 + lr;
                float bo = bout[col];
                #pragma unroll
                for (int r = 0; r < 4; ++r) {
                    float val = acc[i][j][r] + red[wc][i][j][r][l] + bo;
                    int token = tok0 + i * 16 + (l >> 4) * 4 + r;
                    out[(size_t)token * 512 + col] = val;
                }
            }
    }
}

extern "C" void kernel_launch(void* const* d_in, const int* in_sizes, int n_in,
                              void* d_out, int out_size, void* d_ws, size_t ws_size,
                              hipStream_t stream) {
    const float* q     = (const float*)d_in[0];
    const float* k     = (const float*)d_in[1];
    const float* v     = (const float*)d_in[2];
    const float* ln_w  = (const float*)d_in[3];
    const float* ln_b  = (const float*)d_in[4];
    const float* W_in  = (const float*)d_in[5];
    const float* W_out = (const float*)d_in[6];
    const float* b_out = (const float*)d_in[7];
    const float* wp_W1 = (const float*)d_in[8];
    const float* wp_b1 = (const float*)d_in[9];
    const float* wp_lw = (const float*)d_in[10];
    const float* wp_lb = (const float*)d_in[11];
    const float* wp_W2 = (const float*)d_in[12];
    const float* wp_b2 = (const float*)d_in[13];
    const float* wp_W3 = (const float*)d_in[14];
    const float* wp_b3 = (const float*)d_in[15];
    const float* wp_W4 = (const float*)d_in[16];
    const float* wp_b4 = (const float*)d_in[17];
    const float* wtemp = (const float*)d_in[18];

    float* ws = (float*)d_ws;
    f16* ln16     = (f16*)(ws + OFF_LN16);
    f16* lnlo     = (f16*)(ws + OFF_LNLO);
    f16* fq16     = (f16*)(ws + OFF_FQ16);
    f16* fk16     = (f16*)(ws + OFF_FK16);
    f16* fvhT     = (f16*)(ws + OFF_FVHT);
    f16* fvlT     = (f16*)(ws + OFF_FVLT);
    f16* WinTh    = (f16*)(ws + OFF_WINTH);
    f16* WinTl    = (f16*)(ws + OFF_WINTL);
    f16* WoutTh   = (f16*)(ws + OFF_WOUTTH);
    f16* WoutTl   = (f16*)(ws + OFF_WOUTTL);
    f16* avh      = (f16*)(ws + OFF_AVH);
    f16* avl      = (f16*)(ws + OFF_AVL);
    f16* dots     = (f16*)(ws + OFF_DOTS);
    float* rq1    = ws + OFF_RQ1;
    float* rq2    = ws + OFF_RQ2;
    float* muq    = ws + OFF_MUQ;
    float* rk1    = ws + OFF_RK1;
    float* rk2    = ws + OFF_RK2;
    float* sk     = ws + OFF_SK;
    float* vcrow  = ws + OFF_VC;
    float* rmax   = ws + OFF_RMAX;
    float* nuacck = ws + OFF_NUACC;
    float* pb     = ws + OFF_PB;
    float* pb2    = ws + OFF_PB2;
    float* feat   = ws + OFF_FEAT;
    float* wv     = ws + OFF_WV;
    float* scal   = ws + OFF_SCAL;

    k_zero<<<8, 256, 0, stream>>>(feat, nuacck);
    k_wprep<<<dim3(8, 8, 2), 256, 0, stream>>>(W_in, W_out, WinTh, WinTl, WoutTh, WoutTl);
    k_ln16<<<3072, 256, 0, stream>>>(q, k, v, ln_w, ln_b, ln16, lnlo);
    k_proj_mfma<0><<<dim3(4, 32), 256, 0, stream>>>(ln16, nullptr, WinTh, WinTl,
            fq16, nullptr, nullptr, rq1, rq2, muq, feat, nullptr);
    k_proj_mfma<1><<<dim3(4, 32), 256, 0, stream>>>(ln16 + (size_t)4096 * 512, nullptr,
            WinTh, WinTl, fk16, nullptr, nullptr, rk1, rk2, sk, feat, nuacck);
    k_proj_mfma<2><<<dim3(4, 32), 256, 0, stream>>>(ln16 + (size_t)8192 * 512, lnlo,
            WinTh, WinTl, nullptr, fvhT, fvlT, nullptr, nullptr, nullptr,
            nullptr, nullptr);
    k_mlp<<<8, 256, 0, stream>>>(feat, wp_W1, wp_b1, wp_lw, wp_lb,
                                 wp_W2, wp_b2, wp_W3, wp_b3, wp_W4, wp_b4,
                                 wtemp, wv);
    k_passA<<<dim3(16, 32), 256, 0, stream>>>(fq16, fk16, rq1, rq2, muq, rk1, rk2,
                                              sk, nuacck, vcrow, pb);
    k_fin1<<<1, 256, 0, stream>>>(pb, vcrow, scal);
    k_passB<<<dim3(16, 32), 256, 0, stream>>>(fq16, fk16, rq1, muq, rk1, sk, nuacck,
                                              vcrow, wv, scal, rmax, dots, pb2);
    k_fin2<<<1, 256, 0, stream>>>(pb2, scal);
    k_passC<<<dim3(16, 32), 256, 0, stream>>>(dots, rmax, scal, fvhT, fvlT, avh, avl);
    k_out_mfma<<<dim3(4, 64), 256, 0, stream>>>(avh, avl, WoutTh, WoutTl, b_out,
                                                (float*)d_out);
}

// Round 8
// 303.487 us; speedup vs baseline: 37.3513x; 1.0786x over previous
//
#include <hip/hip_runtime.h>
#include <math.h>

typedef _Float16 f16;
typedef _Float16 v8h __attribute__((ext_vector_type(8)));
typedef _Float16 v4h __attribute__((ext_vector_type(4)));
typedef float    v4f __attribute__((ext_vector_type(4)));

#define MFMA(a, b, c) __builtin_amdgcn_mfma_f32_16x16x32_f16((a), (b), (c), 0, 0, 0)

// ---------------- workspace layout (float offsets) ----------------
#define OFF_LN16    0u
#define OFF_LNLO    3145728u
#define OFF_FQ16    4194304u
#define OFF_FK16    5242880u
#define OFF_FVHT    6291456u
#define OFF_FVLT    7340032u
#define OFF_WINTH   8388608u
#define OFF_WINTL   8519680u
#define OFF_WOUTTH  8650752u
#define OFF_WOUTTL  8781824u
#define OFF_AVH     8912896u
#define OFF_AVL     9961472u
#define OFF_RQ1     11010048u
#define OFF_RQ2     11042816u
#define OFF_MUQ     11075584u
#define OFF_RK1     11108352u
#define OFF_RK2     11141120u
#define OFF_SK      11173888u
#define OFF_VC      11206656u   // 65536 (2 halves)
#define OFF_RMAX    11272192u   // 65536 (2 halves)
#define OFF_NUACC   11337728u   // 2048
#define OFF_PB      11339776u   // 1024*4
#define OFF_PB2     11343872u   // 1024*2
#define OFF_FEAT    11345920u   // 1024
#define OFF_WV      11346944u   // 24
#define OFF_SCAL    11346968u   // 8
#define OFF_DOTS    11346976u   // f16[33554432] = 16777216 floats

__device__ __forceinline__ float clampf(float x, float lo, float hi) {
    return fminf(fmaxf(x, lo), hi);
}

__global__ void k_zero(float* feat, float* nuacck) {
    int i = blockIdx.x * 256 + threadIdx.x;
    if (i < 1024) feat[i] = 0.0f;
    if (i < 2048) nuacck[i] = 0.0f;
}

// transpose + hi/lo split of a 512x512 weight: W[k][c] -> WT{h,l}[c][k]
__global__ __launch_bounds__(256) void k_wprep(const float* __restrict__ Win,
        const float* __restrict__ Wout, f16* __restrict__ WinTh, f16* __restrict__ WinTl,
        f16* __restrict__ WoutTh, f16* __restrict__ WoutTl) {
    __shared__ float lds[64][68];
    const float* W = blockIdx.z ? Wout : Win;
    f16* Th = blockIdx.z ? WoutTh : WinTh;
    f16* Tl = blockIdx.z ? WoutTl : WinTl;
    int k0 = blockIdx.y * 64, c0 = blockIdx.x * 64;
    int t = threadIdx.x;
    #pragma unroll
    for (int p = 0; p < 4; ++p) {
        int flat = p * 1024 + t * 4;
        int r = flat >> 6, c = flat & 63;
        *(float4*)&lds[r][c] = *(const float4*)&W[(size_t)(k0 + r) * 512 + c0 + c];
    }
    __syncthreads();
    int c = t >> 2, kk = (t & 3) * 16;
    #pragma unroll
    for (int half = 0; half < 2; ++half) {
        v8h h8, l8;
        #pragma unroll
        for (int ii = 0; ii < 8; ++ii) {
            float v = lds[kk + half * 8 + ii][c];
            f16 h = (f16)v;
            h8[ii] = h;
            l8[ii] = (f16)(v - (float)h);
        }
        *(v8h*)&Th[(size_t)(c0 + c) * 512 + k0 + kk + half * 8] = h8;
        *(v8h*)&Tl[(size_t)(c0 + c) * 512 + k0 + kk + half * 8] = l8;
    }
}

// LayerNorm all 12288 tokens -> ln16 f16; v tokens also get lo residual
__global__ __launch_bounds__(256) void k_ln16(const float* __restrict__ q,
        const float* __restrict__ kk, const float* __restrict__ v,
        const float* __restrict__ lnw, const float* __restrict__ lnb,
        f16* __restrict__ ln16, f16* __restrict__ lnlo) {
    int t = threadIdx.x, wid = t >> 6, lane = t & 63;
    int token = blockIdx.x * 4 + wid;
    int inp = token >> 12, lt = token & 4095;
    const float* xp = (inp == 0) ? q : ((inp == 1) ? kk : v);
    const float4* xr = (const float4*)(xp + (size_t)lt * 512);
    float4 a = xr[lane], b = xr[lane + 64];
    float s = a.x + a.y + a.z + a.w + b.x + b.y + b.z + b.w;
    float s2 = a.x*a.x + a.y*a.y + a.z*a.z + a.w*a.w
             + b.x*b.x + b.y*b.y + b.z*b.z + b.w*b.w;
    for (int o = 32; o > 0; o >>= 1) { s += __shfl_down(s, o); s2 += __shfl_down(s2, o); }
    float m_ = __shfl(s, 0) * (1.0f / 512.0f);
    float var = __shfl(s2, 0) * (1.0f / 512.0f) - m_ * m_;
    var = fmaxf(var, 0.0f);
    float rs = rsqrtf(var + 1e-5f);
    const float4* w4 = (const float4*)lnw;
    const float4* b4 = (const float4*)lnb;
    float4 wa = w4[lane], wb = w4[lane + 64], ba = b4[lane], bb = b4[lane + 64];
    float ga[4] = { (a.x - m_) * rs * wa.x + ba.x, (a.y - m_) * rs * wa.y + ba.y,
                    (a.z - m_) * rs * wa.z + ba.z, (a.w - m_) * rs * wa.w + ba.w };
    float gb[4] = { (b.x - m_) * rs * wb.x + bb.x, (b.y - m_) * rs * wb.y + bb.y,
                    (b.z - m_) * rs * wb.z + bb.z, (b.w - m_) * rs * wb.w + bb.w };
    f16* orow = ln16 + (size_t)token * 512;
    v4h ha, hb;
    #pragma unroll
    for (int i = 0; i < 4; ++i) { ha[i] = (f16)ga[i]; hb[i] = (f16)gb[i]; }
    *(v4h*)&orow[lane * 4] = ha;
    *(v4h*)&orow[lane * 4 + 256] = hb;
    if (inp == 2) {
        f16* lrow = lnlo + (size_t)lt * 512;
        v4h la, lb;
        #pragma unroll
        for (int i = 0; i < 4; ++i) {
            la[i] = (f16)(ga[i] - (float)ha[i]);
            lb[i] = (f16)(gb[i] - (float)hb[i]);
        }
        *(v4h*)&lrow[lane * 4] = la;
        *(v4h*)&lrow[lane * 4 + 256] = lb;
    }
}

// LN16 @ Win (MFMA). MODE 0: q (fq16 + recip stats). MODE 1: k. MODE 2: v.
template<int MODE>
__device__ __forceinline__ void proj_body(const f16* __restrict__ A16,
        const f16* __restrict__ Alo,
        const f16* __restrict__ BTh, const f16* __restrict__ BTl,
        f16* __restrict__ fout16, f16* __restrict__ fhT, f16* __restrict__ flT,
        float* __restrict__ oA, float* __restrict__ oB, float* __restrict__ oC,
        float* __restrict__ feat, float* __restrict__ nuacck) {
    int t = threadIdx.x, l = t & 63, w = t >> 6;
    int wr = w >> 1, wc = w & 1;
    int col0 = blockIdx.x * 128 + wc * 64;
    int tok0 = blockIdx.y * 128 + wr * 64;
    int lr = l & 15, kg = (l >> 4) * 8;
    int rg4 = (l >> 4) * 4;
    v4f acc[4][4] = {};
    for (int ks = 0; ks < 512; ks += 32) {
        v8h a[4], b[4];
        #pragma unroll
        for (int i = 0; i < 4; ++i)
            a[i] = *(const v8h*)&A16[(size_t)(tok0 + i * 16 + lr) * 512 + ks + kg];
        #pragma unroll
        for (int j = 0; j < 4; ++j)
            b[j] = *(const v8h*)&BTh[(size_t)(col0 + j * 16 + lr) * 512 + ks + kg];
        if constexpr (MODE == 2) {
            v8h al[4], bl[4];
            #pragma unroll
            for (int i = 0; i < 4; ++i)
                al[i] = *(const v8h*)&Alo[(size_t)(tok0 + i * 16 + lr) * 512 + ks + kg];
            #pragma unroll
            for (int j = 0; j < 4; ++j)
                bl[j] = *(const v8h*)&BTl[(size_t)(col0 + j * 16 + lr) * 512 + ks + kg];
            #pragma unroll
            for (int i = 0; i < 4; ++i)
                #pragma unroll
                for (int j = 0; j < 4; ++j) {
                    acc[i][j] = MFMA(a[i], b[j], acc[i][j]);
                    acc[i][j] = MFMA(a[i], bl[j], acc[i][j]);
                    acc[i][j] = MFMA(al[i], b[j], acc[i][j]);
                }
        } else {
            #pragma unroll
            for (int i = 0; i < 4; ++i)
                #pragma unroll
                for (int j = 0; j < 4; ++j)
                    acc[i][j] = MFMA(a[i], b[j], acc[i][j]);
        }
    }
    int h = col0 >> 6;
    #pragma unroll
    for (int i = 0; i < 4; ++i)
        #pragma unroll
        for (int j = 0; j < 4; ++j)
            #pragma unroll
            for (int r = 0; r < 4; ++r) {
                int token = tok0 + i * 16 + rg4 + r;
                int d = j * 16 + lr;
                int qi = token >> 10, n = token & 1023;
                float val = acc[i][j][r];
                if constexpr (MODE != 2) {
                    fout16[((size_t)((h << 2) + qi) * 1024 + n) * 64 + d] = (f16)val;
                } else {
                    f16 hi = (f16)val;
                    fhT[((size_t)((h << 2) + qi) * 64 + d) * 1024 + n] = hi;
                    flT[((size_t)((h << 2) + qi) * 64 + d) * 1024 + n] = (f16)(val - (float)hi);
                }
            }
    if constexpr (MODE != 2) {
        #pragma unroll
        for (int i = 0; i < 4; ++i)
            #pragma unroll
            for (int r = 0; r < 4; ++r) {
                float s = 0.f, s2 = 0.f;
                #pragma unroll
                for (int j = 0; j < 4; ++j) { float v = acc[i][j][r]; s += v; s2 += v * v; }
                #pragma unroll
                for (int mk = 1; mk <= 8; mk <<= 1) {
                    s += __shfl_xor(s, mk); s2 += __shfl_xor(s2, mk);
                }
                if (lr == 0) {
                    int token = tok0 + i * 16 + rg4 + r;
                    int qi = token >> 10, n = token & 1023;
                    int row = ((h << 2) + qi) * 1024 + n;
                    float nv = sqrtf(s2);
                    oA[row] = 1.0f / (nv + 1e-6f);
                    oB[row] = 1.0f / fmaxf(nv, 1e-4f);
                    oC[row] = (MODE == 0) ? s * (1.0f / 64.0f) : s;
                }
            }
        float cs[4];
        #pragma unroll
        for (int j = 0; j < 4; ++j) {
            float c = 0.f;
            #pragma unroll
            for (int i = 0; i < 4; ++i)
                #pragma unroll
                for (int r = 0; r < 4; ++r) c += acc[i][j][r];
            c += __shfl_xor(c, 16); c += __shfl_xor(c, 32);
            cs[j] = c;
        }
        if (l < 16) {
            #pragma unroll
            for (int j = 0; j < 4; ++j)
                atomicAdd(&feat[h * 128 + (MODE == 1 ? 64 : 0) + j * 16 + l],
                          cs[j] * (1.0f / 4096.0f));
            if constexpr (MODE == 1) {
                int qi = tok0 >> 10;
                #pragma unroll
                for (int j = 0; j < 4; ++j)
                    atomicAdd(&nuacck[((h << 2) + qi) * 64 + j * 16 + l], cs[j]);
            }
        }
    }
}

__global__ __launch_bounds__(256) void k_proj_all(const f16* __restrict__ ln16,
        const f16* __restrict__ lnlo,
        const f16* __restrict__ BTh, const f16* __restrict__ BTl,
        f16* __restrict__ fq16, f16* __restrict__ fk16,
        f16* __restrict__ fvhT, f16* __restrict__ fvlT,
        float* __restrict__ rq1, float* __restrict__ rq2, float* __restrict__ muq,
        float* __restrict__ rk1, float* __restrict__ rk2, float* __restrict__ sk,
        float* __restrict__ feat, float* __restrict__ nuacck) {
    int mode = blockIdx.z;
    if (mode == 0)
        proj_body<0>(ln16, nullptr, BTh, BTl, fq16, nullptr, nullptr,
                     rq1, rq2, muq, feat, nullptr);
    else if (mode == 1)
        proj_body<1>(ln16 + 2097152u, nullptr, BTh, BTl, fk16, nullptr, nullptr,
                     rk1, rk2, sk, feat, nuacck);
    else
        proj_body<2>(ln16 + 4194304u, lnlo, BTh, BTl, nullptr, fvhT, fvlT,
                     nullptr, nullptr, nullptr, nullptr, nullptr);
}

// tiny MLP weight predictor, one block per head -> wv[h][3]
__global__ __launch_bounds__(256) void k_mlp(const float* __restrict__ feat,
        const float* __restrict__ W1, const float* __restrict__ b1,
        const float* __restrict__ lw, const float* __restrict__ lb,
        const float* __restrict__ W2, const float* __restrict__ b2,
        const float* __restrict__ W3, const float* __restrict__ b3,
        const float* __restrict__ W4, const float* __restrict__ b4,
        const float* __restrict__ wtemp, float* wv) {
    __shared__ float h1[256], h2[192], h3[64], red[8];
    int t = threadIdx.x;
    int h = blockIdx.x;
    float p = 0.0f;
    for (int i = 0; i < 128; ++i) p += feat[h * 128 + i] * W1[i * 256 + t];
    p += b1[t];
    float s = p, s2 = p * p;
    for (int o = 32; o > 0; o >>= 1) { s += __shfl_down(s, o); s2 += __shfl_down(s2, o); }
    if ((t & 63) == 0) { red[t >> 6] = s; red[4 + (t >> 6)] = s2; }
    __syncthreads();
    float S = red[0] + red[1] + red[2] + red[3];
    float S2 = red[4] + red[5] + red[6] + red[7];
    float mu = S / 256.0f;
    float var = S2 / 256.0f - mu * mu; if (var < 0.0f) var = 0.0f;
    float xh = (p - mu) * rsqrtf(var + 1e-5f) * lw[t] + lb[t];
    h1[t] = fmaxf(xh, 0.0f);
    __syncthreads();
    if (t < 192) {
        float a = 0.0f;
        for (int i = 0; i < 256; ++i) a += h1[i] * W2[i * 192 + t];
        h2[t] = fmaxf(a + b2[t], 0.0f);
    }
    __syncthreads();
    if (t < 64) {
        float a = 0.0f;
        for (int i = 0; i < 192; ++i) a += h2[i] * W3[i * 64 + t];
        h3[t] = fmaxf(a + b3[t], 0.0f);
    }
    __syncthreads();
    if (t == 0) {
        float lg[3];
        for (int j = 0; j < 3; ++j) {
            float a = 0.0f;
            for (int i = 0; i < 64; ++i) a += h3[i] * W4[i * 3 + j];
            lg[j] = a + b4[j];
        }
        float mx = fmaxf(lg[0], fmaxf(lg[1], lg[2]));
        float e0 = expf(lg[0] - mx), e1 = expf(lg[1] - mx), e2 = expf(lg[2] - mx);
        float se = e0 + e1 + e2;
        float pr0 = e0 / se, pr1 = e1 / se, pr2 = e2 / se;
        float wt = wtemp[0]; wt = fminf(fmaxf(wt, 0.01f), 1.0f);
        float q0 = pr0 / wt, q1 = pr1 / wt, q2 = pr2 / wt;
        float m2 = fmaxf(q0, fmaxf(q1, q2));
        float f0 = expf(q0 - m2), f1 = expf(q1 - m2), f2 = expf(q2 - m2);
        float sf = f0 + f1 + f2; f0 /= sf; f1 /= sf; f2 /= sf;
        f0 = fminf(fmaxf(f0, 0.01f), 0.95f);
        f1 = fminf(fmaxf(f1, 0.01f), 0.95f);
        f2 = fminf(fmaxf(f2, 0.01f), 0.95f);
        float sw = f0 + f1 + f2;
        wv[h * 3 + 0] = f0 / sw; wv[h * 3 + 1] = f1 / sw; wv[h * 3 + 2] = f2 / sw;
    }
}

// ---- shared per-pass preamble for passA/passB: grid (16, 2, 32) ----
#define PASS_PREAMBLE_AB                                                       \
    int hq = blockIdx.z;                                                       \
    int half = blockIdx.y;                                                     \
    int m0base = half * 512;                                                   \
    int t = threadIdx.x, l = t & 63, w = t >> 6;                               \
    int lr = l & 15, kg = (l >> 4) * 8, rg4 = (l >> 4) * 4;                    \
    int nb = blockIdx.x * 64 + w * 16;                                         \
    const f16* Q = fq16 + (size_t)hq * 65536;                                  \
    const f16* K = fk16 + (size_t)hq * 65536;                                  \
    v8h aq0 = *(const v8h*)&Q[(size_t)(nb + lr) * 64 + kg];                    \
    v8h aq1 = *(const v8h*)&Q[(size_t)(nb + lr) * 64 + 32 + kg];               \
    const float inv1024 = 1.0f / 1024.0f;                                      \
    float uvp = nuacck[hq * 64 + l] * inv1024;                                 \
    _Pragma("unroll")                                                          \
    for (int o = 32; o > 0; o >>= 1) uvp += __shfl_xor(uvp, o);                \
    float uv = uvp;                                                            \
    float tp = 0.f;                                                            \
    _Pragma("unroll")                                                          \
    for (int e = 0; e < 8; ++e)                                                \
        tp += (float)aq0[e] * nuacck[hq * 64 + kg + e]                         \
            + (float)aq1[e] * nuacck[hq * 64 + 32 + kg + e];                   \
    tp *= inv1024;                                                             \
    tp += __shfl_xor(tp, 16);                                                  \
    tp += __shfl_xor(tp, 32);                                                  \
    float muv[4], tv[4];                                                       \
    _Pragma("unroll")                                                          \
    for (int r = 0; r < 4; ++r) {                                              \
        muv[r] = muq[hq * 1024 + nb + rg4 + r];                                \
        tv[r] = __shfl(tp, rg4 + r);                                           \
    }                                                                          \
    const float Acs = (0.001f / 1024.0f) / 8.0001f;                            \
    float Pr[4], Gr[4];                                                        \
    _Pragma("unroll")                                                          \
    for (int r = 0; r < 4; ++r) {                                              \
        Gr[r] = Acs * muv[r];                                                  \
        Pr[r] = Acs * fmaf(muv[r], uv, -tv[r]);                                \
    }

#define LOAD_KTILE(m0a)                                                        \
    v8h b0[4], b1[4];                                                          \
    _Pragma("unroll")                                                          \
    for (int j = 0; j < 4; ++j) {                                              \
        b0[j] = *(const v8h*)&K[(size_t)((m0a) + j * 16 + lr) * 64 + kg];      \
        b1[j] = *(const v8h*)&K[(size_t)((m0a) + j * 16 + lr) * 64 + 32 + kg]; \
    }

// pass A: cos/cov global sums + per-row margin means (K-half split)
__global__ __launch_bounds__(256) void k_passA(const f16* __restrict__ fq16,
        const f16* __restrict__ fk16, const float* __restrict__ rq1,
        const float* __restrict__ rq2, const float* __restrict__ muq,
        const float* __restrict__ rk1, const float* __restrict__ rk2,
        const float* __restrict__ sk, const float* __restrict__ nuacck,
        float* __restrict__ vcrow, float* __restrict__ pb) {
    __shared__ float rk1s[512], rk2s[512], sks[512];
    PASS_PREAMBLE_AB
    {
        int i2 = t * 2;
        *(float2*)&rk1s[i2] = *(const float2*)&rk1[hq * 1024 + m0base + i2];
        *(float2*)&rk2s[i2] = *(const float2*)&rk2[hq * 1024 + m0base + i2];
        *(float2*)&sks[i2]  = *(const float2*)&sk[hq * 1024 + m0base + i2];
    }
    __syncthreads();
    float rq1v[4], rq2v[4];
    #pragma unroll
    for (int r = 0; r < 4; ++r) {
        rq1v[r] = rq1[hq * 1024 + nb + rg4 + r];
        rq2v[r] = rq2[hq * 1024 + nb + rg4 + r];
    }
    float scos = 0, s2cos = 0, scov = 0, s2cov = 0;
    float mp[4] = {};
    #pragma unroll 2
    for (int m0 = 0; m0 < 512; m0 += 64) {
        LOAD_KTILE(m0base + m0)
        float rk1v[4], rk2v[4], skv[4];
        #pragma unroll
        for (int j = 0; j < 4; ++j) {
            int cg = m0 + j * 16 + lr;
            rk1v[j] = rk1s[cg]; rk2v[j] = rk2s[cg]; skv[j] = sks[cg];
        }
        v4f acc[4] = {};
        #pragma unroll
        for (int j = 0; j < 4; ++j) {
            acc[j] = MFMA(aq0, b0[j], acc[j]);
            acc[j] = MFMA(aq1, b1[j], acc[j]);
        }
        #pragma unroll
        for (int j = 0; j < 4; ++j)
            #pragma unroll
            for (int r = 0; r < 4; ++r) {
                float rv = acc[j][r];
                float cosv = clampf(rv * rq1v[r] * rk1v[j], -0.95f, 0.95f);
                float x2 = rv * rq2v[r] * rk2v[j];
                float marg = fmaxf(0.01f - fmaxf(x2, -0.95f), 0.0f);
                float cov = clampf(fmaf(-Gr[r], skv[j], fmaf(Acs, rv, Pr[r])),
                                   -50.0f, 50.0f);
                scos += cosv; s2cos = fmaf(cosv, cosv, s2cos);
                scov += cov;  s2cov = fmaf(cov, cov, s2cov);
                mp[r] += marg;
            }
    }
    #pragma unroll
    for (int r = 0; r < 4; ++r) {
        float m_ = mp[r];
        m_ += __shfl_xor(m_, 1); m_ += __shfl_xor(m_, 2);
        m_ += __shfl_xor(m_, 4); m_ += __shfl_xor(m_, 8);
        if (lr == 0) vcrow[half * 32768 + hq * 1024 + nb + rg4 + r] = m_ * inv1024;
    }
    for (int o = 32; o > 0; o >>= 1) {
        scos += __shfl_down(scos, o); s2cos += __shfl_down(s2cos, o);
        scov += __shfl_down(scov, o); s2cov += __shfl_down(s2cov, o);
    }
    __shared__ float bs[4][4];
    if (l == 0) { bs[w][0] = scos; bs[w][1] = s2cos; bs[w][2] = scov; bs[w][3] = s2cov; }
    __syncthreads();
    if (t == 0) {
        int bid = (hq * 2 + half) * 16 + blockIdx.x;
        pb[bid * 4 + 0] = bs[0][0] + bs[1][0] + bs[2][0] + bs[3][0];
        pb[bid * 4 + 1] = bs[0][1] + bs[1][1] + bs[2][1] + bs[3][1];
        pb[bid * 4 + 2] = bs[0][2] + bs[1][2] + bs[2][2] + bs[3][2];
        pb[bid * 4 + 3] = bs[0][3] + bs[1][3] + bs[2][3] + bs[3][3];
    }
}

__global__ __launch_bounds__(256) void k_fin1(const float* __restrict__ pb,
        const float* __restrict__ vcrow, float* __restrict__ scal) {
    int t = threadIdx.x;
    double s0 = 0, s1 = 0, s2 = 0, s3 = 0, s4 = 0, s5 = 0;
    for (int i = t; i < 1024; i += 256) {
        s0 += pb[i * 4 + 0]; s1 += pb[i * 4 + 1];
        s2 += pb[i * 4 + 2]; s3 += pb[i * 4 + 3];
    }
    for (int i = t; i < 32768; i += 256) {
        double rm = (double)(vcrow[i] + vcrow[32768 + i]);
        s4 += rm; s5 += rm * rm;
    }
    for (int o = 32; o > 0; o >>= 1) {
        s0 += __shfl_down(s0, o); s1 += __shfl_down(s1, o); s2 += __shfl_down(s2, o);
        s3 += __shfl_down(s3, o); s4 += __shfl_down(s4, o); s5 += __shfl_down(s5, o);
    }
    __shared__ double red[6][4];
    int wid = t >> 6, lane = t & 63;
    if (lane == 0) { red[0][wid] = s0; red[1][wid] = s1; red[2][wid] = s2;
                     red[3][wid] = s3; red[4][wid] = s4; red[5][wid] = s5; }
    __syncthreads();
    if (t == 0) {
        double S0 = red[0][0] + red[0][1] + red[0][2] + red[0][3];
        double S1 = red[1][0] + red[1][1] + red[1][2] + red[1][3];
        double S2 = red[2][0] + red[2][1] + red[2][2] + red[2][3];
        double S3 = red[3][0] + red[3][1] + red[3][2] + red[3][3];
        double S4 = red[4][0] + red[4][1] + red[4][2] + red[4][3];
        double S5 = red[5][0] + red[5][1] + red[5][2] + red[5][3];
        const double cnt = 33554432.0;
        scal[0] = (float)sqrt(fmax(0.0, (S1 - S0 * S0 / cnt) / (cnt - 1.0)));
        scal[1] = (float)sqrt(fmax(0.0, (S3 - S2 * S2 / cnt) / (cnt - 1.0)));
        double V4 = S4 * 1024.0, V5 = S5 * 1024.0;
        scal[2] = (float)sqrt(fmax(0.0, (V5 - V4 * V4 / cnt) / (cnt - 1.0)));
    }
}

// pass B: dots -> f16 buffer, sum/sumsq, row max (K-half split)
__global__ __launch_bounds__(256) void k_passB(const f16* __restrict__ fq16,
        const f16* __restrict__ fk16, const float* __restrict__ rq1,
        const float* __restrict__ muq, const float* __restrict__ rk1,
        const float* __restrict__ sk, const float* __restrict__ nuacck,
        const float* __restrict__ vcrow, const float* __restrict__ wv,
        const float* __restrict__ scal, float* __restrict__ rmax,
        f16* __restrict__ dots, float* __restrict__ pb2) {
    __shared__ f16 P[4][16][72];
    __shared__ float rk1s[512], sks[512];
    PASS_PREAMBLE_AB
    {
        int i2 = t * 2;
        *(float2*)&rk1s[i2] = *(const float2*)&rk1[hq * 1024 + m0base + i2];
        *(float2*)&sks[i2]  = *(const float2*)&sk[hq * 1024 + m0base + i2];
    }
    __syncthreads();
    int h = hq >> 2;
    float s1 = scal[0] + 1e-4f, s2v = scal[1] + 1e-4f, s3 = scal[2] + 1e-4f;
    float w0 = wv[h * 3], w1 = wv[h * 3 + 1], w2 = wv[h * 3 + 2];
    float fc1 = w0 / s1;
    float fc2 = w1 * 0.3f / s2v;
    float c3 = w2 * 0.3f / s3;
    float rq1v[4], addc[4];
    #pragma unroll
    for (int r = 0; r < 4; ++r) {
        int row = hq * 1024 + nb + rg4 + r;
        rq1v[r] = rq1[row];
        addc[r] = (vcrow[row] + vcrow[32768 + row]) * c3;
    }
    float sd = 0.f, s2d = 0.f;
    float dmax[4] = { -1e30f, -1e30f, -1e30f, -1e30f };
    int rr = l & 15, cg2 = (l >> 4) * 8;
    for (int m0 = 0; m0 < 512; m0 += 64) {
        LOAD_KTILE(m0base + m0)
        float rk1v[4], skv[4];
        #pragma unroll
        for (int j = 0; j < 4; ++j) {
            int cgl = m0 + j * 16 + lr;
            rk1v[j] = rk1s[cgl]; skv[j] = sks[cgl];
        }
        v4f acc[4] = {};
        #pragma unroll
        for (int j = 0; j < 4; ++j) {
            acc[j] = MFMA(aq0, b0[j], acc[j]);
            acc[j] = MFMA(aq1, b1[j], acc[j]);
        }
        #pragma unroll
        for (int j = 0; j < 4; ++j)
            #pragma unroll
            for (int r = 0; r < 4; ++r) {
                float rv = acc[j][r];
                float cosv = clampf(rv * rq1v[r] * rk1v[j], -0.95f, 0.95f);
                float cov = clampf(fmaf(-Gr[r], skv[j], fmaf(Acs, rv, Pr[r])),
                                   -50.0f, 50.0f);
                float dd = fmaf(fc2, cov, fmaf(fc1, cosv, addc[r]));
                sd += dd; s2d = fmaf(dd, dd, s2d);
                dmax[r] = fmaxf(dmax[r], dd);
                P[w][rg4 + r][j * 16 + lr] = (f16)dd;
            }
        v8h d0 = *(const v8h*)&P[w][rr][cg2];
        v8h d1 = *(const v8h*)&P[w][rr][32 + cg2];
        f16* DP = dots + ((size_t)(hq * 1024 + nb + rr)) * 1024 + m0base + m0;
        *(v8h*)&DP[cg2] = d0;
        *(v8h*)&DP[32 + cg2] = d1;
    }
    #pragma unroll
    for (int r = 0; r < 4; ++r) {
        float m_ = dmax[r];
        m_ = fmaxf(m_, __shfl_xor(m_, 1)); m_ = fmaxf(m_, __shfl_xor(m_, 2));
        m_ = fmaxf(m_, __shfl_xor(m_, 4)); m_ = fmaxf(m_, __shfl_xor(m_, 8));
        if (lr == 0) rmax[half * 32768 + hq * 1024 + nb + rg4 + r] = m_;
    }
    for (int o = 32; o > 0; o >>= 1) { sd += __shfl_down(sd, o); s2d += __shfl_down(s2d, o); }
    __shared__ float fr[2][4];
    if (l == 0) { fr[0][w] = sd; fr[1][w] = s2d; }
    __syncthreads();
    if (t == 0) {
        int bid = (hq * 2 + half) * 16 + blockIdx.x;
        pb2[bid * 2 + 0] = fr[0][0] + fr[0][1] + fr[0][2] + fr[0][3];
        pb2[bid * 2 + 1] = fr[1][0] + fr[1][1] + fr[1][2] + fr[1][3];
    }
}

__global__ __launch_bounds__(256) void k_fin2(const float* __restrict__ pb2,
        float* __restrict__ scal) {
    int t = threadIdx.x;
    double s6 = 0, s7 = 0;
    for (int i = t; i < 1024; i += 256) { s6 += pb2[i * 2]; s7 += pb2[i * 2 + 1]; }
    for (int o = 32; o > 0; o >>= 1) { s6 += __shfl_down(s6, o); s7 += __shfl_down(s7, o); }
    __shared__ double red[2][4];
    int wid = t >> 6, lane = t & 63;
    if (lane == 0) { red[0][wid] = s6; red[1][wid] = s7; }
    __syncthreads();
    if (t == 0) {
        double S6 = red[0][0] + red[0][1] + red[0][2] + red[0][3];
        double S7 = red[1][0] + red[1][1] + red[1][2] + red[1][3];
        const double cnt = 33554432.0;
        double ds = sqrt(fmax(0.0, (S7 - S6 * S6 / cnt) / (cnt - 1.0)));
        float temp = (ds < 1e-5) ? 0.01f : ((ds < 1e-3) ? 0.05f : (0.2f + (float)ds * 2.0f));
        temp = fminf(fmaxf(temp, 0.01f), 8.0f);
        scal[3] = temp;
    }
}

// pass C: 512 threads = 4 row-groups x 2 K-halves; dots prefetch; LDS combine
__global__ __launch_bounds__(512) void k_passC(const f16* __restrict__ dots,
        const float* __restrict__ rmax, const float* __restrict__ scal,
        const f16* __restrict__ fvhT, const f16* __restrict__ fvlT,
        f16* __restrict__ avh, f16* __restrict__ avl) {
    __shared__ float cb[4][17][64];
    int hq = blockIdx.y;
    int t = threadIdx.x, l = t & 63, w = t >> 6;
    int rg = w & 3, kh = w >> 2;
    int lr = l & 15, kg = (l >> 4) * 8, rg4 = (l >> 4) * 4;
    int nb = blockIdx.x * 64 + rg * 16;
    int row = hq * 1024 + nb + lr;
    float invt = 1.0f / scal[3];
    float rmi = fmaxf(rmax[row], rmax[32768 + row]) * invt;
    const f16* Dk = dots + (size_t)row * 1024 + kh * 512;
    const f16* VH = fvhT + ((size_t)hq * 64 + lr) * 1024 + kh * 512;
    const f16* VL = fvlT + ((size_t)hq * 64 + lr) * 1024 + kh * 512;
    v4f acc[4] = {};
    float rs = 0.f;
    v8h dn0 = *(const v8h*)&Dk[kg];
    v8h dn1 = *(const v8h*)&Dk[32 + kg];
    for (int it = 0; it < 8; ++it) {
        int ks = it * 64;
        v8h dv0 = dn0, dv1 = dn1;
        v8h vh0[4], vl0[4], vh1[4], vl1[4];
        #pragma unroll
        for (int j = 0; j < 4; ++j) {
            size_t vb = (size_t)j * 16384 + ks + kg;
            vh0[j] = *(const v8h*)&VH[vb];
            vl0[j] = *(const v8h*)&VL[vb];
            vh1[j] = *(const v8h*)&VH[vb + 32];
            vl1[j] = *(const v8h*)&VL[vb + 32];
        }
        if (it < 7) {
            dn0 = *(const v8h*)&Dk[ks + 64 + kg];
            dn1 = *(const v8h*)&Dk[ks + 96 + kg];
        }
        v8h pa0, pa1;
        #pragma unroll
        for (int e = 0; e < 8; ++e) {
            float p0 = __expf(fmaf((float)dv0[e], invt, -rmi));
            float p1 = __expf(fmaf((float)dv1[e], invt, -rmi));
            f16 q0 = (f16)p0, q1 = (f16)p1;
            pa0[e] = q0; pa1[e] = q1;
            rs += (float)q0 + (float)q1;
        }
        #pragma unroll
        for (int j = 0; j < 4; ++j) {
            acc[j] = MFMA(pa0, vh0[j], acc[j]);
            acc[j] = MFMA(pa0, vl0[j], acc[j]);
            acc[j] = MFMA(pa1, vh1[j], acc[j]);
            acc[j] = MFMA(pa1, vl1[j], acc[j]);
        }
    }
    if (kh == 1) {
        #pragma unroll
        for (int j = 0; j < 4; ++j)
            #pragma unroll
            for (int r = 0; r < 4; ++r)
                cb[rg][j * 4 + r][l] = acc[j][r];
        cb[rg][16][l] = rs;
    }
    __syncthreads();
    if (kh == 0) {
        #pragma unroll
        for (int j = 0; j < 4; ++j)
            #pragma unroll
            for (int r = 0; r < 4; ++r)
                acc[j][r] += cb[rg][j * 4 + r][l];
        rs += cb[rg][16][l];
        rs += __shfl_xor(rs, 16);
        rs += __shfl_xor(rs, 32);
        float rinv[4];
        #pragma unroll
        for (int r = 0; r < 4; ++r) rinv[r] = 1.0f / __shfl(rs, rg4 + r);
        #pragma unroll
        for (int j = 0; j < 4; ++j)
            #pragma unroll
            for (int r = 0; r < 4; ++r) {
                float val = acc[j][r] * rinv[r];
                size_t idx = ((size_t)(hq * 1024 + nb + rg4 + r)) * 64 + j * 16 + lr;
                f16 hi = (f16)val;
                avh[idx] = hi;
                avl[idx] = (f16)(val - (float)hi);
            }
    }
}

// out = av @ Wout + bout (MFMA, 3-way split)
__global__ __launch_bounds__(256) void k_out_mfma(const f16* __restrict__ avh,
        const f16* __restrict__ avl,
        const f16* __restrict__ WoutTh, const f16* __restrict__ WoutTl,
        const float* __restrict__ bout, float* __restrict__ out) {
    __shared__ float red[2][4][4][4][64];
    int t = threadIdx.x, l = t & 63, w = t >> 6;
    int wc = w & 1, kh = w >> 1;
    int col0 = blockIdx.x * 128 + wc * 64;
    int tok0 = blockIdx.y * 64;
    int qi = tok0 >> 10, nb = tok0 & 1023;
    int lr = l & 15, kg = (l >> 4) * 8;
    v4f acc[4][4] = {};
    for (int ks8 = 0; ks8 < 8; ++ks8) {
        int ks = kh * 256 + ks8 * 32;
        int f = ks + kg;
        int h = f >> 6, d = f & 63;
        size_t hb = (size_t)((h << 2) + qi) * 1024;
        v8h ah[4], al4[4], bh[4], bl4[4];
        #pragma unroll
        for (int i = 0; i < 4; ++i) {
            int n = nb + i * 16 + lr;
            ah[i]  = *(const v8h*)&avh[(hb + n) * 64 + d];
            al4[i] = *(const v8h*)&avl[(hb + n) * 64 + d];
        }
        #pragma unroll
        for (int j = 0; j < 4; ++j) {
            bh[j]  = *(const v8h*)&WoutTh[(size_t)(col0 + j * 16 + lr) * 512 + ks + kg];
            bl4[j] = *(const v8h*)&WoutTl[(size_t)(col0 + j * 16 + lr) * 512 + ks + kg];
        }
        #pragma unroll
        for (int i = 0; i < 4; ++i)
            #pragma unroll
            for (int j = 0; j < 4; ++j) {
                acc[i][j] = MFMA(ah[i], bh[j], acc[i][j]);
                acc[i][j] = MFMA(ah[i], bl4[j], acc[i][j]);
                acc[i][j] = MFMA(al4[i], bh[j], acc[i][j]);
            }
    }
    if (kh == 0) {
        #pragma unroll
        for (int i = 0; i < 4; ++i)
            #pragma unroll
            for (int j = 0; j < 4; ++j)
                #pragma unroll
                for (int r = 0; r < 4; ++r)
                    red[wc][i][j][r][l] = acc[i][j][r];
    }
    __syncthreads();
    if (kh == 1) {
        #pragma unroll
        for (int i = 0; i < 4; ++i)
            #pragma unroll
            for (int j = 0; j < 4; ++j) {
                int col = col0 + j * 16 + lr;
                float bo = bout[col];
                #pragma unroll
                for (int r = 0; r < 4; ++r) {
                    float val = acc[i][j][r] + red[wc][i][j][r][l] + bo;
                    int token = tok0 + i * 16 + (l >> 4) * 4 + r;
                    out[(size_t)token * 512 + col] = val;
                }
            }
    }
}

extern "C" void kernel_launch(void* const* d_in, const int* in_sizes, int n_in,
                              void* d_out, int out_size, void* d_ws, size_t ws_size,
                              hipStream_t stream) {
    const float* q     = (const float*)d_in[0];
    const float* k     = (const float*)d_in[1];
    const float* v     = (const float*)d_in[2];
    const float* ln_w  = (const float*)d_in[3];
    const float* ln_b  = (const float*)d_in[4];
    const float* W_in  = (const float*)d_in[5];
    const float* W_out = (const float*)d_in[6];
    const float* b_out = (const float*)d_in[7];
    const float* wp_W1 = (const float*)d_in[8];
    const float* wp_b1 = (const float*)d_in[9];
    const float* wp_lw = (const float*)d_in[10];
    const float* wp_lb = (const float*)d_in[11];
    const float* wp_W2 = (const float*)d_in[12];
    const float* wp_b2 = (const float*)d_in[13];
    const float* wp_W3 = (const float*)d_in[14];
    const float* wp_b3 = (const float*)d_in[15];
    const float* wp_W4 = (const float*)d_in[16];
    const float* wp_b4 = (const float*)d_in[17];
    const float* wtemp = (const float*)d_in[18];

    float* ws = (float*)d_ws;
    f16* ln16     = (f16*)(ws + OFF_LN16);
    f16* lnlo     = (f16*)(ws + OFF_LNLO);
    f16* fq16     = (f16*)(ws + OFF_FQ16);
    f16* fk16     = (f16*)(ws + OFF_FK16);
    f16* fvhT     = (f16*)(ws + OFF_FVHT);
    f16* fvlT     = (f16*)(ws + OFF_FVLT);
    f16* WinTh    = (f16*)(ws + OFF_WINTH);
    f16* WinTl    = (f16*)(ws + OFF_WINTL);
    f16* WoutTh   = (f16*)(ws + OFF_WOUTTH);
    f16* WoutTl   = (f16*)(ws + OFF_WOUTTL);
    f16* avh      = (f16*)(ws + OFF_AVH);
    f16* avl      = (f16*)(ws + OFF_AVL);
    f16* dots     = (f16*)(ws + OFF_DOTS);
    float* rq1    = ws + OFF_RQ1;
    float* rq2    = ws + OFF_RQ2;
    float* muq    = ws + OFF_MUQ;
    float* rk1    = ws + OFF_RK1;
    float* rk2    = ws + OFF_RK2;
    float* sk     = ws + OFF_SK;
    float* vcrow  = ws + OFF_VC;
    float* rmax   = ws + OFF_RMAX;
    float* nuacck = ws + OFF_NUACC;
    float* pb     = ws + OFF_PB;
    float* pb2    = ws + OFF_PB2;
    float* feat   = ws + OFF_FEAT;
    float* wv     = ws + OFF_WV;
    float* scal   = ws + OFF_SCAL;

    k_zero<<<8, 256, 0, stream>>>(feat, nuacck);
    k_wprep<<<dim3(8, 8, 2), 256, 0, stream>>>(W_in, W_out, WinTh, WinTl, WoutTh, WoutTl);
    k_ln16<<<3072, 256, 0, stream>>>(q, k, v, ln_w, ln_b, ln16, lnlo);
    k_proj_all<<<dim3(4, 32, 3), 256, 0, stream>>>(ln16, lnlo, WinTh, WinTl,
            fq16, fk16, fvhT, fvlT, rq1, rq2, muq, rk1, rk2, sk, feat, nuacck);
    k_mlp<<<8, 256, 0, stream>>>(feat, wp_W1, wp_b1, wp_lw, wp_lb,
                                 wp_W2, wp_b2, wp_W3, wp_b3, wp_W4, wp_b4,
                                 wtemp, wv);
    k_passA<<<dim3(16, 2, 32), 256, 0, stream>>>(fq16, fk16, rq1, rq2, muq, rk1, rk2,
                                                 sk, nuacck, vcrow, pb);
    k_fin1<<<1, 256, 0, stream>>>(pb, vcrow, scal);
    k_passB<<<dim3(16, 2, 32), 256, 0, stream>>>(fq16, fk16, rq1, muq, rk1, sk, nuacck,
                                                 vcrow, wv, scal, rmax, dots, pb2);
    k_fin2<<<1, 256, 0, stream>>>(pb2, scal);
    k_passC<<<dim3(16, 32), 512, 0, stream>>>(dots, rmax, scal, fvhT, fvlT, avh, avl);
    k_out_mfma<<<dim3(4, 64), 256, 0, stream>>>(avh, avl, WoutTh, WoutTl, b_out,
                                                (float*)d_out);
}

// Round 9
// 293.229 us; speedup vs baseline: 38.6580x; 1.0350x over previous
//
#include <hip/hip_runtime.h>
#include <math.h>

typedef _Float16 f16;
typedef _Float16 v8h __attribute__((ext_vector_type(8)));
typedef _Float16 v4h __attribute__((ext_vector_type(4)));
typedef float    v4f __attribute__((ext_vector_type(4)));

#define MFMA(a, b, c) __builtin_amdgcn_mfma_f32_16x16x32_f16((a), (b), (c), 0, 0, 0)

// ---------------- workspace layout (float offsets) ----------------
#define OFF_LN16    0u
#define OFF_LNLO    3145728u
#define OFF_FQ16    4194304u
#define OFF_FK16    5242880u
#define OFF_FVHT    6291456u
#define OFF_FVLT    7340032u
#define OFF_WINTH   8388608u
#define OFF_WINTL   8519680u
#define OFF_WOUTTH  8650752u
#define OFF_WOUTTL  8781824u
#define OFF_AVH     8912896u
#define OFF_AVL     9961472u
#define OFF_RQ1     11010048u
#define OFF_RQ2     11042816u
#define OFF_MUQ     11075584u
#define OFF_RK1     11108352u
#define OFF_RK2     11141120u
#define OFF_SK      11173888u
#define OFF_VC      11206656u   // 65536 (2 halves)
#define OFF_ROWCOS  11272192u   // 65536 (2 halves)
#define OFF_ROWCOV  11337728u   // 65536 (2 halves)
#define OFF_NUACC   11403264u   // 2048
#define OFF_PB      11405312u   // 1024*6
#define OFF_HS      11411456u   // 64 (8 heads x 5)
#define OFF_RP      11411520u   // 192 (64 x 3)
#define OFF_FEAT    11411712u   // 1024
#define OFF_WV      11412736u   // 24
#define OFF_SCAL    11412760u   // 8

__device__ __forceinline__ float clampf(float x, float lo, float hi) {
    return fminf(fmaxf(x, lo), hi);
}

__global__ void k_zero(float* feat, float* nuacck) {
    int i = blockIdx.x * 256 + threadIdx.x;
    if (i < 1024) feat[i] = 0.0f;
    if (i < 2048) nuacck[i] = 0.0f;
}

// transpose + hi/lo split of a 512x512 weight: W[k][c] -> WT{h,l}[c][k]
__global__ __launch_bounds__(256) void k_wprep(const float* __restrict__ Win,
        const float* __restrict__ Wout, f16* __restrict__ WinTh, f16* __restrict__ WinTl,
        f16* __restrict__ WoutTh, f16* __restrict__ WoutTl) {
    __shared__ float lds[64][68];
    const float* W = blockIdx.z ? Wout : Win;
    f16* Th = blockIdx.z ? WoutTh : WinTh;
    f16* Tl = blockIdx.z ? WoutTl : WinTl;
    int k0 = blockIdx.y * 64, c0 = blockIdx.x * 64;
    int t = threadIdx.x;
    #pragma unroll
    for (int p = 0; p < 4; ++p) {
        int flat = p * 1024 + t * 4;
        int r = flat >> 6, c = flat & 63;
        *(float4*)&lds[r][c] = *(const float4*)&W[(size_t)(k0 + r) * 512 + c0 + c];
    }
    __syncthreads();
    int c = t >> 2, kk = (t & 3) * 16;
    #pragma unroll
    for (int half = 0; half < 2; ++half) {
        v8h h8, l8;
        #pragma unroll
        for (int ii = 0; ii < 8; ++ii) {
            float v = lds[kk + half * 8 + ii][c];
            f16 h = (f16)v;
            h8[ii] = h;
            l8[ii] = (f16)(v - (float)h);
        }
        *(v8h*)&Th[(size_t)(c0 + c) * 512 + k0 + kk + half * 8] = h8;
        *(v8h*)&Tl[(size_t)(c0 + c) * 512 + k0 + kk + half * 8] = l8;
    }
}

// LayerNorm all 12288 tokens -> ln16 f16; v tokens also get lo residual
__global__ __launch_bounds__(256) void k_ln16(const float* __restrict__ q,
        const float* __restrict__ kk, const float* __restrict__ v,
        const float* __restrict__ lnw, const float* __restrict__ lnb,
        f16* __restrict__ ln16, f16* __restrict__ lnlo) {
    int t = threadIdx.x, wid = t >> 6, lane = t & 63;
    int token = blockIdx.x * 4 + wid;
    int inp = token >> 12, lt = token & 4095;
    const float* xp = (inp == 0) ? q : ((inp == 1) ? kk : v);
    const float4* xr = (const float4*)(xp + (size_t)lt * 512);
    float4 a = xr[lane], b = xr[lane + 64];
    float s = a.x + a.y + a.z + a.w + b.x + b.y + b.z + b.w;
    float s2 = a.x*a.x + a.y*a.y + a.z*a.z + a.w*a.w
             + b.x*b.x + b.y*b.y + b.z*b.z + b.w*b.w;
    for (int o = 32; o > 0; o >>= 1) { s += __shfl_down(s, o); s2 += __shfl_down(s2, o); }
    float m_ = __shfl(s, 0) * (1.0f / 512.0f);
    float var = __shfl(s2, 0) * (1.0f / 512.0f) - m_ * m_;
    var = fmaxf(var, 0.0f);
    float rs = rsqrtf(var + 1e-5f);
    const float4* w4 = (const float4*)lnw;
    const float4* b4 = (const float4*)lnb;
    float4 wa = w4[lane], wb = w4[lane + 64], ba = b4[lane], bb = b4[lane + 64];
    float ga[4] = { (a.x - m_) * rs * wa.x + ba.x, (a.y - m_) * rs * wa.y + ba.y,
                    (a.z - m_) * rs * wa.z + ba.z, (a.w - m_) * rs * wa.w + ba.w };
    float gb[4] = { (b.x - m_) * rs * wb.x + bb.x, (b.y - m_) * rs * wb.y + bb.y,
                    (b.z - m_) * rs * wb.z + bb.z, (b.w - m_) * rs * wb.w + bb.w };
    f16* orow = ln16 + (size_t)token * 512;
    v4h ha, hb;
    #pragma unroll
    for (int i = 0; i < 4; ++i) { ha[i] = (f16)ga[i]; hb[i] = (f16)gb[i]; }
    *(v4h*)&orow[lane * 4] = ha;
    *(v4h*)&orow[lane * 4 + 256] = hb;
    if (inp == 2) {
        f16* lrow = lnlo + (size_t)lt * 512;
        v4h la, lb;
        #pragma unroll
        for (int i = 0; i < 4; ++i) {
            la[i] = (f16)(ga[i] - (float)ha[i]);
            lb[i] = (f16)(gb[i] - (float)hb[i]);
        }
        *(v4h*)&lrow[lane * 4] = la;
        *(v4h*)&lrow[lane * 4 + 256] = lb;
    }
}

// LN16 @ Win (MFMA). MODE 0: q (fq16 + recip stats). MODE 1: k. MODE 2: v.
template<int MODE>
__device__ __forceinline__ void proj_body(const f16* __restrict__ A16,
        const f16* __restrict__ Alo,
        const f16* __restrict__ BTh, const f16* __restrict__ BTl,
        f16* __restrict__ fout16, f16* __restrict__ fhT, f16* __restrict__ flT,
        float* __restrict__ oA, float* __restrict__ oB, float* __restrict__ oC,
        float* __restrict__ feat, float* __restrict__ nuacck) {
    int t = threadIdx.x, l = t & 63, w = t >> 6;
    int wr = w >> 1, wc = w & 1;
    int col0 = blockIdx.x * 128 + wc * 64;
    int tok0 = blockIdx.y * 128 + wr * 64;
    int lr = l & 15, kg = (l >> 4) * 8;
    int rg4 = (l >> 4) * 4;
    v4f acc[4][4] = {};
    for (int ks = 0; ks < 512; ks += 32) {
        v8h a[4], b[4];
        #pragma unroll
        for (int i = 0; i < 4; ++i)
            a[i] = *(const v8h*)&A16[(size_t)(tok0 + i * 16 + lr) * 512 + ks + kg];
        #pragma unroll
        for (int j = 0; j < 4; ++j)
            b[j] = *(const v8h*)&BTh[(size_t)(col0 + j * 16 + lr) * 512 + ks + kg];
        if constexpr (MODE == 2) {
            v8h al[4], bl[4];
            #pragma unroll
            for (int i = 0; i < 4; ++i)
                al[i] = *(const v8h*)&Alo[(size_t)(tok0 + i * 16 + lr) * 512 + ks + kg];
            #pragma unroll
            for (int j = 0; j < 4; ++j)
                bl[j] = *(const v8h*)&BTl[(size_t)(col0 + j * 16 + lr) * 512 + ks + kg];
            #pragma unroll
            for (int i = 0; i < 4; ++i)
                #pragma unroll
                for (int j = 0; j < 4; ++j) {
                    acc[i][j] = MFMA(a[i], b[j], acc[i][j]);
                    acc[i][j] = MFMA(a[i], bl[j], acc[i][j]);
                    acc[i][j] = MFMA(al[i], b[j], acc[i][j]);
                }
        } else {
            #pragma unroll
            for (int i = 0; i < 4; ++i)
                #pragma unroll
                for (int j = 0; j < 4; ++j)
                    acc[i][j] = MFMA(a[i], b[j], acc[i][j]);
        }
    }
    int h = col0 >> 6;
    #pragma unroll
    for (int i = 0; i < 4; ++i)
        #pragma unroll
        for (int j = 0; j < 4; ++j)
            #pragma unroll
            for (int r = 0; r < 4; ++r) {
                int token = tok0 + i * 16 + rg4 + r;
                int d = j * 16 + lr;
                int qi = token >> 10, n = token & 1023;
                float val = acc[i][j][r];
                if constexpr (MODE != 2) {
                    fout16[((size_t)((h << 2) + qi) * 1024 + n) * 64 + d] = (f16)val;
                } else {
                    f16 hi = (f16)val;
                    fhT[((size_t)((h << 2) + qi) * 64 + d) * 1024 + n] = hi;
                    flT[((size_t)((h << 2) + qi) * 64 + d) * 1024 + n] = (f16)(val - (float)hi);
                }
            }
    if constexpr (MODE != 2) {
        #pragma unroll
        for (int i = 0; i < 4; ++i)
            #pragma unroll
            for (int r = 0; r < 4; ++r) {
                float s = 0.f, s2 = 0.f;
                #pragma unroll
                for (int j = 0; j < 4; ++j) { float v = acc[i][j][r]; s += v; s2 += v * v; }
                #pragma unroll
                for (int mk = 1; mk <= 8; mk <<= 1) {
                    s += __shfl_xor(s, mk); s2 += __shfl_xor(s2, mk);
                }
                if (lr == 0) {
                    int token = tok0 + i * 16 + rg4 + r;
                    int qi = token >> 10, n = token & 1023;
                    int row = ((h << 2) + qi) * 1024 + n;
                    float nv = sqrtf(s2);
                    oA[row] = 1.0f / (nv + 1e-6f);
                    oB[row] = 1.0f / fmaxf(nv, 1e-4f);
                    oC[row] = (MODE == 0) ? s * (1.0f / 64.0f) : s;
                }
            }
        float cs[4];
        #pragma unroll
        for (int j = 0; j < 4; ++j) {
            float c = 0.f;
            #pragma unroll
            for (int i = 0; i < 4; ++i)
                #pragma unroll
                for (int r = 0; r < 4; ++r) c += acc[i][j][r];
            c += __shfl_xor(c, 16); c += __shfl_xor(c, 32);
            cs[j] = c;
        }
        if (l < 16) {
            #pragma unroll
            for (int j = 0; j < 4; ++j)
                atomicAdd(&feat[h * 128 + (MODE == 1 ? 64 : 0) + j * 16 + l],
                          cs[j] * (1.0f / 4096.0f));
            if constexpr (MODE == 1) {
                int qi = tok0 >> 10;
                #pragma unroll
                for (int j = 0; j < 4; ++j)
                    atomicAdd(&nuacck[((h << 2) + qi) * 64 + j * 16 + l], cs[j]);
            }
        }
    }
}

__global__ __launch_bounds__(256) void k_proj_all(const f16* __restrict__ ln16,
        const f16* __restrict__ lnlo,
        const f16* __restrict__ BTh, const f16* __restrict__ BTl,
        f16* __restrict__ fq16, f16* __restrict__ fk16,
        f16* __restrict__ fvhT, f16* __restrict__ fvlT,
        float* __restrict__ rq1, float* __restrict__ rq2, float* __restrict__ muq,
        float* __restrict__ rk1, float* __restrict__ rk2, float* __restrict__ sk,
        float* __restrict__ feat, float* __restrict__ nuacck) {
    int mode = blockIdx.z;
    if (mode == 0)
        proj_body<0>(ln16, nullptr, BTh, BTl, fq16, nullptr, nullptr,
                     rq1, rq2, muq, feat, nullptr);
    else if (mode == 1)
        proj_body<1>(ln16 + 2097152u, nullptr, BTh, BTl, fk16, nullptr, nullptr,
                     rk1, rk2, sk, feat, nuacck);
    else
        proj_body<2>(ln16 + 4194304u, lnlo, BTh, BTl, nullptr, fvhT, fvlT,
                     nullptr, nullptr, nullptr, nullptr, nullptr);
}

// tiny MLP weight predictor, one block per head -> wv[h][3]
__global__ __launch_bounds__(256) void k_mlp(const float* __restrict__ feat,
        const float* __restrict__ W1, const float* __restrict__ b1,
        const float* __restrict__ lw, const float* __restrict__ lb,
        const float* __restrict__ W2, const float* __restrict__ b2,
        const float* __restrict__ W3, const float* __restrict__ b3,
        const float* __restrict__ W4, const float* __restrict__ b4,
        const float* __restrict__ wtemp, float* wv) {
    __shared__ float h1[256], h2[192], h3[64], red[8];
    int t = threadIdx.x;
    int h = blockIdx.x;
    float p = 0.0f;
    for (int i = 0; i < 128; ++i) p += feat[h * 128 + i] * W1[i * 256 + t];
    p += b1[t];
    float s = p, s2 = p * p;
    for (int o = 32; o > 0; o >>= 1) { s += __shfl_down(s, o); s2 += __shfl_down(s2, o); }
    if ((t & 63) == 0) { red[t >> 6] = s; red[4 + (t >> 6)] = s2; }
    __syncthreads();
    float S = red[0] + red[1] + red[2] + red[3];
    float S2 = red[4] + red[5] + red[6] + red[7];
    float mu = S / 256.0f;
    float var = S2 / 256.0f - mu * mu; if (var < 0.0f) var = 0.0f;
    float xh = (p - mu) * rsqrtf(var + 1e-5f) * lw[t] + lb[t];
    h1[t] = fmaxf(xh, 0.0f);
    __syncthreads();
    if (t < 192) {
        float a = 0.0f;
        for (int i = 0; i < 256; ++i) a += h1[i] * W2[i * 192 + t];
        h2[t] = fmaxf(a + b2[t], 0.0f);
    }
    __syncthreads();
    if (t < 64) {
        float a = 0.0f;
        for (int i = 0; i < 192; ++i) a += h2[i] * W3[i * 64 + t];
        h3[t] = fmaxf(a + b3[t], 0.0f);
    }
    __syncthreads();
    if (t == 0) {
        float lg[3];
        for (int j = 0; j < 3; ++j) {
            float a = 0.0f;
            for (int i = 0; i < 64; ++i) a += h3[i] * W4[i * 3 + j];
            lg[j] = a + b4[j];
        }
        float mx = fmaxf(lg[0], fmaxf(lg[1], lg[2]));
        float e0 = expf(lg[0] - mx), e1 = expf(lg[1] - mx), e2 = expf(lg[2] - mx);
        float se = e0 + e1 + e2;
        float pr0 = e0 / se, pr1 = e1 / se, pr2 = e2 / se;
        float wt = wtemp[0]; wt = fminf(fmaxf(wt, 0.01f), 1.0f);
        float q0 = pr0 / wt, q1 = pr1 / wt, q2 = pr2 / wt;
        float m2 = fmaxf(q0, fmaxf(q1, q2));
        float f0 = expf(q0 - m2), f1 = expf(q1 - m2), f2 = expf(q2 - m2);
        float sf = f0 + f1 + f2; f0 /= sf; f1 /= sf; f2 /= sf;
        f0 = fminf(fmaxf(f0, 0.01f), 0.95f);
        f1 = fminf(fmaxf(f1, 0.01f), 0.95f);
        f2 = fminf(fmaxf(f2, 0.01f), 0.95f);
        float sw = f0 + f1 + f2;
        wv[h * 3 + 0] = f0 / sw; wv[h * 3 + 1] = f1 / sw; wv[h * 3 + 2] = f2 / sw;
    }
}

// ---- shared per-pass preamble for passA: grid (16, 2, 32) ----
#define PASS_PREAMBLE_AB                                                       \
    int hq = blockIdx.z;                                                       \
    int half = blockIdx.y;                                                     \
    int m0base = half * 512;                                                   \
    int t = threadIdx.x, l = t & 63, w = t >> 6;                               \
    int lr = l & 15, kg = (l >> 4) * 8, rg4 = (l >> 4) * 4;                    \
    int nb = blockIdx.x * 64 + w * 16;                                         \
    const f16* Q = fq16 + (size_t)hq * 65536;                                  \
    const f16* K = fk16 + (size_t)hq * 65536;                                  \
    v8h aq0 = *(const v8h*)&Q[(size_t)(nb + lr) * 64 + kg];                    \
    v8h aq1 = *(const v8h*)&Q[(size_t)(nb + lr) * 64 + 32 + kg];               \
    const float inv1024 = 1.0f / 1024.0f;                                      \
    float uvp = nuacck[hq * 64 + l] * inv1024;                                 \
    _Pragma("unroll")                                                          \
    for (int o = 32; o > 0; o >>= 1) uvp += __shfl_xor(uvp, o);                \
    float uv = uvp;                                                            \
    float tp = 0.f;                                                            \
    _Pragma("unroll")                                                          \
    for (int e = 0; e < 8; ++e)                                                \
        tp += (float)aq0[e] * nuacck[hq * 64 + kg + e]                         \
            + (float)aq1[e] * nuacck[hq * 64 + 32 + kg + e];                   \
    tp *= inv1024;                                                             \
    tp += __shfl_xor(tp, 16);                                                  \
    tp += __shfl_xor(tp, 32);                                                  \
    float muv[4], tv[4];                                                       \
    _Pragma("unroll")                                                          \
    for (int r = 0; r < 4; ++r) {                                              \
        muv[r] = muq[hq * 1024 + nb + rg4 + r];                                \
        tv[r] = __shfl(tp, rg4 + r);                                           \
    }                                                                          \
    const float Acs = (0.001f / 1024.0f) / 8.0001f;                            \
    float Pr[4], Gr[4];                                                        \
    _Pragma("unroll")                                                          \
    for (int r = 0; r < 4; ++r) {                                              \
        Gr[r] = Acs * muv[r];                                                  \
        Pr[r] = Acs * fmaf(muv[r], uv, -tv[r]);                                \
    }

#define LOAD_KTILE(m0a)                                                        \
    v8h b0[4], b1[4];                                                          \
    _Pragma("unroll")                                                          \
    for (int j = 0; j < 4; ++j) {                                              \
        b0[j] = *(const v8h*)&K[(size_t)((m0a) + j * 16 + lr) * 64 + kg];      \
        b1[j] = *(const v8h*)&K[(size_t)((m0a) + j * 16 + lr) * 64 + 32 + kg]; \
    }

// pass A: cos/cov global+cross sums, per-row cos/cov sums, margin means
__global__ __launch_bounds__(256) void k_passA(const f16* __restrict__ fq16,
        const f16* __restrict__ fk16, const float* __restrict__ rq1,
        const float* __restrict__ rq2, const float* __restrict__ muq,
        const float* __restrict__ rk1, const float* __restrict__ rk2,
        const float* __restrict__ sk, const float* __restrict__ nuacck,
        float* __restrict__ vcrow, float* __restrict__ rowcos,
        float* __restrict__ rowcov, float* __restrict__ pb) {
    __shared__ float rk1s[512], rk2s[512], sks[512];
    PASS_PREAMBLE_AB
    {
        int i2 = t * 2;
        *(float2*)&rk1s[i2] = *(const float2*)&rk1[hq * 1024 + m0base + i2];
        *(float2*)&rk2s[i2] = *(const float2*)&rk2[hq * 1024 + m0base + i2];
        *(float2*)&sks[i2]  = *(const float2*)&sk[hq * 1024 + m0base + i2];
    }
    __syncthreads();
    float rq1v[4], rq2v[4];
    #pragma unroll
    for (int r = 0; r < 4; ++r) {
        rq1v[r] = rq1[hq * 1024 + nb + rg4 + r];
        rq2v[r] = rq2[hq * 1024 + nb + rg4 + r];
    }
    float scos = 0, s2cos = 0, scov = 0, s2cov = 0, sccov = 0;
    float mp[4] = {}, rcs[4] = {}, rcv[4] = {};
    #pragma unroll 2
    for (int m0 = 0; m0 < 512; m0 += 64) {
        LOAD_KTILE(m0base + m0)
        float rk1v[4], rk2v[4], skv[4];
        #pragma unroll
        for (int j = 0; j < 4; ++j) {
            int cg = m0 + j * 16 + lr;
            rk1v[j] = rk1s[cg]; rk2v[j] = rk2s[cg]; skv[j] = sks[cg];
        }
        v4f acc[4] = {};
        #pragma unroll
        for (int j = 0; j < 4; ++j) {
            acc[j] = MFMA(aq0, b0[j], acc[j]);
            acc[j] = MFMA(aq1, b1[j], acc[j]);
        }
        #pragma unroll
        for (int j = 0; j < 4; ++j)
            #pragma unroll
            for (int r = 0; r < 4; ++r) {
                float rv = acc[j][r];
                float cosv = clampf(rv * rq1v[r] * rk1v[j], -0.95f, 0.95f);
                float x2 = rv * rq2v[r] * rk2v[j];
                float marg = fmaxf(0.01f - fmaxf(x2, -0.95f), 0.0f);
                float cov = clampf(fmaf(-Gr[r], skv[j], fmaf(Acs, rv, Pr[r])),
                                   -50.0f, 50.0f);
                scos += cosv; s2cos = fmaf(cosv, cosv, s2cos);
                scov += cov;  s2cov = fmaf(cov, cov, s2cov);
                sccov = fmaf(cosv, cov, sccov);
                mp[r] += marg; rcs[r] += cosv; rcv[r] += cov;
            }
    }
    #pragma unroll
    for (int r = 0; r < 4; ++r) {
        float m_ = mp[r], c_ = rcs[r], v_ = rcv[r];
        #pragma unroll
        for (int mk = 1; mk <= 8; mk <<= 1) {
            m_ += __shfl_xor(m_, mk);
            c_ += __shfl_xor(c_, mk);
            v_ += __shfl_xor(v_, mk);
        }
        if (lr == 0) {
            int row = hq * 1024 + nb + rg4 + r;
            vcrow[half * 32768 + row] = m_ * inv1024;
            rowcos[half * 32768 + row] = c_;
            rowcov[half * 32768 + row] = v_;
        }
    }
    for (int o = 32; o > 0; o >>= 1) {
        scos += __shfl_down(scos, o); s2cos += __shfl_down(s2cos, o);
        scov += __shfl_down(scov, o); s2cov += __shfl_down(s2cov, o);
        sccov += __shfl_down(sccov, o);
    }
    __shared__ float bs[4][5];
    if (l == 0) { bs[w][0] = scos; bs[w][1] = s2cos; bs[w][2] = scov;
                  bs[w][3] = s2cov; bs[w][4] = sccov; }
    __syncthreads();
    if (t == 0) {
        int bid = (hq * 2 + half) * 16 + blockIdx.x;
        #pragma unroll
        for (int s = 0; s < 5; ++s)
            pb[bid * 6 + s] = bs[0][s] + bs[1][s] + bs[2][s] + bs[3][s];
    }
}

// fin1: per-head sums -> hs, global scal[0..2]
__global__ __launch_bounds__(256) void k_fin1(const float* __restrict__ pb,
        const float* __restrict__ vcrow, float* __restrict__ hs,
        float* __restrict__ scal) {
    __shared__ float hsl[40];
    int t = threadIdx.x;
    int hd = t >> 5, idx = t & 31;
    double a0 = 0, a1 = 0, a2 = 0, a3 = 0, a4 = 0;
    for (int i = idx; i < 128; i += 32) {
        const float* p = &pb[(hd * 128 + i) * 6];
        a0 += p[0]; a1 += p[1]; a2 += p[2]; a3 += p[3]; a4 += p[4];
    }
    for (int m = 1; m <= 16; m <<= 1) {
        a0 += __shfl_xor(a0, m); a1 += __shfl_xor(a1, m); a2 += __shfl_xor(a2, m);
        a3 += __shfl_xor(a3, m); a4 += __shfl_xor(a4, m);
    }
    if (idx == 0) {
        hsl[hd * 5 + 0] = (float)a0; hsl[hd * 5 + 1] = (float)a1;
        hsl[hd * 5 + 2] = (float)a2; hsl[hd * 5 + 3] = (float)a3;
        hsl[hd * 5 + 4] = (float)a4;
        hs[hd * 5 + 0] = (float)a0; hs[hd * 5 + 1] = (float)a1;
        hs[hd * 5 + 2] = (float)a2; hs[hd * 5 + 3] = (float)a3;
        hs[hd * 5 + 4] = (float)a4;
    }
    double s4 = 0, s5 = 0;
    for (int i = t; i < 32768; i += 256) {
        double rm = (double)(vcrow[i] + vcrow[32768 + i]);
        s4 += rm; s5 += rm * rm;
    }
    for (int o = 32; o > 0; o >>= 1) { s4 += __shfl_down(s4, o); s5 += __shfl_down(s5, o); }
    __shared__ double red[2][4];
    int wid = t >> 6, lane = t & 63;
    if (lane == 0) { red[0][wid] = s4; red[1][wid] = s5; }
    __syncthreads();
    if (t == 0) {
        double S4 = red[0][0] + red[0][1] + red[0][2] + red[0][3];
        double S5 = red[1][0] + red[1][1] + red[1][2] + red[1][3];
        double S0 = 0, S1 = 0, S2 = 0, S3 = 0;
        for (int h2 = 0; h2 < 8; ++h2) {
            S0 += hsl[h2 * 5 + 0]; S1 += hsl[h2 * 5 + 1];
            S2 += hsl[h2 * 5 + 2]; S3 += hsl[h2 * 5 + 3];
        }
        const double cnt = 33554432.0;
        scal[0] = (float)sqrt(fmax(0.0, (S1 - S0 * S0 / cnt) / (cnt - 1.0)));
        scal[1] = (float)sqrt(fmax(0.0, (S3 - S2 * S2 / cnt) / (cnt - 1.0)));
        double V4 = S4 * 1024.0, V5 = S5 * 1024.0;
        scal[2] = (float)sqrt(fmax(0.0, (V5 - V4 * V4 / cnt) / (cnt - 1.0)));
    }
}

// finrow: per-row addc cross terms -> rp[64][3]
__global__ __launch_bounds__(256) void k_finrow(const float* __restrict__ vcrow,
        const float* __restrict__ rowcos, const float* __restrict__ rowcov,
        const float* __restrict__ wv, const float* __restrict__ scal,
        float* __restrict__ rp) {
    int t = threadIdx.x;
    float s1 = scal[0] + 1e-4f, s2v = scal[1] + 1e-4f, s3 = scal[2] + 1e-4f;
    float p1 = 0, p2 = 0, p3 = 0;
    #pragma unroll
    for (int i = 0; i < 2; ++i) {
        int row = blockIdx.x * 512 + i * 256 + t;
        int h = row >> 12;
        float fc1 = wv[h * 3] / s1;
        float fc2 = wv[h * 3 + 1] * 0.3f / s2v;
        float c3 = wv[h * 3 + 2] * 0.3f / s3;
        float a = (vcrow[row] + vcrow[32768 + row]) * c3;
        float b = fc1 * (rowcos[row] + rowcos[32768 + row])
                + fc2 * (rowcov[row] + rowcov[32768 + row]);
        p1 += a; p2 = fmaf(a, a, p2); p3 = fmaf(a, b, p3);
    }
    for (int o = 32; o > 0; o >>= 1) {
        p1 += __shfl_down(p1, o); p2 += __shfl_down(p2, o); p3 += __shfl_down(p3, o);
    }
    __shared__ float red[3][4];
    int wid = t >> 6, lane = t & 63;
    if (lane == 0) { red[0][wid] = p1; red[1][wid] = p2; red[2][wid] = p3; }
    __syncthreads();
    if (t == 0) {
        rp[blockIdx.x * 3 + 0] = red[0][0] + red[0][1] + red[0][2] + red[0][3];
        rp[blockIdx.x * 3 + 1] = red[1][0] + red[1][1] + red[1][2] + red[1][3];
        rp[blockIdx.x * 3 + 2] = red[2][0] + red[2][1] + red[2][2] + red[2][3];
    }
}

// fin2: ds via decomposition -> temp
__global__ __launch_bounds__(64) void k_fin2(const float* __restrict__ rp,
        const float* __restrict__ hs, const float* __restrict__ wv,
        float* __restrict__ scal) {
    int t = threadIdx.x;
    double p1 = rp[t * 3 + 0], p2 = rp[t * 3 + 1], p3 = rp[t * 3 + 2];
    for (int o = 32; o > 0; o >>= 1) {
        p1 += __shfl_down(p1, o); p2 += __shfl_down(p2, o); p3 += __shfl_down(p3, o);
    }
    if (t == 0) {
        double s1 = (double)scal[0] + 1e-4, s2v = (double)scal[1] + 1e-4;
        double sdd = 1024.0 * p1;
        double sdd2 = 2.0 * p3 + 1024.0 * p2;
        for (int h = 0; h < 8; ++h) {
            double fc1 = (double)wv[h * 3] / s1;
            double fc2 = (double)wv[h * 3 + 1] * 0.3 / s2v;
            sdd += fc1 * hs[h * 5 + 0] + fc2 * hs[h * 5 + 2];
            sdd2 += fc1 * fc1 * hs[h * 5 + 1] + fc2 * fc2 * hs[h * 5 + 3]
                  + 2.0 * fc1 * fc2 * hs[h * 5 + 4];
        }
        const double cnt = 33554432.0;
        double ds = sqrt(fmax(0.0, (sdd2 - sdd * sdd / cnt) / (cnt - 1.0)));
        float temp = (ds < 1e-5) ? 0.01f : ((ds < 1e-3) ? 0.05f : (0.2f + (float)ds * 2.0f));
        temp = fminf(fmaxf(temp, 0.01f), 8.0f);
        scal[3] = temp;
    }
}

// pass C: recompute QK^T -> dots -> ONLINE softmax -> PV (hi/lo V) -> av.
// 512 threads = 4 row-groups x 2 K-halves; flash combine in LDS.
__global__ __launch_bounds__(512) void k_passC(const f16* __restrict__ fq16,
        const f16* __restrict__ fk16, const float* __restrict__ rq1,
        const float* __restrict__ muq, const float* __restrict__ rk1,
        const float* __restrict__ sk, const float* __restrict__ nuacck,
        const float* __restrict__ vcrow, const float* __restrict__ wv,
        const float* __restrict__ scal,
        const f16* __restrict__ fvhT, const f16* __restrict__ fvlT,
        f16* __restrict__ avh, f16* __restrict__ avl) {
    __shared__ f16 P[8][16][72];
    __shared__ float rk1s[1024], sks[1024];
    __shared__ float cbacc[4][16][64];
    __shared__ float cbrs[4][4][64];
    __shared__ float cbm[4][16];
    int hq = blockIdx.y;
    int t = threadIdx.x, l = t & 63, w = t >> 6;
    int rg = w & 3, kh = w >> 2;
    int lr = l & 15, kg = (l >> 4) * 8, rg4 = (l >> 4) * 4;
    int nb = blockIdx.x * 64 + rg * 16;
    int m0base = kh * 512;
    const f16* Q = fq16 + (size_t)hq * 65536;
    const f16* K = fk16 + (size_t)hq * 65536;
    {
        int i2 = t * 2;
        *(float2*)&rk1s[i2] = *(const float2*)&rk1[hq * 1024 + i2];
        *(float2*)&sks[i2]  = *(const float2*)&sk[hq * 1024 + i2];
    }
    __syncthreads();
    v8h aq0 = *(const v8h*)&Q[(size_t)(nb + lr) * 64 + kg];
    v8h aq1 = *(const v8h*)&Q[(size_t)(nb + lr) * 64 + 32 + kg];
    const float inv1024 = 1.0f / 1024.0f;
    float uvp = nuacck[hq * 64 + l] * inv1024;
    #pragma unroll
    for (int o = 32; o > 0; o >>= 1) uvp += __shfl_xor(uvp, o);
    float uv = uvp;
    float tpv = 0.f;
    #pragma unroll
    for (int e = 0; e < 8; ++e)
        tpv += (float)aq0[e] * nuacck[hq * 64 + kg + e]
             + (float)aq1[e] * nuacck[hq * 64 + 32 + kg + e];
    tpv *= inv1024;
    tpv += __shfl_xor(tpv, 16);
    tpv += __shfl_xor(tpv, 32);
    float muv[4], tv[4];
    #pragma unroll
    for (int r = 0; r < 4; ++r) {
        muv[r] = muq[hq * 1024 + nb + rg4 + r];
        tv[r] = __shfl(tpv, rg4 + r);
    }
    const float Acs = (0.001f / 1024.0f) / 8.0001f;
    float Pcr[4], Gcr[4];
    #pragma unroll
    for (int r = 0; r < 4; ++r) {
        Gcr[r] = Acs * muv[r];
        Pcr[r] = Acs * fmaf(muv[r], uv, -tv[r]);
    }
    int h = hq >> 2;
    float s1 = scal[0] + 1e-4f, s2v = scal[1] + 1e-4f, s3 = scal[2] + 1e-4f;
    float fc1 = wv[h * 3] / s1;
    float fc2 = wv[h * 3 + 1] * 0.3f / s2v;
    float c3 = wv[h * 3 + 2] * 0.3f / s3;
    float invt = 1.0f / scal[3];
    float rq1v[4], addc[4];
    #pragma unroll
    for (int r = 0; r < 4; ++r) {
        int row = hq * 1024 + nb + rg4 + r;
        rq1v[r] = rq1[row];
        addc[r] = (vcrow[row] + vcrow[32768 + row]) * c3;
    }
    v4f accpv[4] = {};
    float rsacc[4] = {};
    float mrun[4] = { -1e30f, -1e30f, -1e30f, -1e30f };
    for (int m0i = 0; m0i < 512; m0i += 64) {
        int mk = m0base + m0i;
        v8h b0[4], b1[4];
        #pragma unroll
        for (int j = 0; j < 4; ++j) {
            b0[j] = *(const v8h*)&K[(size_t)(mk + j * 16 + lr) * 64 + kg];
            b1[j] = *(const v8h*)&K[(size_t)(mk + j * 16 + lr) * 64 + 32 + kg];
        }
        float rk1v[4], skv[4];
        #pragma unroll
        for (int j = 0; j < 4; ++j) {
            int cg = mk + j * 16 + lr;
            rk1v[j] = rk1s[cg]; skv[j] = sks[cg];
        }
        v4f acc[4] = {};
        #pragma unroll
        for (int j = 0; j < 4; ++j) {
            acc[j] = MFMA(aq0, b0[j], acc[j]);
            acc[j] = MFMA(aq1, b1[j], acc[j]);
        }
        float dd[4][4];
        float tmax[4] = { -1e30f, -1e30f, -1e30f, -1e30f };
        #pragma unroll
        for (int j = 0; j < 4; ++j)
            #pragma unroll
            for (int r = 0; r < 4; ++r) {
                float rv = acc[j][r];
                float cosv = clampf(rv * rq1v[r] * rk1v[j], -0.95f, 0.95f);
                float cov = clampf(fmaf(-Gcr[r], skv[j], fmaf(Acs, rv, Pcr[r])),
                                   -50.0f, 50.0f);
                float d2 = fmaf(fc2, cov, fmaf(fc1, cosv, addc[r]));
                dd[j][r] = d2;
                tmax[r] = fmaxf(tmax[r], d2);
            }
        v4f fv;
        #pragma unroll
        for (int r = 0; r < 4; ++r) {
            float tm = tmax[r];
            tm = fmaxf(tm, __shfl_xor(tm, 1)); tm = fmaxf(tm, __shfl_xor(tm, 2));
            tm = fmaxf(tm, __shfl_xor(tm, 4)); tm = fmaxf(tm, __shfl_xor(tm, 8));
            float mnew = fmaxf(mrun[r], tm);
            float fr_ = __expf((mrun[r] - mnew) * invt);
            mrun[r] = mnew;
            rsacc[r] *= fr_;
            fv[r] = fr_;
        }
        #pragma unroll
        for (int j = 0; j < 4; ++j) accpv[j] *= fv;
        #pragma unroll
        for (int j = 0; j < 4; ++j)
            #pragma unroll
            for (int r = 0; r < 4; ++r) {
                float pe = __expf((dd[j][r] - mrun[r]) * invt);
                f16 p16 = (f16)pe;
                rsacc[r] += (float)p16;
                P[w][rg4 + r][j * 16 + lr] = p16;
            }
        v8h pa0 = *(const v8h*)&P[w][lr][kg];
        v8h pa1 = *(const v8h*)&P[w][lr][32 + kg];
        #pragma unroll
        for (int j = 0; j < 4; ++j) {
            size_t vb = ((size_t)hq * 64 + j * 16 + lr) * 1024 + mk;
            v8h vh0 = *(const v8h*)&fvhT[vb + kg];
            v8h vh1 = *(const v8h*)&fvhT[vb + 32 + kg];
            v8h vl0 = *(const v8h*)&fvlT[vb + kg];
            v8h vl1 = *(const v8h*)&fvlT[vb + 32 + kg];
            accpv[j] = MFMA(pa0, vh0, accpv[j]);
            accpv[j] = MFMA(pa1, vh1, accpv[j]);
            accpv[j] = MFMA(pa0, vl0, accpv[j]);
            accpv[j] = MFMA(pa1, vl1, accpv[j]);
        }
    }
    #pragma unroll
    for (int r = 0; r < 4; ++r) {
        float s = rsacc[r];
        s += __shfl_xor(s, 1); s += __shfl_xor(s, 2);
        s += __shfl_xor(s, 4); s += __shfl_xor(s, 8);
        rsacc[r] = s;
    }
    if (kh == 1) {
        #pragma unroll
        for (int j = 0; j < 4; ++j)
            #pragma unroll
            for (int r = 0; r < 4; ++r)
                cbacc[rg][j * 4 + r][l] = accpv[j][r];
        #pragma unroll
        for (int r = 0; r < 4; ++r) cbrs[rg][r][l] = rsacc[r];
        if (lr == 0) {
            #pragma unroll
            for (int r = 0; r < 4; ++r) cbm[rg][rg4 + r] = mrun[r];
        }
    }
    __syncthreads();
    if (kh == 0) {
        v4f f0v, f1v;
        float rinv[4];
        #pragma unroll
        for (int r = 0; r < 4; ++r) {
            float m1 = cbm[rg][rg4 + r];
            float mf = fmaxf(mrun[r], m1);
            float f0 = __expf((mrun[r] - mf) * invt);
            float f1 = __expf((m1 - mf) * invt);
            f0v[r] = f0; f1v[r] = f1;
            float rst = rsacc[r] * f0 + cbrs[rg][r][l] * f1;
            rinv[r] = 1.0f / rst;
        }
        #pragma unroll
        for (int j = 0; j < 4; ++j)
            #pragma unroll
            for (int r = 0; r < 4; ++r) {
                float val = (accpv[j][r] * f0v[r] + cbacc[rg][j * 4 + r][l] * f1v[r])
                            * rinv[r];
                size_t idx = ((size_t)(hq * 1024 + nb + rg4 + r)) * 64 + j * 16 + lr;
                f16 hi = (f16)val;
                avh[idx] = hi;
                avl[idx] = (f16)(val - (float)hi);
            }
    }
}

// out = av @ Wout + bout (MFMA, 3-way split)
__global__ __launch_bounds__(256) void k_out_mfma(const f16* __restrict__ avh,
        const f16* __restrict__ avl,
        const f16* __restrict__ WoutTh, const f16* __restrict__ WoutTl,
        const float* __restrict__ bout, float* __restrict__ out) {
    __shared__ float red[2][4][4][4][64];
    int t = threadIdx.x, l = t & 63, w = t >> 6;
    int wc = w & 1, kh = w >> 1;
    int col0 = blockIdx.x * 128 + wc * 64;
    int tok0 = blockIdx.y * 64;
    int qi = tok0 >> 10, nb = tok0 & 1023;
    int lr = l & 15, kg = (l >> 4) * 8;
    v4f acc[4][4] = {};
    for (int ks8 = 0; ks8 < 8; ++ks8) {
        int ks = kh * 256 + ks8 * 32;
        int f = ks + kg;
        int h = f >> 6, d = f & 63;
        size_t hb = (size_t)((h << 2) + qi) * 1024;
        v8h ah[4], al4[4], bh[4], bl4[4];
        #pragma unroll
        for (int i = 0; i < 4; ++i) {
            int n = nb + i * 16 + lr;
            ah[i]  = *(const v8h*)&avh[(hb + n) * 64 + d];
            al4[i] = *(const v8h*)&avl[(hb + n) * 64 + d];
        }
        #pragma unroll
        for (int j = 0; j < 4; ++j) {
            bh[j]  = *(const v8h*)&WoutTh[(size_t)(col0 + j * 16 + lr) * 512 + ks + kg];
            bl4[j] = *(const v8h*)&WoutTl[(size_t)(col0 + j * 16 + lr) * 512 + ks + kg];
        }
        #pragma unroll
        for (int i = 0; i < 4; ++i)
            #pragma unroll
            for (int j = 0; j < 4; ++j) {
                acc[i][j] = MFMA(ah[i], bh[j], acc[i][j]);
                acc[i][j] = MFMA(ah[i], bl4[j], acc[i][j]);
                acc[i][j] = MFMA(al4[i], bh[j], acc[i][j]);
            }
    }
    if (kh == 0) {
        #pragma unroll
        for (int i = 0; i < 4; ++i)
            #pragma unroll
            for (int j = 0; j < 4; ++j)
                #pragma unroll
                for (int r = 0; r < 4; ++r)
                    red[wc][i][j][r][l] = acc[i][j][r];
    }
    __syncthreads();
    if (kh == 1) {
        #pragma unroll
        for (int i = 0; i < 4; ++i)
            #pragma unroll
            for (int j = 0; j < 4; ++j) {
                int col = col0 + j * 16 + lr;
                float bo = bout[col];
                #pragma unroll
                for (int r = 0; r < 4; ++r) {
                    float val = acc[i][j][r] + red[wc][i][j][r][l] + bo;
                    int token = tok0 + i * 16 + (l >> 4) * 4 + r;
                    out[(size_t)token * 512 + col] = val;
                }
            }
    }
}

extern "C" void kernel_launch(void* const* d_in, const int* in_sizes, int n_in,
                              void* d_out, int out_size, void* d_ws, size_t ws_size,
                              hipStream_t stream) {
    const float* q     = (const float*)d_in[0];
    const float* k     = (const float*)d_in[1];
    const float* v     = (const float*)d_in[2];
    const float* ln_w  = (const float*)d_in[3];
    const float* ln_b  = (const float*)d_in[4];
    const float* W_in  = (const float*)d_in[5];
    const float* W_out = (const float*)d_in[6];
    const float* b_out = (const float*)d_in[7];
    const float* wp_W1 = (const float*)d_in[8];
    const float* wp_b1 = (const float*)d_in[9];
    const float* wp_lw = (const float*)d_in[10];
    const float* wp_lb = (const float*)d_in[11];
    const float* wp_W2 = (const float*)d_in[12];
    const float* wp_b2 = (const float*)d_in[13];
    const float* wp_W3 = (const float*)d_in[14];
    const float* wp_b3 = (const float*)d_in[15];
    const float* wp_W4 = (const float*)d_in[16];
    const float* wp_b4 = (const float*)d_in[17];
    const float* wtemp = (const float*)d_in[18];

    float* ws = (float*)d_ws;
    f16* ln16     = (f16*)(ws + OFF_LN16);
    f16* lnlo     = (f16*)(ws + OFF_LNLO);
    f16* fq16     = (f16*)(ws + OFF_FQ16);
    f16* fk16     = (f16*)(ws + OFF_FK16);
    f16* fvhT     = (f16*)(ws + OFF_FVHT);
    f16* fvlT     = (f16*)(ws + OFF_FVLT);
    f16* WinTh    = (f16*)(ws + OFF_WINTH);
    f16* WinTl    = (f16*)(ws + OFF_WINTL);
    f16* WoutTh   = (f16*)(ws + OFF_WOUTTH);
    f16* WoutTl   = (f16*)(ws + OFF_WOUTTL);
    f16* avh      = (f16*)(ws + OFF_AVH);
    f16* avl      = (f16*)(ws + OFF_AVL);
    float* rq1    = ws + OFF_RQ1;
    float* rq2    = ws + OFF_RQ2;
    float* muq    = ws + OFF_MUQ;
    float* rk1    = ws + OFF_RK1;
    float* rk2    = ws + OFF_RK2;
    float* sk     = ws + OFF_SK;
    float* vcrow  = ws + OFF_VC;
    float* rowcos = ws + OFF_ROWCOS;
    float* rowcov = ws + OFF_ROWCOV;
    float* nuacck = ws + OFF_NUACC;
    float* pb     = ws + OFF_PB;
    float* hs     = ws + OFF_HS;
    float* rp     = ws + OFF_RP;
    float* feat   = ws + OFF_FEAT;
    float* wv     = ws + OFF_WV;
    float* scal   = ws + OFF_SCAL;

    k_zero<<<8, 256, 0, stream>>>(feat, nuacck);
    k_wprep<<<dim3(8, 8, 2), 256, 0, stream>>>(W_in, W_out, WinTh, WinTl, WoutTh, WoutTl);
    k_ln16<<<3072, 256, 0, stream>>>(q, k, v, ln_w, ln_b, ln16, lnlo);
    k_proj_all<<<dim3(4, 32, 3), 256, 0, stream>>>(ln16, lnlo, WinTh, WinTl,
            fq16, fk16, fvhT, fvlT, rq1, rq2, muq, rk1, rk2, sk, feat, nuacck);
    k_mlp<<<8, 256, 0, stream>>>(feat, wp_W1, wp_b1, wp_lw, wp_lb,
                                 wp_W2, wp_b2, wp_W3, wp_b3, wp_W4, wp_b4,
                                 wtemp, wv);
    k_passA<<<dim3(16, 2, 32), 256, 0, stream>>>(fq16, fk16, rq1, rq2, muq, rk1, rk2,
                                                 sk, nuacck, vcrow, rowcos, rowcov, pb);
    k_fin1<<<1, 256, 0, stream>>>(pb, vcrow, hs, scal);
    k_finrow<<<64, 256, 0, stream>>>(vcrow, rowcos, rowcov, wv, scal, rp);
    k_fin2<<<1, 64, 0, stream>>>(rp, hs, wv, scal);
    k_passC<<<dim3(16, 32), 512, 0, stream>>>(fq16, fk16, rq1, muq, rk1, sk, nuacck,
                                              vcrow, wv, scal, fvhT, fvlT, avh, avl);
    k_out_mfma<<<dim3(4, 64), 256, 0, stream>>>(avh, avl, WoutTh, WoutTl, b_out,
                                                (float*)d_out);
}